// Round 1
// baseline (2792.270 us; speedup 1.0000x reference)
//
#include <hip/hip_runtime.h>
#include <math.h>

// ---- problem constants ----
#define V_   32000
#define D_   1024
#define H_   16
#define HD_  64
#define L_   6
#define F_   4096
#define S_   1024
#define B_   2
#define MTOK (B_*S_)      // 2048
#define EPSLN 1e-5f

typedef unsigned short ushort_t;
typedef __attribute__((ext_vector_type(8))) short  s16x8;
typedef __attribute__((ext_vector_type(4))) float  f32x4;
typedef __attribute__((ext_vector_type(4))) unsigned short u16x4;

// ---- bf16 helpers (raw ushort) ----
__device__ __forceinline__ float bf2f(unsigned short u) {
    unsigned int x = ((unsigned int)u) << 16;
    return __builtin_bit_cast(float, x);
}
__device__ __forceinline__ unsigned short f2bf(float f) {
    unsigned int x = __builtin_bit_cast(unsigned int, f);
    unsigned int r = (x + 0x7FFFu + ((x >> 16) & 1u)) >> 16;   // RNE
    return (unsigned short)r;
}

// ---- block reductions (256 threads = 4 waves of 64) ----
__device__ __forceinline__ float blk_sum(float v, float* sb) {
    #pragma unroll
    for (int o = 32; o; o >>= 1) v += __shfl_xor(v, o, 64);
    int w = threadIdx.x >> 6;
    __syncthreads();
    if ((threadIdx.x & 63) == 0) sb[w] = v;
    __syncthreads();
    return sb[0] + sb[1] + sb[2] + sb[3];
}
__device__ __forceinline__ float blk_max(float v, float* sb) {
    #pragma unroll
    for (int o = 32; o; o >>= 1) v = fmaxf(v, __shfl_xor(v, o, 64));
    int w = threadIdx.x >> 6;
    __syncthreads();
    if ((threadIdx.x & 63) == 0) sb[w] = v;
    __syncthreads();
    return fmaxf(fmaxf(sb[0], sb[1]), fmaxf(sb[2], sb[3]));
}

// =====================================================================
// Generic bf16 MFMA GEMM:  C = epi( A[M,K] @ BT[N,K]^T * scale + bias )
// m97-style: 128x128 tile, BK=32, 4 waves (2x2), 4x4 frags of 16x16x32.
// Batched via blockIdx.z: offsets = (z/H)*s?b + (z%H)*s?h  (elements).
// causal_flags bit0: skip tiles with n0 > m0 (upper-tri score tiles)
//              bit1: bound K-loop at m0+128 (PV over zeroed-causal P)
// =====================================================================
template<bool GELU, bool RES, bool OUTBF>
__global__ __launch_bounds__(256)
void gemm_bt(const ushort_t* __restrict__ A, int lda, long long sAb, long long sAh,
             const ushort_t* __restrict__ BT, int ldb, long long sBb, long long sBh,
             void* __restrict__ Cv, int ldc, long long sCb, long long sCh,
             const float* __restrict__ bias,
             const float* __restrict__ res,
             int M, int N, int K, float scale, int causal_flags)
{
    const int BM = 128, BN = 128, BK = 32;
    int m0 = blockIdx.y * BM;
    int n0 = blockIdx.x * BN;
    if ((causal_flags & 1) && n0 > m0) return;   // tile fully above diagonal

    int z  = blockIdx.z;
    int zb = z / H_, zh = z % H_;
    const ushort_t* Ab = A + (size_t)zb * sAb + (size_t)zh * sAh;
    const ushort_t* Bb = BT + (size_t)zb * sBb + (size_t)zh * sBh;

    __shared__ __align__(16) ushort_t lA[BM * BK];
    __shared__ __align__(16) ushort_t lB[BN * BK];

    int tid  = threadIdx.x;
    int lane = tid & 63;
    int wave = tid >> 6;
    int lr = lane & 15, lg = lane >> 4;
    int wr = wave >> 1, wc = wave & 1;

    f32x4 acc[4][4] = {};

    int kend = K;
    if (causal_flags & 2) { int kb = m0 + BM; kend = (K < kb) ? K : kb; }
    int nkt = kend / BK;

    for (int kt = 0; kt < nkt; ++kt) {
        int k0 = kt * BK;
        // stage A tile (128x32 bf16 = 8KB): 2 rounds x 256 thr x 16B
        #pragma unroll
        for (int i = 0; i < 2; ++i) {
            int e   = (i * 256 + tid) * 8;        // element index in tile
            int row = e >> 5, col = e & 31;
            const ushort_t* g = Ab + (size_t)(m0 + row) * lda + k0 + col;
            __builtin_amdgcn_global_load_lds(
                (const __attribute__((address_space(1))) void*)g,
                (__attribute__((address_space(3))) void*)&lA[e], 16, 0, 0);
        }
        // stage B tile (rows clamped for N < 128, e.g. PV N=64)
        #pragma unroll
        for (int i = 0; i < 2; ++i) {
            int e   = (i * 256 + tid) * 8;
            int row = e >> 5, col = e & 31;
            int gr = n0 + row; if (gr >= N) gr = N - 1;
            const ushort_t* g = Bb + (size_t)gr * ldb + k0 + col;
            __builtin_amdgcn_global_load_lds(
                (const __attribute__((address_space(1))) void*)g,
                (__attribute__((address_space(3))) void*)&lB[e], 16, 0, 0);
        }
        __syncthreads();

        s16x8 af[4], bfr[4];
        #pragma unroll
        for (int m = 0; m < 4; ++m)
            af[m] = *(const s16x8*)&lA[(wr * 64 + m * 16 + lr) * BK + lg * 8];
        #pragma unroll
        for (int n = 0; n < 4; ++n)
            bfr[n] = *(const s16x8*)&lB[(wc * 64 + n * 16 + lr) * BK + lg * 8];
        #pragma unroll
        for (int m = 0; m < 4; ++m)
            #pragma unroll
            for (int n = 0; n < 4; ++n)
                acc[m][n] = __builtin_amdgcn_mfma_f32_16x16x32_bf16(
                    af[m], bfr[n], acc[m][n], 0, 0, 0);
        __syncthreads();
    }

    // epilogue: C/D frag layout col=lane&15, row=(lane>>4)*4+j
    size_t coff = (size_t)zb * sCb + (size_t)zh * sCh;
    float*    Cf = (float*)Cv;
    ushort_t* Cb = (ushort_t*)Cv;
    #pragma unroll
    for (int m = 0; m < 4; ++m) {
        int gm0 = m0 + wr * 64 + m * 16 + lg * 4;
        #pragma unroll
        for (int n = 0; n < 4; ++n) {
            int gn = n0 + wc * 64 + n * 16 + lr;
            if (gn >= N) continue;
            #pragma unroll
            for (int j = 0; j < 4; ++j) {
                float v = acc[m][n][j] * scale;
                if (bias) v += bias[gn];
                size_t ci = coff + (size_t)(gm0 + j) * ldc + gn;
                if (RES)  v += res[ci];
                if (GELU) v = 0.5f * v * (1.0f + erff(v * 0.70710678118f));
                if (OUTBF) Cb[ci] = f2bf(v);
                else       Cf[ci] = v;
            }
        }
    }
}

// ---- f32 [R,C] -> bf16 [C,R] transpose-convert ----
__global__ __launch_bounds__(256)
void tconv(const float* __restrict__ in, ushort_t* __restrict__ out, int R, int C)
{
    __shared__ float t[32][33];
    int c0 = blockIdx.x * 32, r0 = blockIdx.y * 32;
    int tx = threadIdx.x & 31, ty = threadIdx.x >> 5;    // 32 x 8
    #pragma unroll
    for (int i = 0; i < 4; ++i)
        t[ty + i * 8][tx] = in[(size_t)(r0 + ty + i * 8) * C + c0 + tx];
    __syncthreads();
    #pragma unroll
    for (int i = 0; i < 4; ++i)
        out[(size_t)(c0 + ty + i * 8) * R + r0 + tx] = f2bf(t[tx][ty + i * 8]);
}

// ---- per-head V transpose: v[B,S,D] -> vt[BH][HD][S] (bf16) ----
__global__ __launch_bounds__(256)
void vtrans(const ushort_t* __restrict__ v, ushort_t* __restrict__ vt)
{
    int z = blockIdx.z, b = z / H_, h = z % H_;
    int s0 = blockIdx.x * 32, d0 = blockIdx.y * 32;
    __shared__ ushort_t t[32][33];
    int tx = threadIdx.x & 31, ty = threadIdx.x >> 5;
    #pragma unroll
    for (int i = 0; i < 4; ++i)
        t[ty + i * 8][tx] = v[(size_t)(b * S_ + s0 + ty + i * 8) * D_ + h * HD_ + d0 + tx];
    __syncthreads();
    #pragma unroll
    for (int i = 0; i < 4; ++i)
        vt[((size_t)z * HD_ + d0 + ty + i * 8) * S_ + s0 + tx] = t[tx][ty + i * 8];
}

// ---- embedding * sqrt(D) + sinusoidal PE -> x (f32) ----
__global__ __launch_bounds__(256)
void embed_pe(const int* __restrict__ ids, const float* __restrict__ emb,
              float* __restrict__ x)
{
    int row = blockIdx.x;           // 0..MTOK-1
    int s   = row & (S_ - 1);
    int id  = ids[row];
    int d   = threadIdx.x * 4;
    f32x4 ev = *(const f32x4*)&emb[(size_t)id * D_ + d];
    f32x4 o;
    #pragma unroll
    for (int j = 0; j < 4; ++j) {
        int dd = d + j;
        int i  = dd >> 1;
        float div = expf(-(float)(2 * i) * (9.210340371976184f / 1024.0f));
        float arg = (float)s * div;
        float pe  = (dd & 1) ? cosf(arg) : sinf(arg);
        o[j] = ev[j] * 32.0f + pe;
    }
    *(f32x4*)&x[(size_t)row * D_ + d] = o;
}

// ---- LayerNorm row kernel: f32 in -> bf16 out ----
__global__ __launch_bounds__(256)
void ln_kernel(const float* __restrict__ x, const float* __restrict__ g,
               const float* __restrict__ b, ushort_t* __restrict__ out)
{
    __shared__ float sb[4];
    int row = blockIdx.x;
    const float* xr = x + (size_t)row * D_;
    int c = threadIdx.x * 4;
    f32x4 v = *(const f32x4*)&xr[c];
    float s = v[0] + v[1] + v[2] + v[3];
    s = blk_sum(s, sb);
    float mean = s * (1.0f / D_);
    f32x4 dv = v - mean;
    float sq = dv[0]*dv[0] + dv[1]*dv[1] + dv[2]*dv[2] + dv[3]*dv[3];
    sq = blk_sum(sq, sb);
    float rstd = rsqrtf(sq * (1.0f / D_) + EPSLN);
    u16x4 o;
    #pragma unroll
    for (int j = 0; j < 4; ++j)
        o[j] = f2bf(dv[j] * rstd * g[c + j] + b[c + j]);
    *(u16x4*)&out[(size_t)row * D_ + c] = o;
}

// ---- causal softmax, in-place on bf16 scores; zeros upper triangle ----
__global__ __launch_bounds__(256)
void softmax_causal(ushort_t* __restrict__ p)
{
    __shared__ float sb[4];
    int r = blockIdx.x, z = blockIdx.y;
    ushort_t* rp = p + ((size_t)z * S_ + r) * S_;
    int c0 = threadIdx.x * 4;
    u16x4 u = *(const u16x4*)&rp[c0];
    float vv[4];
    float mx = -1e30f;
    #pragma unroll
    for (int j = 0; j < 4; ++j) {
        vv[j] = bf2f(u[j]);
        if (c0 + j <= r) mx = fmaxf(mx, vv[j]);
    }
    mx = blk_max(mx, sb);
    float e[4], s = 0.f;
    #pragma unroll
    for (int j = 0; j < 4; ++j) {
        e[j] = (c0 + j <= r) ? expf(vv[j] - mx) : 0.f;
        s += e[j];
    }
    s = blk_sum(s, sb);
    float inv = 1.0f / s;
    u16x4 o;
    #pragma unroll
    for (int j = 0; j < 4; ++j) o[j] = f2bf(e[j] * inv);
    *(u16x4*)&rp[c0] = o;
}

__global__ void ws_marker(float* o) { o[threadIdx.x] = -777777.0f; }

// =====================================================================
extern "C" void kernel_launch(void* const* d_in, const int* in_sizes, int n_in,
                              void* d_out, int out_size, void* d_ws, size_t ws_size,
                              hipStream_t stream)
{
    (void)in_sizes; (void)n_in; (void)out_size;
    const int*   ids  = (const int*)d_in[0];
    const float* emb  = (const float*)d_in[1];
    const float* Wq   = (const float*)d_in[2];
    const float* bq   = (const float*)d_in[3];
    const float* Wk   = (const float*)d_in[4];
    const float* bk   = (const float*)d_in[5];
    const float* Wv   = (const float*)d_in[6];
    const float* bv   = (const float*)d_in[7];
    const float* Wo   = (const float*)d_in[8];
    const float* bo   = (const float*)d_in[9];
    const float* ln1g = (const float*)d_in[10];
    const float* ln1b = (const float*)d_in[11];
    const float* ln2g = (const float*)d_in[12];
    const float* ln2b = (const float*)d_in[13];
    const float* W1   = (const float*)d_in[14];
    const float* b1   = (const float*)d_in[15];
    const float* W2   = (const float*)d_in[16];
    const float* b2   = (const float*)d_in[17];
    const float* fng  = (const float*)d_in[18];
    const float* fnb  = (const float*)d_in[19];
    const float* Wout = (const float*)d_in[20];
    const float* bout = (const float*)d_in[21];
    float* out = (float*)d_out;

    // ---- workspace layout ----
    char* base = (char*)d_ws;
    size_t off = 0;
    float*    x   = (float*)(base + off);    off += (size_t)MTOK * D_ * 4;
    ushort_t* h   = (ushort_t*)(base + off); off += (size_t)MTOK * D_ * 2;
    ushort_t* q   = (ushort_t*)(base + off); off += (size_t)MTOK * D_ * 2;
    ushort_t* kk  = (ushort_t*)(base + off); off += (size_t)MTOK * D_ * 2;
    ushort_t* vv  = (ushort_t*)(base + off); off += (size_t)MTOK * D_ * 2;
    ushort_t* vt  = (ushort_t*)(base + off); off += (size_t)B_ * H_ * HD_ * S_ * 2;
    ushort_t* ctx = (ushort_t*)(base + off); off += (size_t)MTOK * D_ * 2;
    ushort_t* ff  = (ushort_t*)(base + off); off += (size_t)MTOK * F_ * 2;
    ushort_t* P   = (ushort_t*)(base + off); off += (size_t)B_ * H_ * S_ * S_ * 2;
    ushort_t* wT  = (ushort_t*)(base + off); off += (size_t)V_ * D_ * 2;
    if (ws_size < off) { ws_marker<<<1, 64, 0, stream>>>(out); return; }

    ushort_t* wqT = wT;
    ushort_t* wkT = wT + (size_t)1 * D_ * D_;
    ushort_t* wvT = wT + (size_t)2 * D_ * D_;
    ushort_t* woT = wT + (size_t)3 * D_ * D_;
    ushort_t* w1T = wT + (size_t)4 * D_ * D_;
    ushort_t* w2T = w1T + (size_t)D_ * F_;

    const long long sTok = (long long)S_ * D_;     // batch stride into q/k/v/ctx
    const long long sPb  = (long long)H_ * S_ * S_;
    const long long sPh  = (long long)S_ * S_;
    const long long sVtb = (long long)H_ * HD_ * S_;
    const long long sVth = (long long)HD_ * S_;

    embed_pe<<<MTOK, 256, 0, stream>>>(ids, emb, x);

    for (int i = 0; i < L_; ++i) {
        tconv<<<dim3(32, 32),  256, 0, stream>>>(Wq + (size_t)i * D_ * D_, wqT, D_, D_);
        tconv<<<dim3(32, 32),  256, 0, stream>>>(Wk + (size_t)i * D_ * D_, wkT, D_, D_);
        tconv<<<dim3(32, 32),  256, 0, stream>>>(Wv + (size_t)i * D_ * D_, wvT, D_, D_);
        tconv<<<dim3(32, 32),  256, 0, stream>>>(Wo + (size_t)i * D_ * D_, woT, D_, D_);
        tconv<<<dim3(128, 32), 256, 0, stream>>>(W1 + (size_t)i * D_ * F_, w1T, D_, F_);
        tconv<<<dim3(32, 128), 256, 0, stream>>>(W2 + (size_t)i * F_ * D_, w2T, F_, D_);

        ln_kernel<<<MTOK, 256, 0, stream>>>(x, ln1g + i * D_, ln1b + i * D_, h);

        gemm_bt<false,false,true><<<dim3(8, 16, 1), 256, 0, stream>>>(
            h, D_, 0, 0, wqT, D_, 0, 0, q, D_, 0, 0,
            bq + i * D_, nullptr, MTOK, D_, D_, 1.0f, 0);
        gemm_bt<false,false,true><<<dim3(8, 16, 1), 256, 0, stream>>>(
            h, D_, 0, 0, wkT, D_, 0, 0, kk, D_, 0, 0,
            bk + i * D_, nullptr, MTOK, D_, D_, 1.0f, 0);
        gemm_bt<false,false,true><<<dim3(8, 16, 1), 256, 0, stream>>>(
            h, D_, 0, 0, wvT, D_, 0, 0, vv, D_, 0, 0,
            bv + i * D_, nullptr, MTOK, D_, D_, 1.0f, 0);

        vtrans<<<dim3(32, 2, B_ * H_), 256, 0, stream>>>(vv, vt);

        // scores = (q @ k^T) / 8   -> P (bf16), causal tile skip
        gemm_bt<false,false,true><<<dim3(8, 8, B_ * H_), 256, 0, stream>>>(
            q, D_, sTok, HD_, kk, D_, sTok, HD_, P, S_, sPb, sPh,
            nullptr, nullptr, S_, S_, HD_, 0.125f, 1);

        softmax_causal<<<dim3(S_, B_ * H_), 256, 0, stream>>>(P);

        // ctx = P @ V   (K bounded at diagonal; N=64)
        gemm_bt<false,false,true><<<dim3(1, 8, B_ * H_), 256, 0, stream>>>(
            P, S_, sPb, sPh, vt, S_, sVtb, sVth, ctx, D_, sTok, HD_,
            nullptr, nullptr, S_, HD_, S_, 1.0f, 2);

        // x = x + ctx @ Wo + bo
        gemm_bt<false,true,false><<<dim3(8, 16, 1), 256, 0, stream>>>(
            ctx, D_, 0, 0, woT, D_, 0, 0, x, D_, 0, 0,
            bo + i * D_, x, MTOK, D_, D_, 1.0f, 0);

        ln_kernel<<<MTOK, 256, 0, stream>>>(x, ln2g + i * D_, ln2b + i * D_, h);

        // ff = gelu(h @ W1 + b1)
        gemm_bt<true,false,true><<<dim3(32, 16, 1), 256, 0, stream>>>(
            h, D_, 0, 0, w1T, D_, 0, 0, ff, F_, 0, 0,
            b1 + i * F_, nullptr, MTOK, F_, D_, 1.0f, 0);

        // x = x + ff @ W2 + b2
        gemm_bt<false,true,false><<<dim3(8, 16, 1), 256, 0, stream>>>(
            ff, F_, 0, 0, w2T, F_, 0, 0, x, D_, 0, 0,
            b2 + i * D_, x, MTOK, D_, F_, 1.0f, 0);
    }

    ln_kernel<<<MTOK, 256, 0, stream>>>(x, fng, fnb, h);
    tconv<<<dim3(1000, 32), 256, 0, stream>>>(Wout, wT, D_, V_);
    gemm_bt<false,false,false><<<dim3(250, 16, 1), 256, 0, stream>>>(
        h, D_, 0, 0, wT, D_, 0, 0, out, V_, 0, 0,
        bout, nullptr, MTOK, V_, D_, 1.0f, 0);
}

// Round 2
// 2150.290 us; speedup vs baseline: 1.2986x; 1.2986x over previous
//
#include <hip/hip_runtime.h>
#include <math.h>

// ---- problem constants ----
#define V_   32000
#define D_   1024
#define H_   16
#define HD_  64
#define L_   6
#define F_   4096
#define S_   1024
#define B_   2
#define MTOK (B_*S_)      // 2048
#define EPSLN 1e-5f

typedef unsigned short ushort_t;
typedef __attribute__((ext_vector_type(8))) short  s16x8;
typedef __attribute__((ext_vector_type(4))) float  f32x4;
typedef __attribute__((ext_vector_type(4))) unsigned short u16x4;

// ---- bf16 helpers (raw ushort) ----
__device__ __forceinline__ float bf2f(unsigned short u) {
    unsigned int x = ((unsigned int)u) << 16;
    return __builtin_bit_cast(float, x);
}
__device__ __forceinline__ unsigned short f2bf(float f) {
    unsigned int x = __builtin_bit_cast(unsigned int, f);
    unsigned int r = (x + 0x7FFFu + ((x >> 16) & 1u)) >> 16;   // RNE
    return (unsigned short)r;
}

// ---- block reductions (256 threads = 4 waves of 64) ----
__device__ __forceinline__ float blk_sum(float v, float* sb) {
    #pragma unroll
    for (int o = 32; o; o >>= 1) v += __shfl_xor(v, o, 64);
    int w = threadIdx.x >> 6;
    __syncthreads();
    if ((threadIdx.x & 63) == 0) sb[w] = v;
    __syncthreads();
    return sb[0] + sb[1] + sb[2] + sb[3];
}

// =====================================================================
// Generic bf16 MFMA GEMM:  C = epi( A[M,K] @ BT[N,K]^T + bias )
// 128x128 tile, BK=32, 4 waves (2x2), 4x4 frags of 16x16x32.
// Grid: x = M-tiles (fast -> concurrent blocks share B panels, B streams
// once through L2/L3), y = N-tiles.
// =====================================================================
template<bool GELU, bool RES, bool OUTBF>
__global__ __launch_bounds__(256)
void gemm_bt(const ushort_t* __restrict__ A, int lda,
             const ushort_t* __restrict__ BT, int ldb,
             void* __restrict__ Cv, int ldc,
             const float* __restrict__ bias,
             const float* __restrict__ res,
             int M, int N, int K)
{
    const int BM = 128, BN = 128, BK = 32;
    int m0 = blockIdx.x * BM;
    int n0 = blockIdx.y * BN;

    __shared__ __align__(16) ushort_t lA[BM * BK];
    __shared__ __align__(16) ushort_t lB[BN * BK];

    int tid  = threadIdx.x;
    int lane = tid & 63;
    int wave = tid >> 6;
    int lr = lane & 15, lg = lane >> 4;
    int wr = wave >> 1, wc = wave & 1;

    f32x4 acc[4][4] = {};
    int nkt = K / BK;

    for (int kt = 0; kt < nkt; ++kt) {
        int k0 = kt * BK;
        #pragma unroll
        for (int i = 0; i < 2; ++i) {
            int e   = (i * 256 + tid) * 8;
            int row = e >> 5, col = e & 31;
            const ushort_t* g = A + (size_t)(m0 + row) * lda + k0 + col;
            __builtin_amdgcn_global_load_lds(
                (const __attribute__((address_space(1))) void*)g,
                (__attribute__((address_space(3))) void*)&lA[e], 16, 0, 0);
        }
        #pragma unroll
        for (int i = 0; i < 2; ++i) {
            int e   = (i * 256 + tid) * 8;
            int row = e >> 5, col = e & 31;
            const ushort_t* g = BT + (size_t)(n0 + row) * ldb + k0 + col;
            __builtin_amdgcn_global_load_lds(
                (const __attribute__((address_space(1))) void*)g,
                (__attribute__((address_space(3))) void*)&lB[e], 16, 0, 0);
        }
        __syncthreads();

        s16x8 af[4], bfr[4];
        #pragma unroll
        for (int m = 0; m < 4; ++m)
            af[m] = *(const s16x8*)&lA[(wr * 64 + m * 16 + lr) * BK + lg * 8];
        #pragma unroll
        for (int n = 0; n < 4; ++n)
            bfr[n] = *(const s16x8*)&lB[(wc * 64 + n * 16 + lr) * BK + lg * 8];
        #pragma unroll
        for (int m = 0; m < 4; ++m)
            #pragma unroll
            for (int n = 0; n < 4; ++n)
                acc[m][n] = __builtin_amdgcn_mfma_f32_16x16x32_bf16(
                    af[m], bfr[n], acc[m][n], 0, 0, 0);
        __syncthreads();
    }

    float*    Cf = (float*)Cv;
    ushort_t* Cb = (ushort_t*)Cv;
    #pragma unroll
    for (int m = 0; m < 4; ++m) {
        int gm0 = m0 + wr * 64 + m * 16 + lg * 4;
        #pragma unroll
        for (int n = 0; n < 4; ++n) {
            int gn = n0 + wc * 64 + n * 16 + lr;
            #pragma unroll
            for (int j = 0; j < 4; ++j) {
                float v = acc[m][n][j];
                if (bias) v += bias[gn];
                size_t ci = (size_t)(gm0 + j) * ldc + gn;
                if (RES)  v += res[ci];
                if (GELU) v = 0.5f * v * (1.0f + erff(v * 0.70710678118f));
                if (OUTBF) Cb[ci] = f2bf(v);
                else       Cf[ci] = v;
            }
        }
    }
}

// =====================================================================
// Flash attention: one block = (b,h) x 64-row Q tile. 4 waves.
// qkv [M][3072] bf16 (Q|K|V cols), vt [BH][HD][S] bf16, ctx [M][D] bf16.
// LDS Q/K/VT tiles XOR-swizzled (slot ^= row&7) with pre-swizzled global
// source so global_load_lds stays linear-dest.
// =====================================================================
__global__ __launch_bounds__(256)
void flash_attn(const ushort_t* __restrict__ qkv,
                const ushort_t* __restrict__ vt,
                ushort_t* __restrict__ ctx)
{
    const int QB = 64, KB = 64;
    int z  = blockIdx.y;            // b*H + h
    int b  = z >> 4, hh = z & 15;
    int q0 = blockIdx.x * QB;

    __shared__ __align__(16) ushort_t Qs[QB * 64];
    __shared__ __align__(16) ushort_t Ks[KB * 64];
    __shared__ __align__(16) ushort_t Vs[64 * KB];     // rows = d
    __shared__ float    Ss[QB][68];
    __shared__ __align__(16) ushort_t Ps[QB][72];
    __shared__ float mrow[QB], lrow[QB], arow[QB];

    int tid  = threadIdx.x;
    int lane = tid & 63, wave = tid >> 6;
    int lr = lane & 15, lg = lane >> 4;

    if (tid < QB) { mrow[tid] = -1e30f; lrow[tid] = 0.f; }

    // ---- stage Q tile (swizzled source, linear LDS dest) ----
    const ushort_t* qbase = qkv + (size_t)(b * S_ + q0) * 3072 + hh * HD_;
    #pragma unroll
    for (int rnd = 0; rnd < 2; ++rnd) {
        int e8   = rnd * 256 + tid;            // 16B unit
        int row  = e8 >> 3;
        int slot = e8 & 7;
        int ls   = slot ^ (row & 7);
        const ushort_t* g = qbase + (size_t)row * 3072 + ls * 8;
        __builtin_amdgcn_global_load_lds(
            (const __attribute__((address_space(1))) void*)g,
            (__attribute__((address_space(3))) void*)&Qs[e8 * 8], 16, 0, 0);
    }
    __syncthreads();

    // preload Q A-frags: row = mf*16+lr, k-slot = lg + ks*4 (swizzled read)
    s16x8 qa[4][2];
    #pragma unroll
    for (int mf = 0; mf < 4; ++mf)
        #pragma unroll
        for (int ks = 0; ks < 2; ++ks) {
            int row = mf * 16 + lr;
            int sl  = (lg + ks * 4) ^ (row & 7);
            qa[mf][ks] = *(const s16x8*)&Qs[row * 64 + sl * 8];
        }

    f32x4 acc[4] = {};
    int r = tid >> 2, p = tid & 3;             // softmax role

    int kv_end = q0 + QB;
    for (int kv0 = 0; kv0 < kv_end; kv0 += KB) {
        // ---- stage K and V^T tiles ----
        const ushort_t* kbase = qkv + (size_t)(b * S_ + kv0) * 3072 + 1024 + hh * HD_;
        const ushort_t* vbase = vt + (size_t)z * HD_ * S_ + kv0;
        #pragma unroll
        for (int rnd = 0; rnd < 2; ++rnd) {
            int e8 = rnd * 256 + tid;
            int row = e8 >> 3, slot = e8 & 7;
            int ls = slot ^ (row & 7);
            const ushort_t* gk = kbase + (size_t)row * 3072 + ls * 8;
            __builtin_amdgcn_global_load_lds(
                (const __attribute__((address_space(1))) void*)gk,
                (__attribute__((address_space(3))) void*)&Ks[e8 * 8], 16, 0, 0);
            const ushort_t* gv = vbase + (size_t)row * S_ + ls * 8;
            __builtin_amdgcn_global_load_lds(
                (const __attribute__((address_space(1))) void*)gv,
                (__attribute__((address_space(3))) void*)&Vs[e8 * 8], 16, 0, 0);
        }
        __syncthreads();

        // ---- QK^T: wave owns kv slice wave*16 ----
        s16x8 kb[2];
        #pragma unroll
        for (int ks = 0; ks < 2; ++ks) {
            int row = wave * 16 + lr;
            int sl  = (lg + ks * 4) ^ (row & 7);
            kb[ks] = *(const s16x8*)&Ks[row * 64 + sl * 8];
        }
        f32x4 sa[4] = {};
        #pragma unroll
        for (int mf = 0; mf < 4; ++mf)
            #pragma unroll
            for (int ks = 0; ks < 2; ++ks)
                sa[mf] = __builtin_amdgcn_mfma_f32_16x16x32_bf16(
                    qa[mf][ks], kb[ks], sa[mf], 0, 0, 0);

        int ki = kv0 + wave * 16 + lr;
        #pragma unroll
        for (int mf = 0; mf < 4; ++mf)
            #pragma unroll
            for (int j = 0; j < 4; ++j) {
                int qi = q0 + mf * 16 + lg * 4 + j;
                float s = (ki <= qi) ? sa[mf][j] * 0.125f : -1e30f;
                Ss[mf * 16 + lg * 4 + j][wave * 16 + lr] = s;
            }
        __syncthreads();

        // ---- online softmax: 4 threads per row ----
        float mo = mrow[r];
        float sv[16];
        float pm = -1e30f;
        #pragma unroll
        for (int i = 0; i < 16; ++i) {
            sv[i] = Ss[r][p * 16 + i];
            pm = fmaxf(pm, sv[i]);
        }
        pm = fmaxf(pm, __shfl_xor(pm, 1, 64));
        pm = fmaxf(pm, __shfl_xor(pm, 2, 64));
        float M = fmaxf(mo, pm);
        float sum = 0.f;
        s16x8 pk0, pk1;
        #pragma unroll
        for (int i = 0; i < 8; ++i) {
            float e0 = __expf(sv[i] - M);
            float e1 = __expf(sv[i + 8] - M);
            sum += e0 + e1;
            pk0[i] = (short)f2bf(e0);
            pk1[i] = (short)f2bf(e1);
        }
        *(s16x8*)&Ps[r][p * 16]     = pk0;
        *(s16x8*)&Ps[r][p * 16 + 8] = pk1;
        sum += __shfl_xor(sum, 1, 64);
        sum += __shfl_xor(sum, 2, 64);
        if (p == 0) {
            float al = __expf(mo - M);
            arow[r] = al;
            mrow[r] = M;
            lrow[r] = lrow[r] * al + sum;
        }
        __syncthreads();

        // ---- PV: rescale acc, accumulate P @ V ----
        #pragma unroll
        for (int mf = 0; mf < 4; ++mf) {
            #pragma unroll
            for (int j = 0; j < 4; ++j)
                acc[mf][j] *= arow[mf * 16 + lg * 4 + j];
        }
        s16x8 vb[2];
        #pragma unroll
        for (int ks = 0; ks < 2; ++ks) {
            int row = wave * 16 + lr;              // d index
            int sl  = (lg + ks * 4) ^ (row & 7);
            vb[ks] = *(const s16x8*)&Vs[row * 64 + sl * 8];
        }
        #pragma unroll
        for (int mf = 0; mf < 4; ++mf)
            #pragma unroll
            for (int ks = 0; ks < 2; ++ks) {
                s16x8 pa = *(const s16x8*)((const char*)&Ps[0][0]
                            + (mf * 16 + lr) * 144 + lg * 16 + ks * 64);
                acc[mf] = __builtin_amdgcn_mfma_f32_16x16x32_bf16(
                    pa, vb[ks], acc[mf], 0, 0, 0);
            }
        __syncthreads();
    }

    // ---- epilogue: ctx[b, q, h, d] = acc / l ----
    #pragma unroll
    for (int mf = 0; mf < 4; ++mf)
        #pragma unroll
        for (int j = 0; j < 4; ++j) {
            int rr = mf * 16 + lg * 4 + j;
            float o = acc[mf][j] / lrow[rr];
            ctx[(size_t)(b * S_ + q0 + rr) * D_ + hh * HD_ + wave * 16 + lr] = f2bf(o);
        }
}

// ---- f32 [R,C] -> bf16 [C,R] transpose-convert ----
__global__ __launch_bounds__(256)
void tconv(const float* __restrict__ in, ushort_t* __restrict__ out, int R, int C)
{
    __shared__ float t[32][33];
    int c0 = blockIdx.x * 32, r0 = blockIdx.y * 32;
    int tx = threadIdx.x & 31, ty = threadIdx.x >> 5;    // 32 x 8
    #pragma unroll
    for (int i = 0; i < 4; ++i)
        t[ty + i * 8][tx] = in[(size_t)(r0 + ty + i * 8) * C + c0 + tx];
    __syncthreads();
    #pragma unroll
    for (int i = 0; i < 4; ++i)
        out[(size_t)(c0 + ty + i * 8) * R + r0 + tx] = f2bf(t[tx][ty + i * 8]);
}

// ---- per-head V transpose: v (qkv cols 2048..3071) -> vt[BH][HD][S] ----
__global__ __launch_bounds__(256)
void vtrans(const ushort_t* __restrict__ v, ushort_t* __restrict__ vt)
{
    int z = blockIdx.z, b = z >> 4, h = z & 15;
    int s0 = blockIdx.x * 32, d0 = blockIdx.y * 32;
    __shared__ ushort_t t[32][33];
    int tx = threadIdx.x & 31, ty = threadIdx.x >> 5;
    #pragma unroll
    for (int i = 0; i < 4; ++i)
        t[ty + i * 8][tx] = v[(size_t)(b * S_ + s0 + ty + i * 8) * 3072 + h * HD_ + d0 + tx];
    __syncthreads();
    #pragma unroll
    for (int i = 0; i < 4; ++i)
        vt[((size_t)z * HD_ + d0 + ty + i * 8) * S_ + s0 + tx] = t[tx][ty + i * 8];
}

// ---- embedding * sqrt(D) + sinusoidal PE -> x (f32) ----
__global__ __launch_bounds__(256)
void embed_pe(const int* __restrict__ ids, const float* __restrict__ emb,
              float* __restrict__ x)
{
    int row = blockIdx.x;
    int s   = row & (S_ - 1);
    int id  = ids[row];
    int d   = threadIdx.x * 4;
    f32x4 ev = *(const f32x4*)&emb[(size_t)id * D_ + d];
    f32x4 o;
    #pragma unroll
    for (int j = 0; j < 4; ++j) {
        int dd = d + j;
        int i  = dd >> 1;
        float div = expf(-(float)(2 * i) * (9.210340371976184f / 1024.0f));
        float arg = (float)s * div;
        float pe  = (dd & 1) ? cosf(arg) : sinf(arg);
        o[j] = ev[j] * 32.0f + pe;
    }
    *(f32x4*)&x[(size_t)row * D_ + d] = o;
}

// ---- LayerNorm row kernel: f32 in -> bf16 out ----
__global__ __launch_bounds__(256)
void ln_kernel(const float* __restrict__ x, const float* __restrict__ g,
               const float* __restrict__ b, ushort_t* __restrict__ out)
{
    __shared__ float sb[4];
    int row = blockIdx.x;
    const float* xr = x + (size_t)row * D_;
    int c = threadIdx.x * 4;
    f32x4 v = *(const f32x4*)&xr[c];
    float s = v[0] + v[1] + v[2] + v[3];
    s = blk_sum(s, sb);
    float mean = s * (1.0f / D_);
    f32x4 dv = v - mean;
    float sq = dv[0]*dv[0] + dv[1]*dv[1] + dv[2]*dv[2] + dv[3]*dv[3];
    sq = blk_sum(sq, sb);
    float rstd = rsqrtf(sq * (1.0f / D_) + EPSLN);
    u16x4 o;
    #pragma unroll
    for (int j = 0; j < 4; ++j)
        o[j] = f2bf(dv[j] * rstd * g[c + j] + b[c + j]);
    *(u16x4*)&out[(size_t)row * D_ + c] = o;
}

// ---- concat qkv bias ----
__global__ __launch_bounds__(256)
void bias_cat(const float* __restrict__ bq, const float* __restrict__ bk,
              const float* __restrict__ bv, float* __restrict__ o)
{
    int i = blockIdx.x * 256 + threadIdx.x;
    if (i < 1024)       o[i] = bq[i];
    else if (i < 2048)  o[i] = bk[i - 1024];
    else                o[i] = bv[i - 2048];
}

__global__ void ws_marker(float* o) { o[threadIdx.x] = -777777.0f; }

// =====================================================================
extern "C" void kernel_launch(void* const* d_in, const int* in_sizes, int n_in,
                              void* d_out, int out_size, void* d_ws, size_t ws_size,
                              hipStream_t stream)
{
    (void)in_sizes; (void)n_in; (void)out_size;
    const int*   ids  = (const int*)d_in[0];
    const float* emb  = (const float*)d_in[1];
    const float* Wq   = (const float*)d_in[2];
    const float* bq   = (const float*)d_in[3];
    const float* Wk   = (const float*)d_in[4];
    const float* bk   = (const float*)d_in[5];
    const float* Wv   = (const float*)d_in[6];
    const float* bv   = (const float*)d_in[7];
    const float* Wo   = (const float*)d_in[8];
    const float* bo   = (const float*)d_in[9];
    const float* ln1g = (const float*)d_in[10];
    const float* ln1b = (const float*)d_in[11];
    const float* ln2g = (const float*)d_in[12];
    const float* ln2b = (const float*)d_in[13];
    const float* W1   = (const float*)d_in[14];
    const float* b1   = (const float*)d_in[15];
    const float* W2   = (const float*)d_in[16];
    const float* b2   = (const float*)d_in[17];
    const float* fng  = (const float*)d_in[18];
    const float* fnb  = (const float*)d_in[19];
    const float* Wout = (const float*)d_in[20];
    const float* bout = (const float*)d_in[21];
    float* out = (float*)d_out;

    // ---- workspace layout ----
    char* base = (char*)d_ws;
    size_t off = 0;
    float*    x    = (float*)(base + off);    off += (size_t)MTOK * D_ * 4;
    ushort_t* h    = (ushort_t*)(base + off); off += (size_t)MTOK * D_ * 2;
    ushort_t* qkv  = (ushort_t*)(base + off); off += (size_t)MTOK * 3 * D_ * 2;
    ushort_t* vt   = (ushort_t*)(base + off); off += (size_t)B_ * H_ * HD_ * S_ * 2;
    ushort_t* ctx  = (ushort_t*)(base + off); off += (size_t)MTOK * D_ * 2;
    ushort_t* ff   = (ushort_t*)(base + off); off += (size_t)MTOK * F_ * 2;
    float*    qkvb = (float*)(base + off);    off += 3072 * 4;
    ushort_t* wqkvT= (ushort_t*)(base + off); off += (size_t)3 * D_ * D_ * 2;
    ushort_t* woT  = (ushort_t*)(base + off); off += (size_t)D_ * D_ * 2;
    ushort_t* w1T  = (ushort_t*)(base + off); off += (size_t)D_ * F_ * 2;
    ushort_t* w2T  = (ushort_t*)(base + off); off += (size_t)F_ * D_ * 2;
    ushort_t* wouT = (ushort_t*)(base + off); off += (size_t)V_ * D_ * 2;
    if (ws_size < off) { ws_marker<<<1, 64, 0, stream>>>(out); return; }

    embed_pe<<<MTOK, 256, 0, stream>>>(ids, emb, x);

    for (int i = 0; i < L_; ++i) {
        tconv<<<dim3(32, 32),  256, 0, stream>>>(Wq + (size_t)i * D_ * D_, wqkvT, D_, D_);
        tconv<<<dim3(32, 32),  256, 0, stream>>>(Wk + (size_t)i * D_ * D_, wqkvT + (size_t)D_ * D_, D_, D_);
        tconv<<<dim3(32, 32),  256, 0, stream>>>(Wv + (size_t)i * D_ * D_, wqkvT + (size_t)2 * D_ * D_, D_, D_);
        tconv<<<dim3(32, 32),  256, 0, stream>>>(Wo + (size_t)i * D_ * D_, woT, D_, D_);
        tconv<<<dim3(128, 32), 256, 0, stream>>>(W1 + (size_t)i * D_ * F_, w1T, D_, F_);
        tconv<<<dim3(32, 128), 256, 0, stream>>>(W2 + (size_t)i * F_ * D_, w2T, F_, D_);
        bias_cat<<<12, 256, 0, stream>>>(bq + i * D_, bk + i * D_, bv + i * D_, qkvb);

        ln_kernel<<<MTOK, 256, 0, stream>>>(x, ln1g + i * D_, ln1b + i * D_, h);

        // qkv = h @ [Wq|Wk|Wv] + bias   (M=2048, N=3072, K=1024)
        gemm_bt<false,false,true><<<dim3(16, 24), 256, 0, stream>>>(
            h, D_, wqkvT, D_, qkv, 3 * D_, qkvb, nullptr, MTOK, 3 * D_, D_);

        vtrans<<<dim3(32, 2, B_ * H_), 256, 0, stream>>>(qkv + 2 * D_, vt);

        flash_attn<<<dim3(S_ / 64, B_ * H_), 256, 0, stream>>>(qkv, vt, ctx);

        // x = x + ctx @ Wo + bo
        gemm_bt<false,true,false><<<dim3(16, 8), 256, 0, stream>>>(
            ctx, D_, woT, D_, x, D_, bo + i * D_, x, MTOK, D_, D_);

        ln_kernel<<<MTOK, 256, 0, stream>>>(x, ln2g + i * D_, ln2b + i * D_, h);

        // ff = gelu(h @ W1 + b1)
        gemm_bt<true,false,true><<<dim3(16, 32), 256, 0, stream>>>(
            h, D_, w1T, D_, ff, F_, b1 + i * F_, nullptr, MTOK, F_, D_);

        // x = x + ff @ W2 + b2
        gemm_bt<false,true,false><<<dim3(16, 8), 256, 0, stream>>>(
            ff, F_, w2T, F_, x, D_, b2 + i * D_, x, MTOK, D_, F_);
    }

    ln_kernel<<<MTOK, 256, 0, stream>>>(x, fng, fnb, h);
    tconv<<<dim3(1000, 32), 256, 0, stream>>>(Wout, wouT, D_, V_);
    gemm_bt<false,false,false><<<dim3(16, 250), 256, 0, stream>>>(
        h, D_, wouT, D_, out, V_, bout, nullptr, MTOK, V_, D_);
}

// Round 3
// 2080.485 us; speedup vs baseline: 1.3421x; 1.0336x over previous
//
#include <hip/hip_runtime.h>
#include <math.h>

// ---- problem constants ----
#define V_   32000
#define D_   1024
#define H_   16
#define HD_  64
#define L_   6
#define F_   4096
#define S_   1024
#define B_   2
#define MTOK (B_*S_)      // 2048
#define EPSLN 1e-5f

typedef unsigned short ushort_t;
typedef __attribute__((ext_vector_type(8))) short  s16x8;
typedef __attribute__((ext_vector_type(4))) float  f32x4;
typedef __attribute__((ext_vector_type(4))) unsigned short u16x4;

// ---- bf16 helpers (raw ushort) ----
__device__ __forceinline__ float bf2f(unsigned short u) {
    unsigned int x = ((unsigned int)u) << 16;
    return __builtin_bit_cast(float, x);
}
__device__ __forceinline__ unsigned short f2bf(float f) {
    unsigned int x = __builtin_bit_cast(unsigned int, f);
    unsigned int r = (x + 0x7FFFu + ((x >> 16) & 1u)) >> 16;   // RNE
    return (unsigned short)r;
}

// ---- block reductions (256 threads = 4 waves of 64) ----
__device__ __forceinline__ float blk_sum(float v, float* sb) {
    #pragma unroll
    for (int o = 32; o; o >>= 1) v += __shfl_xor(v, o, 64);
    int w = threadIdx.x >> 6;
    __syncthreads();
    if ((threadIdx.x & 63) == 0) sb[w] = v;
    __syncthreads();
    return sb[0] + sb[1] + sb[2] + sb[3];
}

// =====================================================================
// gemm256: 2-phase double-buffered 256x256xBK64 bf16 MFMA GEMM.
// C = epi( A[M,K] @ BT[N,K]^T + bias ). 512 threads = 8 waves (2M x 4N),
// per-wave 128x64 output (8x4 frags of 16x16x32). LDS 128 KiB (dbuf).
// XOR swizzle: LDS row slot s_phys = s_log ^ (row&7); staged via
// pre-swizzled GLOBAL source + linear LDS dest (rule #21), read with the
// same involution -> ds_read_b128 ~conflict-free.
// Grid %8==0 -> XCD-contiguous chunk swizzle (T1) for B-panel L2 reuse.
// =====================================================================
template<bool GELU, bool OUTBF>
__global__ __launch_bounds__(512, 2)
void gemm256(const ushort_t* __restrict__ A, int lda,
             const ushort_t* __restrict__ BT, int ldb,
             void* __restrict__ Cv, int ldc,
             const float* __restrict__ bias,
             int M, int N, int K)
{
    int nmt = M >> 8;
    int nwg = gridDim.x * gridDim.y;
    int id  = blockIdx.x + gridDim.x * blockIdx.y;
    int swz = ((nwg & 7) == 0) ? ((id & 7) * (nwg >> 3) + (id >> 3)) : id;
    int m0 = (swz % nmt) << 8;
    int n0 = (swz / nmt) << 8;

    __shared__ __align__(16) ushort_t lA[2][256 * 64];
    __shared__ __align__(16) ushort_t lB[2][256 * 64];

    int tid  = threadIdx.x;
    int lane = tid & 63, wave = tid >> 6;
    int lr = lane & 15, lg = lane >> 4;
    int wm = wave >> 2, wn = wave & 3;

    f32x4 acc[8][4] = {};
    int nkt = K >> 6;

    auto stage = [&](int buf, int kt) {
        int k0 = kt << 6;
        #pragma unroll
        for (int r = 0; r < 4; ++r) {
            int e8  = r * 512 + tid;
            int row = e8 >> 3, slot = e8 & 7;
            int ls  = slot ^ (row & 7);
            const ushort_t* ga = A + (size_t)(m0 + row) * lda + k0 + ls * 8;
            __builtin_amdgcn_global_load_lds(
                (const __attribute__((address_space(1))) void*)ga,
                (__attribute__((address_space(3))) void*)&lA[buf][e8 * 8], 16, 0, 0);
        }
        #pragma unroll
        for (int r = 0; r < 4; ++r) {
            int e8  = r * 512 + tid;
            int row = e8 >> 3, slot = e8 & 7;
            int ls  = slot ^ (row & 7);
            const ushort_t* gb = BT + (size_t)(n0 + row) * ldb + k0 + ls * 8;
            __builtin_amdgcn_global_load_lds(
                (const __attribute__((address_space(1))) void*)gb,
                (__attribute__((address_space(3))) void*)&lB[buf][e8 * 8], 16, 0, 0);
        }
    };

    stage(0, 0);
    __syncthreads();

    int cur = 0;
    for (int kt = 0; kt < nkt; ++kt) {
        if (kt + 1 < nkt) stage(cur ^ 1, kt + 1);   // prefetch overlaps compute
        __builtin_amdgcn_sched_barrier(0);          // keep loads issued early
        #pragma unroll
        for (int ks = 0; ks < 2; ++ks) {
            s16x8 af[8], bfr[4];
            #pragma unroll
            for (int mf = 0; mf < 8; ++mf) {
                int row = wm * 128 + mf * 16 + lr;
                int sl  = (lg + ks * 4) ^ (row & 7);
                af[mf] = *(const s16x8*)&lA[cur][row * 64 + sl * 8];
            }
            #pragma unroll
            for (int nf = 0; nf < 4; ++nf) {
                int row = wn * 64 + nf * 16 + lr;
                int sl  = (lg + ks * 4) ^ (row & 7);
                bfr[nf] = *(const s16x8*)&lB[cur][row * 64 + sl * 8];
            }
            __builtin_amdgcn_s_setprio(1);
            #pragma unroll
            for (int mf = 0; mf < 8; ++mf)
                #pragma unroll
                for (int nf = 0; nf < 4; ++nf)
                    acc[mf][nf] = __builtin_amdgcn_mfma_f32_16x16x32_bf16(
                        af[mf], bfr[nf], acc[mf][nf], 0, 0, 0);
            __builtin_amdgcn_s_setprio(0);
        }
        __syncthreads();                            // vmcnt(0)+lgkmcnt(0)+barrier
        cur ^= 1;
    }

    float*    Cf = (float*)Cv;
    ushort_t* Cb = (ushort_t*)Cv;
    #pragma unroll
    for (int mf = 0; mf < 8; ++mf) {
        int gm0 = m0 + wm * 128 + mf * 16 + lg * 4;
        #pragma unroll
        for (int nf = 0; nf < 4; ++nf) {
            int gn = n0 + wn * 64 + nf * 16 + lr;
            float bv = bias ? bias[gn] : 0.f;
            #pragma unroll
            for (int j = 0; j < 4; ++j) {
                float v = acc[mf][nf][j] + bv;
                if (GELU) v = 0.5f * v * (1.0f + erff(v * 0.70710678118f));
                size_t ci = (size_t)(gm0 + j) * ldc + gn;
                if (OUTBF) Cb[ci] = f2bf(v);
                else       Cf[ci] = v;
            }
        }
    }
}

// =====================================================================
// gemm_bt: 128x128xBK32, now 2-phase double-buffered + 4-slot XOR swizzle.
// Used for N=1024 GEMMs (Wo, FFN2) where a 256^2 grid would underfill.
// =====================================================================
template<bool GELU, bool RES, bool OUTBF>
__global__ __launch_bounds__(256)
void gemm_bt(const ushort_t* __restrict__ A, int lda,
             const ushort_t* __restrict__ BT, int ldb,
             void* __restrict__ Cv, int ldc,
             const float* __restrict__ bias,
             const float* __restrict__ res,
             int M, int N, int K)
{
    const int BK = 32;
    int m0 = blockIdx.x * 128;
    int n0 = blockIdx.y * 128;

    __shared__ __align__(16) ushort_t lA[2][128 * BK];
    __shared__ __align__(16) ushort_t lB[2][128 * BK];

    int tid  = threadIdx.x;
    int lane = tid & 63;
    int wave = tid >> 6;
    int lr = lane & 15, lg = lane >> 4;
    int wr = wave >> 1, wc = wave & 1;

    f32x4 acc[4][4] = {};
    int nkt = K / BK;

    auto stage = [&](int buf, int kt) {
        int k0 = kt * BK;
        #pragma unroll
        for (int i = 0; i < 2; ++i) {
            int e8  = i * 256 + tid;
            int row = e8 >> 2, slot = e8 & 3;
            int ls  = slot ^ (row & 3);
            const ushort_t* g = A + (size_t)(m0 + row) * lda + k0 + ls * 8;
            __builtin_amdgcn_global_load_lds(
                (const __attribute__((address_space(1))) void*)g,
                (__attribute__((address_space(3))) void*)&lA[buf][e8 * 8], 16, 0, 0);
        }
        #pragma unroll
        for (int i = 0; i < 2; ++i) {
            int e8  = i * 256 + tid;
            int row = e8 >> 2, slot = e8 & 3;
            int ls  = slot ^ (row & 3);
            const ushort_t* g = BT + (size_t)(n0 + row) * ldb + k0 + ls * 8;
            __builtin_amdgcn_global_load_lds(
                (const __attribute__((address_space(1))) void*)g,
                (__attribute__((address_space(3))) void*)&lB[buf][e8 * 8], 16, 0, 0);
        }
    };

    stage(0, 0);
    __syncthreads();

    int cur = 0;
    for (int kt = 0; kt < nkt; ++kt) {
        if (kt + 1 < nkt) stage(cur ^ 1, kt + 1);
        __builtin_amdgcn_sched_barrier(0);
        s16x8 af[4], bfr[4];
        #pragma unroll
        for (int m = 0; m < 4; ++m) {
            int row = wr * 64 + m * 16 + lr;
            int sl  = lg ^ (row & 3);
            af[m] = *(const s16x8*)&lA[cur][row * BK + sl * 8];
        }
        #pragma unroll
        for (int n = 0; n < 4; ++n) {
            int row = wc * 64 + n * 16 + lr;
            int sl  = lg ^ (row & 3);
            bfr[n] = *(const s16x8*)&lB[cur][row * BK + sl * 8];
        }
        #pragma unroll
        for (int m = 0; m < 4; ++m)
            #pragma unroll
            for (int n = 0; n < 4; ++n)
                acc[m][n] = __builtin_amdgcn_mfma_f32_16x16x32_bf16(
                    af[m], bfr[n], acc[m][n], 0, 0, 0);
        __syncthreads();
        cur ^= 1;
    }

    float*    Cf = (float*)Cv;
    ushort_t* Cb = (ushort_t*)Cv;
    #pragma unroll
    for (int m = 0; m < 4; ++m) {
        int gm0 = m0 + wr * 64 + m * 16 + lg * 4;
        #pragma unroll
        for (int n = 0; n < 4; ++n) {
            int gn = n0 + wc * 64 + n * 16 + lr;
            #pragma unroll
            for (int j = 0; j < 4; ++j) {
                float v = acc[m][n][j];
                if (bias) v += bias[gn];
                size_t ci = (size_t)(gm0 + j) * ldc + gn;
                if (RES)  v += res[ci];
                if (GELU) v = 0.5f * v * (1.0f + erff(v * 0.70710678118f));
                if (OUTBF) Cb[ci] = f2bf(v);
                else       Cf[ci] = v;
            }
        }
    }
}

// =====================================================================
// Flash attention: one block = (b,h) x 64-row Q tile. 4 waves.
// =====================================================================
__global__ __launch_bounds__(256)
void flash_attn(const ushort_t* __restrict__ qkv,
                const ushort_t* __restrict__ vt,
                ushort_t* __restrict__ ctx)
{
    const int QB = 64, KB = 64;
    int z  = blockIdx.y;            // b*H + h
    int b  = z >> 4, hh = z & 15;
    int q0 = blockIdx.x * QB;

    __shared__ __align__(16) ushort_t Qs[QB * 64];
    __shared__ __align__(16) ushort_t Ks[KB * 64];
    __shared__ __align__(16) ushort_t Vs[64 * KB];     // rows = d
    __shared__ float    Ss[QB][68];
    __shared__ __align__(16) ushort_t Ps[QB][72];
    __shared__ float mrow[QB], lrow[QB], arow[QB];

    int tid  = threadIdx.x;
    int lane = tid & 63, wave = tid >> 6;
    int lr = lane & 15, lg = lane >> 4;

    if (tid < QB) { mrow[tid] = -1e30f; lrow[tid] = 0.f; }

    const ushort_t* qbase = qkv + (size_t)(b * S_ + q0) * 3072 + hh * HD_;
    #pragma unroll
    for (int rnd = 0; rnd < 2; ++rnd) {
        int e8   = rnd * 256 + tid;
        int row  = e8 >> 3;
        int slot = e8 & 7;
        int ls   = slot ^ (row & 7);
        const ushort_t* g = qbase + (size_t)row * 3072 + ls * 8;
        __builtin_amdgcn_global_load_lds(
            (const __attribute__((address_space(1))) void*)g,
            (__attribute__((address_space(3))) void*)&Qs[e8 * 8], 16, 0, 0);
    }
    __syncthreads();

    s16x8 qa[4][2];
    #pragma unroll
    for (int mf = 0; mf < 4; ++mf)
        #pragma unroll
        for (int ks = 0; ks < 2; ++ks) {
            int row = mf * 16 + lr;
            int sl  = (lg + ks * 4) ^ (row & 7);
            qa[mf][ks] = *(const s16x8*)&Qs[row * 64 + sl * 8];
        }

    f32x4 acc[4] = {};
    int r = tid >> 2, p = tid & 3;

    int kv_end = q0 + QB;
    for (int kv0 = 0; kv0 < kv_end; kv0 += KB) {
        const ushort_t* kbase = qkv + (size_t)(b * S_ + kv0) * 3072 + 1024 + hh * HD_;
        const ushort_t* vbase = vt + (size_t)z * HD_ * S_ + kv0;
        #pragma unroll
        for (int rnd = 0; rnd < 2; ++rnd) {
            int e8 = rnd * 256 + tid;
            int row = e8 >> 3, slot = e8 & 7;
            int ls = slot ^ (row & 7);
            const ushort_t* gk = kbase + (size_t)row * 3072 + ls * 8;
            __builtin_amdgcn_global_load_lds(
                (const __attribute__((address_space(1))) void*)gk,
                (__attribute__((address_space(3))) void*)&Ks[e8 * 8], 16, 0, 0);
            const ushort_t* gv = vbase + (size_t)row * S_ + ls * 8;
            __builtin_amdgcn_global_load_lds(
                (const __attribute__((address_space(1))) void*)gv,
                (__attribute__((address_space(3))) void*)&Vs[e8 * 8], 16, 0, 0);
        }
        __syncthreads();

        s16x8 kb[2];
        #pragma unroll
        for (int ks = 0; ks < 2; ++ks) {
            int row = wave * 16 + lr;
            int sl  = (lg + ks * 4) ^ (row & 7);
            kb[ks] = *(const s16x8*)&Ks[row * 64 + sl * 8];
        }
        f32x4 sa[4] = {};
        #pragma unroll
        for (int mf = 0; mf < 4; ++mf)
            #pragma unroll
            for (int ks = 0; ks < 2; ++ks)
                sa[mf] = __builtin_amdgcn_mfma_f32_16x16x32_bf16(
                    qa[mf][ks], kb[ks], sa[mf], 0, 0, 0);

        int ki = kv0 + wave * 16 + lr;
        #pragma unroll
        for (int mf = 0; mf < 4; ++mf)
            #pragma unroll
            for (int j = 0; j < 4; ++j) {
                int qi = q0 + mf * 16 + lg * 4 + j;
                float s = (ki <= qi) ? sa[mf][j] * 0.125f : -1e30f;
                Ss[mf * 16 + lg * 4 + j][wave * 16 + lr] = s;
            }
        __syncthreads();

        float mo = mrow[r];
        float sv[16];
        float pm = -1e30f;
        #pragma unroll
        for (int i = 0; i < 16; ++i) {
            sv[i] = Ss[r][p * 16 + i];
            pm = fmaxf(pm, sv[i]);
        }
        pm = fmaxf(pm, __shfl_xor(pm, 1, 64));
        pm = fmaxf(pm, __shfl_xor(pm, 2, 64));
        float M = fmaxf(mo, pm);
        float sum = 0.f;
        s16x8 pk0, pk1;
        #pragma unroll
        for (int i = 0; i < 8; ++i) {
            float e0 = __expf(sv[i] - M);
            float e1 = __expf(sv[i + 8] - M);
            sum += e0 + e1;
            pk0[i] = (short)f2bf(e0);
            pk1[i] = (short)f2bf(e1);
        }
        *(s16x8*)&Ps[r][p * 16]     = pk0;
        *(s16x8*)&Ps[r][p * 16 + 8] = pk1;
        sum += __shfl_xor(sum, 1, 64);
        sum += __shfl_xor(sum, 2, 64);
        if (p == 0) {
            float al = __expf(mo - M);
            arow[r] = al;
            mrow[r] = M;
            lrow[r] = lrow[r] * al + sum;
        }
        __syncthreads();

        #pragma unroll
        for (int mf = 0; mf < 4; ++mf) {
            #pragma unroll
            for (int j = 0; j < 4; ++j)
                acc[mf][j] *= arow[mf * 16 + lg * 4 + j];
        }
        s16x8 vb[2];
        #pragma unroll
        for (int ks = 0; ks < 2; ++ks) {
            int row = wave * 16 + lr;
            int sl  = (lg + ks * 4) ^ (row & 7);
            vb[ks] = *(const s16x8*)&Vs[row * 64 + sl * 8];
        }
        #pragma unroll
        for (int mf = 0; mf < 4; ++mf)
            #pragma unroll
            for (int ks = 0; ks < 2; ++ks) {
                s16x8 pa = *(const s16x8*)((const char*)&Ps[0][0]
                            + (mf * 16 + lr) * 144 + lg * 16 + ks * 64);
                acc[mf] = __builtin_amdgcn_mfma_f32_16x16x32_bf16(
                    pa, vb[ks], acc[mf], 0, 0, 0);
            }
        __syncthreads();
    }

    #pragma unroll
    for (int mf = 0; mf < 4; ++mf)
        #pragma unroll
        for (int j = 0; j < 4; ++j) {
            int rr = mf * 16 + lg * 4 + j;
            float o = acc[mf][j] / lrow[rr];
            ctx[(size_t)(b * S_ + q0 + rr) * D_ + hh * HD_ + wave * 16 + lr] = f2bf(o);
        }
}

// ---- f32 [R,C] -> bf16 [C,R] transpose-convert ----
__global__ __launch_bounds__(256)
void tconv(const float* __restrict__ in, ushort_t* __restrict__ out, int R, int C)
{
    __shared__ float t[32][33];
    int c0 = blockIdx.x * 32, r0 = blockIdx.y * 32;
    int tx = threadIdx.x & 31, ty = threadIdx.x >> 5;
    #pragma unroll
    for (int i = 0; i < 4; ++i)
        t[ty + i * 8][tx] = in[(size_t)(r0 + ty + i * 8) * C + c0 + tx];
    __syncthreads();
    #pragma unroll
    for (int i = 0; i < 4; ++i)
        out[(size_t)(c0 + ty + i * 8) * R + r0 + tx] = f2bf(t[tx][ty + i * 8]);
}

// ---- per-head V transpose: v (qkv cols 2048..3071) -> vt[BH][HD][S] ----
__global__ __launch_bounds__(256)
void vtrans(const ushort_t* __restrict__ v, ushort_t* __restrict__ vt)
{
    int z = blockIdx.z, b = z >> 4, h = z & 15;
    int s0 = blockIdx.x * 32, d0 = blockIdx.y * 32;
    __shared__ ushort_t t[32][33];
    int tx = threadIdx.x & 31, ty = threadIdx.x >> 5;
    #pragma unroll
    for (int i = 0; i < 4; ++i)
        t[ty + i * 8][tx] = v[(size_t)(b * S_ + s0 + ty + i * 8) * 3072 + h * HD_ + d0 + tx];
    __syncthreads();
    #pragma unroll
    for (int i = 0; i < 4; ++i)
        vt[((size_t)z * HD_ + d0 + ty + i * 8) * S_ + s0 + tx] = t[tx][ty + i * 8];
}

// ---- embedding * sqrt(D) + sinusoidal PE -> x (f32) ----
__global__ __launch_bounds__(256)
void embed_pe(const int* __restrict__ ids, const float* __restrict__ emb,
              float* __restrict__ x)
{
    int row = blockIdx.x;
    int s   = row & (S_ - 1);
    int id  = ids[row];
    int d   = threadIdx.x * 4;
    f32x4 ev = *(const f32x4*)&emb[(size_t)id * D_ + d];
    f32x4 o;
    #pragma unroll
    for (int j = 0; j < 4; ++j) {
        int dd = d + j;
        int i  = dd >> 1;
        float div = expf(-(float)(2 * i) * (9.210340371976184f / 1024.0f));
        float arg = (float)s * div;
        float pe  = (dd & 1) ? cosf(arg) : sinf(arg);
        o[j] = ev[j] * 32.0f + pe;
    }
    *(f32x4*)&x[(size_t)row * D_ + d] = o;
}

// ---- LayerNorm row kernel: f32 in -> bf16 out ----
__global__ __launch_bounds__(256)
void ln_kernel(const float* __restrict__ x, const float* __restrict__ g,
               const float* __restrict__ b, ushort_t* __restrict__ out)
{
    __shared__ float sb[4];
    int row = blockIdx.x;
    const float* xr = x + (size_t)row * D_;
    int c = threadIdx.x * 4;
    f32x4 v = *(const f32x4*)&xr[c];
    float s = v[0] + v[1] + v[2] + v[3];
    s = blk_sum(s, sb);
    float mean = s * (1.0f / D_);
    f32x4 dv = v - mean;
    float sq = dv[0]*dv[0] + dv[1]*dv[1] + dv[2]*dv[2] + dv[3]*dv[3];
    sq = blk_sum(sq, sb);
    float rstd = rsqrtf(sq * (1.0f / D_) + EPSLN);
    u16x4 o;
    #pragma unroll
    for (int j = 0; j < 4; ++j)
        o[j] = f2bf(dv[j] * rstd * g[c + j] + b[c + j]);
    *(u16x4*)&out[(size_t)row * D_ + c] = o;
}

// ---- concat qkv bias ----
__global__ __launch_bounds__(256)
void bias_cat(const float* __restrict__ bq, const float* __restrict__ bk,
              const float* __restrict__ bv, float* __restrict__ o)
{
    int i = blockIdx.x * 256 + threadIdx.x;
    if (i < 1024)       o[i] = bq[i];
    else if (i < 2048)  o[i] = bk[i - 1024];
    else                o[i] = bv[i - 2048];
}

__global__ void ws_marker(float* o) { o[threadIdx.x] = -777777.0f; }

// =====================================================================
extern "C" void kernel_launch(void* const* d_in, const int* in_sizes, int n_in,
                              void* d_out, int out_size, void* d_ws, size_t ws_size,
                              hipStream_t stream)
{
    (void)in_sizes; (void)n_in; (void)out_size;
    const int*   ids  = (const int*)d_in[0];
    const float* emb  = (const float*)d_in[1];
    const float* Wq   = (const float*)d_in[2];
    const float* bq   = (const float*)d_in[3];
    const float* Wk   = (const float*)d_in[4];
    const float* bk   = (const float*)d_in[5];
    const float* Wv   = (const float*)d_in[6];
    const float* bv   = (const float*)d_in[7];
    const float* Wo   = (const float*)d_in[8];
    const float* bo   = (const float*)d_in[9];
    const float* ln1g = (const float*)d_in[10];
    const float* ln1b = (const float*)d_in[11];
    const float* ln2g = (const float*)d_in[12];
    const float* ln2b = (const float*)d_in[13];
    const float* W1   = (const float*)d_in[14];
    const float* b1   = (const float*)d_in[15];
    const float* W2   = (const float*)d_in[16];
    const float* b2   = (const float*)d_in[17];
    const float* fng  = (const float*)d_in[18];
    const float* fnb  = (const float*)d_in[19];
    const float* Wout = (const float*)d_in[20];
    const float* bout = (const float*)d_in[21];
    float* out = (float*)d_out;

    // ---- workspace layout ----
    char* base = (char*)d_ws;
    size_t off = 0;
    float*    x    = (float*)(base + off);    off += (size_t)MTOK * D_ * 4;
    ushort_t* h    = (ushort_t*)(base + off); off += (size_t)MTOK * D_ * 2;
    ushort_t* qkv  = (ushort_t*)(base + off); off += (size_t)MTOK * 3 * D_ * 2;
    ushort_t* vt   = (ushort_t*)(base + off); off += (size_t)B_ * H_ * HD_ * S_ * 2;
    ushort_t* ctx  = (ushort_t*)(base + off); off += (size_t)MTOK * D_ * 2;
    ushort_t* ff   = (ushort_t*)(base + off); off += (size_t)MTOK * F_ * 2;
    float*    qkvb = (float*)(base + off);    off += 3072 * 4;
    ushort_t* wqkvT= (ushort_t*)(base + off); off += (size_t)3 * D_ * D_ * 2;
    ushort_t* woT  = (ushort_t*)(base + off); off += (size_t)D_ * D_ * 2;
    ushort_t* w1T  = (ushort_t*)(base + off); off += (size_t)D_ * F_ * 2;
    ushort_t* w2T  = (ushort_t*)(base + off); off += (size_t)F_ * D_ * 2;
    ushort_t* wouT = (ushort_t*)(base + off); off += (size_t)V_ * D_ * 2;
    if (ws_size < off) { ws_marker<<<1, 64, 0, stream>>>(out); return; }

    embed_pe<<<MTOK, 256, 0, stream>>>(ids, emb, x);

    for (int i = 0; i < L_; ++i) {
        tconv<<<dim3(32, 32),  256, 0, stream>>>(Wq + (size_t)i * D_ * D_, wqkvT, D_, D_);
        tconv<<<dim3(32, 32),  256, 0, stream>>>(Wk + (size_t)i * D_ * D_, wqkvT + (size_t)D_ * D_, D_, D_);
        tconv<<<dim3(32, 32),  256, 0, stream>>>(Wv + (size_t)i * D_ * D_, wqkvT + (size_t)2 * D_ * D_, D_, D_);
        tconv<<<dim3(32, 32),  256, 0, stream>>>(Wo + (size_t)i * D_ * D_, woT, D_, D_);
        tconv<<<dim3(128, 32), 256, 0, stream>>>(W1 + (size_t)i * D_ * F_, w1T, D_, F_);
        tconv<<<dim3(32, 128), 256, 0, stream>>>(W2 + (size_t)i * F_ * D_, w2T, F_, D_);
        bias_cat<<<12, 256, 0, stream>>>(bq + i * D_, bk + i * D_, bv + i * D_, qkvb);

        ln_kernel<<<MTOK, 256, 0, stream>>>(x, ln1g + i * D_, ln1b + i * D_, h);

        // qkv = h @ [Wq|Wk|Wv] + bias   (M=2048, N=3072, K=1024)
        gemm256<false,true><<<dim3(8, 12), 512, 0, stream>>>(
            h, D_, wqkvT, D_, qkv, 3 * D_, qkvb, MTOK, 3 * D_, D_);

        vtrans<<<dim3(32, 2, B_ * H_), 256, 0, stream>>>(qkv + 2 * D_, vt);

        flash_attn<<<dim3(S_ / 64, B_ * H_), 256, 0, stream>>>(qkv, vt, ctx);

        // x = x + ctx @ Wo + bo
        gemm_bt<false,true,false><<<dim3(16, 8), 256, 0, stream>>>(
            ctx, D_, woT, D_, x, D_, bo + i * D_, x, MTOK, D_, D_);

        ln_kernel<<<MTOK, 256, 0, stream>>>(x, ln2g + i * D_, ln2b + i * D_, h);

        // ff = gelu(h @ W1 + b1)
        gemm256<true,true><<<dim3(8, 16), 512, 0, stream>>>(
            h, D_, w1T, D_, ff, F_, b1 + i * F_, MTOK, F_, D_);

        // x = x + ff @ W2 + b2
        gemm_bt<false,true,false><<<dim3(16, 8), 256, 0, stream>>>(
            ff, F_, w2T, F_, x, D_, b2 + i * D_, x, MTOK, D_, F_);
    }

    ln_kernel<<<MTOK, 256, 0, stream>>>(x, fng, fnb, h);
    tconv<<<dim3(1000, 32), 256, 0, stream>>>(Wout, wouT, D_, V_);
    gemm256<false,false><<<dim3(8, 125), 512, 0, stream>>>(
        h, D_, wouT, D_, out, V_, bout, MTOK, V_, D_);
}

// Round 4
// 1968.100 us; speedup vs baseline: 1.4188x; 1.0571x over previous
//
#include <hip/hip_runtime.h>
#include <math.h>

// ---- problem constants ----
#define V_   32000
#define D_   1024
#define H_   16
#define HD_  64
#define L_   6
#define F_   4096
#define S_   1024
#define B_   2
#define MTOK (B_*S_)      // 2048
#define EPSLN 1e-5f

typedef unsigned short ushort_t;
typedef __attribute__((ext_vector_type(8))) short  s16x8;
typedef __attribute__((ext_vector_type(4))) float  f32x4;
typedef __attribute__((ext_vector_type(4))) unsigned short u16x4;

// ---- bf16 helpers (raw ushort) ----
__device__ __forceinline__ float bf2f(unsigned short u) {
    unsigned int x = ((unsigned int)u) << 16;
    return __builtin_bit_cast(float, x);
}
__device__ __forceinline__ unsigned short f2bf(float f) {
    unsigned int x = __builtin_bit_cast(unsigned int, f);
    unsigned int r = (x + 0x7FFFu + ((x >> 16) & 1u)) >> 16;   // RNE
    return (unsigned short)r;
}

// ---- block reductions (256 threads = 4 waves of 64) ----
__device__ __forceinline__ float blk_sum(float v, float* sb) {
    #pragma unroll
    for (int o = 32; o; o >>= 1) v += __shfl_xor(v, o, 64);
    int w = threadIdx.x >> 6;
    __syncthreads();
    if ((threadIdx.x & 63) == 0) sb[w] = v;
    __syncthreads();
    return sb[0] + sb[1] + sb[2] + sb[3];
}

// =====================================================================
// gemm256: 4-phase pipelined 256x256xBK64 bf16 MFMA GEMM (T3+T4+T2+T5).
// C = epi( A[M,K] @ BT[N,K]^T + bias ). 512 thr = 8 waves (2M x 4N),
// per-wave 128x64 out (8x4 frags). LDS 128 KiB double-buffered.
// Per K-tile u: 4 phases x {ds_read subtile | stage half-tile | barrier |
// lgkm0 | 16 MFMA | barrier}; vmcnt(4) once per tile (counted, not 0).
// Stage plan (liveness-checked): P1->Alo(u+1), P2->Ahi(u+1) [nxt buf],
// P3->Blo(u+2), P4->Bhi(u+2) [cur buf, released after P2].
// XOR swizzle slot^=(row&7): pre-swizzled global src + swizzled ds_read.
// =====================================================================
template<bool GELU, bool OUTBF>
__global__ __launch_bounds__(512, 2)
void gemm256(const ushort_t* __restrict__ A, int lda,
             const ushort_t* __restrict__ BT, int ldb,
             void* __restrict__ Cv, int ldc,
             const float* __restrict__ bias,
             int M, int N, int K)
{
    int nmt = M >> 8;
    int nwg = gridDim.x * gridDim.y;
    int id  = blockIdx.x + gridDim.x * blockIdx.y;
    int swz = ((nwg & 7) == 0) ? ((id & 7) * (nwg >> 3) + (id >> 3)) : id;
    int m0 = (swz % nmt) << 8;
    int n0 = (swz / nmt) << 8;

    __shared__ __align__(16) ushort_t lA[2][256 * 64];
    __shared__ __align__(16) ushort_t lB[2][256 * 64];

    int tid  = threadIdx.x;
    int lane = tid & 63, wave = tid >> 6;
    int lr = lane & 15, lg = lane >> 4;
    int wm = wave >> 2, wn = wave & 3;

    f32x4 acc[8][4] = {};
    int nkt = K >> 6;

    // stage one half-tile: sel 0=Alo 1=Ahi 2=Blo 3=Bhi (128 rows x 64 k)
    auto stageu = [&](int buf, int kt, int sel) {
        int k0 = kt << 6;
        const ushort_t* src = (sel < 2) ? A : BT;
        int ld    = (sel < 2) ? lda : ldb;
        int rbase = ((sel < 2) ? m0 : n0) + ((sel & 1) << 7);
        ushort_t* dst = ((sel < 2) ? &lA[buf][0] : &lB[buf][0]) + ((sel & 1) << 13);
        #pragma unroll
        for (int r = 0; r < 2; ++r) {
            int e8  = r * 512 + tid;           // 0..1023 (16B units)
            int row = e8 >> 3, slot = e8 & 7;
            int ls  = slot ^ (row & 7);
            const ushort_t* g = src + (size_t)(rbase + row) * ld + k0 + ls * 8;
            __builtin_amdgcn_global_load_lds(
                (const __attribute__((address_space(1))) void*)g,
                (__attribute__((address_space(3))) void*)(dst + e8 * 8), 16, 0, 0);
        }
    };
    auto rdA = [&](int buf, int row, int ks) -> s16x8 {
        int sl = (lg + ks * 4) ^ (row & 7);
        return *(const s16x8*)&lA[buf][row * 64 + sl * 8];
    };
    auto rdB = [&](int buf, int row, int ks) -> s16x8 {
        int sl = (lg + ks * 4) ^ (row & 7);
        return *(const s16x8*)&lB[buf][row * 64 + sl * 8];
    };

    // ---- prologue: tile0 fully + B halves of tile1; first 8 loads must land
    stageu(0, 0, 0); stageu(0, 0, 1); stageu(0, 0, 2); stageu(0, 0, 3);
    if (nkt > 1) {
        stageu(1, 1, 2); stageu(1, 1, 3);
        asm volatile("s_waitcnt vmcnt(4)" ::: "memory");
    } else {
        asm volatile("s_waitcnt vmcnt(0)" ::: "memory");
    }
    __builtin_amdgcn_sched_barrier(0);
    __builtin_amdgcn_s_barrier();

    for (int u = 0; u < nkt; ++u) {
        int cur = u & 1, nxt = cur ^ 1;
        s16x8 af0[4][2], af1[4][2], bf0[2][2], bf1[2][2];

        // ---- P1: read af0 (A rows wm*128+[0,64)) + bf0 (B rows wn*64+[0,32))
        #pragma unroll
        for (int mf = 0; mf < 4; ++mf)
            #pragma unroll
            for (int ks = 0; ks < 2; ++ks)
                af0[mf][ks] = rdA(cur, wm * 128 + mf * 16 + lr, ks);
        #pragma unroll
        for (int nf = 0; nf < 2; ++nf)
            #pragma unroll
            for (int ks = 0; ks < 2; ++ks)
                bf0[nf][ks] = rdB(cur, wn * 64 + nf * 16 + lr, ks);
        if (u + 1 < nkt) stageu(nxt, u + 1, 0);
        __builtin_amdgcn_s_barrier();
        asm volatile("s_waitcnt lgkmcnt(0)" ::: "memory");
        __builtin_amdgcn_sched_barrier(0);
        __builtin_amdgcn_s_setprio(1);
        #pragma unroll
        for (int mf = 0; mf < 4; ++mf)
            #pragma unroll
            for (int nf = 0; nf < 2; ++nf)
                #pragma unroll
                for (int ks = 0; ks < 2; ++ks)
                    acc[mf][nf] = __builtin_amdgcn_mfma_f32_16x16x32_bf16(
                        af0[mf][ks], bf0[nf][ks], acc[mf][nf], 0, 0, 0);
        __builtin_amdgcn_s_setprio(0);
        __builtin_amdgcn_s_barrier();

        // ---- P2: read bf1 (B rows wn*64+32+[0,32))
        #pragma unroll
        for (int nf = 0; nf < 2; ++nf)
            #pragma unroll
            for (int ks = 0; ks < 2; ++ks)
                bf1[nf][ks] = rdB(cur, wn * 64 + 32 + nf * 16 + lr, ks);
        if (u + 1 < nkt) stageu(nxt, u + 1, 1);
        __builtin_amdgcn_s_barrier();
        asm volatile("s_waitcnt lgkmcnt(0)" ::: "memory");
        __builtin_amdgcn_sched_barrier(0);
        __builtin_amdgcn_s_setprio(1);
        #pragma unroll
        for (int mf = 0; mf < 4; ++mf)
            #pragma unroll
            for (int nf = 0; nf < 2; ++nf)
                #pragma unroll
                for (int ks = 0; ks < 2; ++ks)
                    acc[mf][2 + nf] = __builtin_amdgcn_mfma_f32_16x16x32_bf16(
                        af0[mf][ks], bf1[nf][ks], acc[mf][2 + nf], 0, 0, 0);
        __builtin_amdgcn_s_setprio(0);
        __builtin_amdgcn_s_barrier();

        // ---- P3: read af1 (A rows wm*128+64+[0,64))
        #pragma unroll
        for (int mf = 0; mf < 4; ++mf)
            #pragma unroll
            for (int ks = 0; ks < 2; ++ks)
                af1[mf][ks] = rdA(cur, wm * 128 + 64 + mf * 16 + lr, ks);
        if (u + 2 < nkt) stageu(cur, u + 2, 2);    // Blo released after P2
        __builtin_amdgcn_s_barrier();
        asm volatile("s_waitcnt lgkmcnt(0)" ::: "memory");
        __builtin_amdgcn_sched_barrier(0);
        __builtin_amdgcn_s_setprio(1);
        #pragma unroll
        for (int mf = 0; mf < 4; ++mf)
            #pragma unroll
            for (int nf = 0; nf < 2; ++nf)
                #pragma unroll
                for (int ks = 0; ks < 2; ++ks)
                    acc[4 + mf][2 + nf] = __builtin_amdgcn_mfma_f32_16x16x32_bf16(
                        af1[mf][ks], bf1[nf][ks], acc[4 + mf][2 + nf], 0, 0, 0);
        __builtin_amdgcn_s_setprio(0);
        __builtin_amdgcn_s_barrier();

        // ---- P4: no new ds_read (bf0 held in regs); stage Bhi(u+2)
        if (u + 2 < nkt) stageu(cur, u + 2, 3);    // Bhi released after P2
        __builtin_amdgcn_s_barrier();
        __builtin_amdgcn_s_setprio(1);
        #pragma unroll
        for (int mf = 0; mf < 4; ++mf)
            #pragma unroll
            for (int nf = 0; nf < 2; ++nf)
                #pragma unroll
                for (int ks = 0; ks < 2; ++ks)
                    acc[4 + mf][nf] = __builtin_amdgcn_mfma_f32_16x16x32_bf16(
                        af1[mf][ks], bf0[nf][ks], acc[4 + mf][nf], 0, 0, 0);
        __builtin_amdgcn_s_setprio(0);
        // counted wait: tile u+1 fully resident; <=4 loads (tile u+2 B) in flight
        if (u + 2 < nkt) asm volatile("s_waitcnt vmcnt(4)" ::: "memory");
        else             asm volatile("s_waitcnt vmcnt(0)" ::: "memory");
        __builtin_amdgcn_sched_barrier(0);
        __builtin_amdgcn_s_barrier();
    }

    float*    Cf = (float*)Cv;
    ushort_t* Cb = (ushort_t*)Cv;
    #pragma unroll
    for (int mf = 0; mf < 8; ++mf) {
        int gm0 = m0 + wm * 128 + mf * 16 + lg * 4;
        #pragma unroll
        for (int nf = 0; nf < 4; ++nf) {
            int gn = n0 + wn * 64 + nf * 16 + lr;
            float bv = bias ? bias[gn] : 0.f;
            #pragma unroll
            for (int j = 0; j < 4; ++j) {
                float v = acc[mf][nf][j] + bv;
                if (GELU) v = 0.5f * v * (1.0f + erff(v * 0.70710678118f));
                size_t ci = (size_t)(gm0 + j) * ldc + gn;
                if (OUTBF) Cb[ci] = f2bf(v);
                else       Cf[ci] = v;
            }
        }
    }
}

// =====================================================================
// gemm_bt: 128x128xBK32, 2-phase double-buffered + 4-slot XOR swizzle.
// Used for N=1024 GEMMs (Wo, FFN2).
// =====================================================================
template<bool GELU, bool RES, bool OUTBF>
__global__ __launch_bounds__(256)
void gemm_bt(const ushort_t* __restrict__ A, int lda,
             const ushort_t* __restrict__ BT, int ldb,
             void* __restrict__ Cv, int ldc,
             const float* __restrict__ bias,
             const float* __restrict__ res,
             int M, int N, int K)
{
    const int BK = 32;
    int m0 = blockIdx.x * 128;
    int n0 = blockIdx.y * 128;

    __shared__ __align__(16) ushort_t lA[2][128 * BK];
    __shared__ __align__(16) ushort_t lB[2][128 * BK];

    int tid  = threadIdx.x;
    int lane = tid & 63;
    int wave = tid >> 6;
    int lr = lane & 15, lg = lane >> 4;
    int wr = wave >> 1, wc = wave & 1;

    f32x4 acc[4][4] = {};
    int nkt = K / BK;

    auto stage = [&](int buf, int kt) {
        int k0 = kt * BK;
        #pragma unroll
        for (int i = 0; i < 2; ++i) {
            int e8  = i * 256 + tid;
            int row = e8 >> 2, slot = e8 & 3;
            int ls  = slot ^ (row & 3);
            const ushort_t* g = A + (size_t)(m0 + row) * lda + k0 + ls * 8;
            __builtin_amdgcn_global_load_lds(
                (const __attribute__((address_space(1))) void*)g,
                (__attribute__((address_space(3))) void*)&lA[buf][e8 * 8], 16, 0, 0);
        }
        #pragma unroll
        for (int i = 0; i < 2; ++i) {
            int e8  = i * 256 + tid;
            int row = e8 >> 2, slot = e8 & 3;
            int ls  = slot ^ (row & 3);
            const ushort_t* g = BT + (size_t)(n0 + row) * ldb + k0 + ls * 8;
            __builtin_amdgcn_global_load_lds(
                (const __attribute__((address_space(1))) void*)g,
                (__attribute__((address_space(3))) void*)&lB[buf][e8 * 8], 16, 0, 0);
        }
    };

    stage(0, 0);
    __syncthreads();

    int cur = 0;
    for (int kt = 0; kt < nkt; ++kt) {
        if (kt + 1 < nkt) stage(cur ^ 1, kt + 1);
        __builtin_amdgcn_sched_barrier(0);
        s16x8 af[4], bfr[4];
        #pragma unroll
        for (int m = 0; m < 4; ++m) {
            int row = wr * 64 + m * 16 + lr;
            int sl  = lg ^ (row & 3);
            af[m] = *(const s16x8*)&lA[cur][row * BK + sl * 8];
        }
        #pragma unroll
        for (int n = 0; n < 4; ++n) {
            int row = wc * 64 + n * 16 + lr;
            int sl  = lg ^ (row & 3);
            bfr[n] = *(const s16x8*)&lB[cur][row * BK + sl * 8];
        }
        #pragma unroll
        for (int m = 0; m < 4; ++m)
            #pragma unroll
            for (int n = 0; n < 4; ++n)
                acc[m][n] = __builtin_amdgcn_mfma_f32_16x16x32_bf16(
                    af[m], bfr[n], acc[m][n], 0, 0, 0);
        __syncthreads();
        cur ^= 1;
    }

    float*    Cf = (float*)Cv;
    ushort_t* Cb = (ushort_t*)Cv;
    #pragma unroll
    for (int m = 0; m < 4; ++m) {
        int gm0 = m0 + wr * 64 + m * 16 + lg * 4;
        #pragma unroll
        for (int n = 0; n < 4; ++n) {
            int gn = n0 + wc * 64 + n * 16 + lr;
            #pragma unroll
            for (int j = 0; j < 4; ++j) {
                float v = acc[m][n][j];
                if (bias) v += bias[gn];
                size_t ci = (size_t)(gm0 + j) * ldc + gn;
                if (RES)  v += res[ci];
                if (GELU) v = 0.5f * v * (1.0f + erff(v * 0.70710678118f));
                if (OUTBF) Cb[ci] = f2bf(v);
                else       Cf[ci] = v;
            }
        }
    }
}

// =====================================================================
// Flash attention: one block = (b,h) x 64-row Q tile. 4 waves.
// =====================================================================
__global__ __launch_bounds__(256)
void flash_attn(const ushort_t* __restrict__ qkv,
                const ushort_t* __restrict__ vt,
                ushort_t* __restrict__ ctx)
{
    const int QB = 64, KB = 64;
    int z  = blockIdx.y;            // b*H + h
    int b  = z >> 4, hh = z & 15;
    int q0 = blockIdx.x * QB;

    __shared__ __align__(16) ushort_t Qs[QB * 64];
    __shared__ __align__(16) ushort_t Ks[KB * 64];
    __shared__ __align__(16) ushort_t Vs[64 * KB];     // rows = d
    __shared__ float    Ss[QB][68];
    __shared__ __align__(16) ushort_t Ps[QB][72];
    __shared__ float mrow[QB], lrow[QB], arow[QB];

    int tid  = threadIdx.x;
    int lane = tid & 63, wave = tid >> 6;
    int lr = lane & 15, lg = lane >> 4;

    if (tid < QB) { mrow[tid] = -1e30f; lrow[tid] = 0.f; }

    const ushort_t* qbase = qkv + (size_t)(b * S_ + q0) * 3072 + hh * HD_;
    #pragma unroll
    for (int rnd = 0; rnd < 2; ++rnd) {
        int e8   = rnd * 256 + tid;
        int row  = e8 >> 3;
        int slot = e8 & 7;
        int ls   = slot ^ (row & 7);
        const ushort_t* g = qbase + (size_t)row * 3072 + ls * 8;
        __builtin_amdgcn_global_load_lds(
            (const __attribute__((address_space(1))) void*)g,
            (__attribute__((address_space(3))) void*)&Qs[e8 * 8], 16, 0, 0);
    }
    __syncthreads();

    s16x8 qa[4][2];
    #pragma unroll
    for (int mf = 0; mf < 4; ++mf)
        #pragma unroll
        for (int ks = 0; ks < 2; ++ks) {
            int row = mf * 16 + lr;
            int sl  = (lg + ks * 4) ^ (row & 7);
            qa[mf][ks] = *(const s16x8*)&Qs[row * 64 + sl * 8];
        }

    f32x4 acc[4] = {};
    int r = tid >> 2, p = tid & 3;

    int kv_end = q0 + QB;
    for (int kv0 = 0; kv0 < kv_end; kv0 += KB) {
        const ushort_t* kbase = qkv + (size_t)(b * S_ + kv0) * 3072 + 1024 + hh * HD_;
        const ushort_t* vbase = vt + (size_t)z * HD_ * S_ + kv0;
        #pragma unroll
        for (int rnd = 0; rnd < 2; ++rnd) {
            int e8 = rnd * 256 + tid;
            int row = e8 >> 3, slot = e8 & 7;
            int ls = slot ^ (row & 7);
            const ushort_t* gk = kbase + (size_t)row * 3072 + ls * 8;
            __builtin_amdgcn_global_load_lds(
                (const __attribute__((address_space(1))) void*)gk,
                (__attribute__((address_space(3))) void*)&Ks[e8 * 8], 16, 0, 0);
            const ushort_t* gv = vbase + (size_t)row * S_ + ls * 8;
            __builtin_amdgcn_global_load_lds(
                (const __attribute__((address_space(1))) void*)gv,
                (__attribute__((address_space(3))) void*)&Vs[e8 * 8], 16, 0, 0);
        }
        __syncthreads();

        s16x8 kb[2];
        #pragma unroll
        for (int ks = 0; ks < 2; ++ks) {
            int row = wave * 16 + lr;
            int sl  = (lg + ks * 4) ^ (row & 7);
            kb[ks] = *(const s16x8*)&Ks[row * 64 + sl * 8];
        }
        f32x4 sa[4] = {};
        #pragma unroll
        for (int mf = 0; mf < 4; ++mf)
            #pragma unroll
            for (int ks = 0; ks < 2; ++ks)
                sa[mf] = __builtin_amdgcn_mfma_f32_16x16x32_bf16(
                    qa[mf][ks], kb[ks], sa[mf], 0, 0, 0);

        int ki = kv0 + wave * 16 + lr;
        #pragma unroll
        for (int mf = 0; mf < 4; ++mf)
            #pragma unroll
            for (int j = 0; j < 4; ++j) {
                int qi = q0 + mf * 16 + lg * 4 + j;
                float s = (ki <= qi) ? sa[mf][j] * 0.125f : -1e30f;
                Ss[mf * 16 + lg * 4 + j][wave * 16 + lr] = s;
            }
        __syncthreads();

        float mo = mrow[r];
        float sv[16];
        float pm = -1e30f;
        #pragma unroll
        for (int i = 0; i < 16; ++i) {
            sv[i] = Ss[r][p * 16 + i];
            pm = fmaxf(pm, sv[i]);
        }
        pm = fmaxf(pm, __shfl_xor(pm, 1, 64));
        pm = fmaxf(pm, __shfl_xor(pm, 2, 64));
        float M = fmaxf(mo, pm);
        float sum = 0.f;
        s16x8 pk0, pk1;
        #pragma unroll
        for (int i = 0; i < 8; ++i) {
            float e0 = __expf(sv[i] - M);
            float e1 = __expf(sv[i + 8] - M);
            sum += e0 + e1;
            pk0[i] = (short)f2bf(e0);
            pk1[i] = (short)f2bf(e1);
        }
        *(s16x8*)&Ps[r][p * 16]     = pk0;
        *(s16x8*)&Ps[r][p * 16 + 8] = pk1;
        sum += __shfl_xor(sum, 1, 64);
        sum += __shfl_xor(sum, 2, 64);
        if (p == 0) {
            float al = __expf(mo - M);
            arow[r] = al;
            mrow[r] = M;
            lrow[r] = lrow[r] * al + sum;
        }
        __syncthreads();

        #pragma unroll
        for (int mf = 0; mf < 4; ++mf) {
            #pragma unroll
            for (int j = 0; j < 4; ++j)
                acc[mf][j] *= arow[mf * 16 + lg * 4 + j];
        }
        s16x8 vb[2];
        #pragma unroll
        for (int ks = 0; ks < 2; ++ks) {
            int row = wave * 16 + lr;
            int sl  = (lg + ks * 4) ^ (row & 7);
            vb[ks] = *(const s16x8*)&Vs[row * 64 + sl * 8];
        }
        #pragma unroll
        for (int mf = 0; mf < 4; ++mf)
            #pragma unroll
            for (int ks = 0; ks < 2; ++ks) {
                s16x8 pa = *(const s16x8*)((const char*)&Ps[0][0]
                            + (mf * 16 + lr) * 144 + lg * 16 + ks * 64);
                acc[mf] = __builtin_amdgcn_mfma_f32_16x16x32_bf16(
                    pa, vb[ks], acc[mf], 0, 0, 0);
            }
        __syncthreads();
    }

    #pragma unroll
    for (int mf = 0; mf < 4; ++mf)
        #pragma unroll
        for (int j = 0; j < 4; ++j) {
            int rr = mf * 16 + lg * 4 + j;
            float o = acc[mf][j] / lrow[rr];
            ctx[(size_t)(b * S_ + q0 + rr) * D_ + hh * HD_ + wave * 16 + lr] = f2bf(o);
        }
}

// =====================================================================
// prep_layer: all weight transposes+converts for one layer + qkv bias
// concat in ONE launch. 12291 blocks x 256 thr.
//   [0,4096):      Wq/Wk/Wv/Wo  (1024 tiles each, 32x32)
//   [4096,8192):   W1 [1024,4096] -> [4096,1024]
//   [8192,12288):  W2 [4096,1024] -> [1024,4096]
//   [12288,12291): bias concat
// =====================================================================
__global__ __launch_bounds__(256)
void prep_layer(const float* __restrict__ Wq, const float* __restrict__ Wk,
                const float* __restrict__ Wv, const float* __restrict__ Wo,
                const float* __restrict__ W1, const float* __restrict__ W2,
                const float* __restrict__ bq, const float* __restrict__ bk,
                const float* __restrict__ bv,
                ushort_t* __restrict__ wqkvT, ushort_t* __restrict__ woT,
                ushort_t* __restrict__ w1T, ushort_t* __restrict__ w2T,
                float* __restrict__ qkvb)
{
    int bid = blockIdx.x;
    if (bid >= 12288) {
        int j = bid - 12288;
        const float* bsrc = (j == 0) ? bq : (j == 1) ? bk : bv;
        int c = threadIdx.x * 4;
        *(f32x4*)&qkvb[j * 1024 + c] = *(const f32x4*)&bsrc[c];
        return;
    }
    __shared__ float t[32][33];
    int tx = threadIdx.x & 31, ty = threadIdx.x >> 5;
    const float* src; ushort_t* dst; int R, C, c0, r0;
    if (bid < 4096) {
        int mat = bid >> 10, tnum = bid & 1023;
        src = (mat == 0) ? Wq : (mat == 1) ? Wk : (mat == 2) ? Wv : Wo;
        dst = (mat < 3) ? (wqkvT + (size_t)mat * D_ * D_) : woT;
        R = D_; C = D_;
        c0 = (tnum & 31) * 32; r0 = (tnum >> 5) * 32;
    } else if (bid < 8192) {
        int tnum = bid - 4096;
        src = W1; dst = w1T; R = D_; C = F_;
        c0 = (tnum & 127) * 32; r0 = (tnum >> 7) * 32;
    } else {
        int tnum = bid - 8192;
        src = W2; dst = w2T; R = F_; C = D_;
        c0 = (tnum & 31) * 32; r0 = (tnum >> 5) * 32;
    }
    #pragma unroll
    for (int i = 0; i < 4; ++i)
        t[ty + i * 8][tx] = src[(size_t)(r0 + ty + i * 8) * C + c0 + tx];
    __syncthreads();
    #pragma unroll
    for (int i = 0; i < 4; ++i)
        dst[(size_t)(c0 + ty + i * 8) * R + r0 + tx] = f2bf(t[tx][ty + i * 8]);
}

// ---- f32 [R,C] -> bf16 [C,R] transpose-convert (used for Wout) ----
__global__ __launch_bounds__(256)
void tconv(const float* __restrict__ in, ushort_t* __restrict__ out, int R, int C)
{
    __shared__ float t[32][33];
    int c0 = blockIdx.x * 32, r0 = blockIdx.y * 32;
    int tx = threadIdx.x & 31, ty = threadIdx.x >> 5;
    #pragma unroll
    for (int i = 0; i < 4; ++i)
        t[ty + i * 8][tx] = in[(size_t)(r0 + ty + i * 8) * C + c0 + tx];
    __syncthreads();
    #pragma unroll
    for (int i = 0; i < 4; ++i)
        out[(size_t)(c0 + ty + i * 8) * R + r0 + tx] = f2bf(t[tx][ty + i * 8]);
}

// ---- per-head V transpose: v (qkv cols 2048..3071) -> vt[BH][HD][S] ----
__global__ __launch_bounds__(256)
void vtrans(const ushort_t* __restrict__ v, ushort_t* __restrict__ vt)
{
    int z = blockIdx.z, b = z >> 4, h = z & 15;
    int s0 = blockIdx.x * 32, d0 = blockIdx.y * 32;
    __shared__ ushort_t t[32][33];
    int tx = threadIdx.x & 31, ty = threadIdx.x >> 5;
    #pragma unroll
    for (int i = 0; i < 4; ++i)
        t[ty + i * 8][tx] = v[(size_t)(b * S_ + s0 + ty + i * 8) * 3072 + h * HD_ + d0 + tx];
    __syncthreads();
    #pragma unroll
    for (int i = 0; i < 4; ++i)
        vt[((size_t)z * HD_ + d0 + ty + i * 8) * S_ + s0 + tx] = t[tx][ty + i * 8];
}

// ---- embedding * sqrt(D) + sinusoidal PE -> x (f32) ----
__global__ __launch_bounds__(256)
void embed_pe(const int* __restrict__ ids, const float* __restrict__ emb,
              float* __restrict__ x)
{
    int row = blockIdx.x;
    int s   = row & (S_ - 1);
    int id  = ids[row];
    int d   = threadIdx.x * 4;
    f32x4 ev = *(const f32x4*)&emb[(size_t)id * D_ + d];
    f32x4 o;
    #pragma unroll
    for (int j = 0; j < 4; ++j) {
        int dd = d + j;
        int i  = dd >> 1;
        float div = expf(-(float)(2 * i) * (9.210340371976184f / 1024.0f));
        float arg = (float)s * div;
        float pe  = (dd & 1) ? cosf(arg) : sinf(arg);
        o[j] = ev[j] * 32.0f + pe;
    }
    *(f32x4*)&x[(size_t)row * D_ + d] = o;
}

// ---- LayerNorm row kernel: f32 in -> bf16 out ----
__global__ __launch_bounds__(256)
void ln_kernel(const float* __restrict__ x, const float* __restrict__ g,
               const float* __restrict__ b, ushort_t* __restrict__ out)
{
    __shared__ float sb[4];
    int row = blockIdx.x;
    const float* xr = x + (size_t)row * D_;
    int c = threadIdx.x * 4;
    f32x4 v = *(const f32x4*)&xr[c];
    float s = v[0] + v[1] + v[2] + v[3];
    s = blk_sum(s, sb);
    float mean = s * (1.0f / D_);
    f32x4 dv = v - mean;
    float sq = dv[0]*dv[0] + dv[1]*dv[1] + dv[2]*dv[2] + dv[3]*dv[3];
    sq = blk_sum(sq, sb);
    float rstd = rsqrtf(sq * (1.0f / D_) + EPSLN);
    u16x4 o;
    #pragma unroll
    for (int j = 0; j < 4; ++j)
        o[j] = f2bf(dv[j] * rstd * g[c + j] + b[c + j]);
    *(u16x4*)&out[(size_t)row * D_ + c] = o;
}

__global__ void ws_marker(float* o) { o[threadIdx.x] = -777777.0f; }

// =====================================================================
extern "C" void kernel_launch(void* const* d_in, const int* in_sizes, int n_in,
                              void* d_out, int out_size, void* d_ws, size_t ws_size,
                              hipStream_t stream)
{
    (void)in_sizes; (void)n_in; (void)out_size;
    const int*   ids  = (const int*)d_in[0];
    const float* emb  = (const float*)d_in[1];
    const float* Wq   = (const float*)d_in[2];
    const float* bq   = (const float*)d_in[3];
    const float* Wk   = (const float*)d_in[4];
    const float* bk   = (const float*)d_in[5];
    const float* Wv   = (const float*)d_in[6];
    const float* bv   = (const float*)d_in[7];
    const float* Wo   = (const float*)d_in[8];
    const float* bo   = (const float*)d_in[9];
    const float* ln1g = (const float*)d_in[10];
    const float* ln1b = (const float*)d_in[11];
    const float* ln2g = (const float*)d_in[12];
    const float* ln2b = (const float*)d_in[13];
    const float* W1   = (const float*)d_in[14];
    const float* b1   = (const float*)d_in[15];
    const float* W2   = (const float*)d_in[16];
    const float* b2   = (const float*)d_in[17];
    const float* fng  = (const float*)d_in[18];
    const float* fnb  = (const float*)d_in[19];
    const float* Wout = (const float*)d_in[20];
    const float* bout = (const float*)d_in[21];
    float* out = (float*)d_out;

    // ---- workspace layout ----
    char* base = (char*)d_ws;
    size_t off = 0;
    float*    x    = (float*)(base + off);    off += (size_t)MTOK * D_ * 4;
    ushort_t* h    = (ushort_t*)(base + off); off += (size_t)MTOK * D_ * 2;
    ushort_t* qkv  = (ushort_t*)(base + off); off += (size_t)MTOK * 3 * D_ * 2;
    ushort_t* vt   = (ushort_t*)(base + off); off += (size_t)B_ * H_ * HD_ * S_ * 2;
    ushort_t* ctx  = (ushort_t*)(base + off); off += (size_t)MTOK * D_ * 2;
    ushort_t* ff   = (ushort_t*)(base + off); off += (size_t)MTOK * F_ * 2;
    float*    qkvb = (float*)(base + off);    off += 3072 * 4;
    ushort_t* wqkvT= (ushort_t*)(base + off); off += (size_t)3 * D_ * D_ * 2;
    ushort_t* woT  = (ushort_t*)(base + off); off += (size_t)D_ * D_ * 2;
    ushort_t* w1T  = (ushort_t*)(base + off); off += (size_t)D_ * F_ * 2;
    ushort_t* w2T  = (ushort_t*)(base + off); off += (size_t)F_ * D_ * 2;
    ushort_t* wouT = (ushort_t*)(base + off); off += (size_t)V_ * D_ * 2;
    if (ws_size < off) { ws_marker<<<1, 64, 0, stream>>>(out); return; }

    embed_pe<<<MTOK, 256, 0, stream>>>(ids, emb, x);

    for (int i = 0; i < L_; ++i) {
        prep_layer<<<12291, 256, 0, stream>>>(
            Wq + (size_t)i * D_ * D_, Wk + (size_t)i * D_ * D_,
            Wv + (size_t)i * D_ * D_, Wo + (size_t)i * D_ * D_,
            W1 + (size_t)i * D_ * F_, W2 + (size_t)i * F_ * D_,
            bq + i * D_, bk + i * D_, bv + i * D_,
            wqkvT, woT, w1T, w2T, qkvb);

        ln_kernel<<<MTOK, 256, 0, stream>>>(x, ln1g + i * D_, ln1b + i * D_, h);

        // qkv = h @ [Wq|Wk|Wv] + bias   (M=2048, N=3072, K=1024)
        gemm256<false,true><<<dim3(8, 12), 512, 0, stream>>>(
            h, D_, wqkvT, D_, qkv, 3 * D_, qkvb, MTOK, 3 * D_, D_);

        vtrans<<<dim3(32, 2, B_ * H_), 256, 0, stream>>>(qkv + 2 * D_, vt);

        flash_attn<<<dim3(S_ / 64, B_ * H_), 256, 0, stream>>>(qkv, vt, ctx);

        // x = x + ctx @ Wo + bo
        gemm_bt<false,true,false><<<dim3(16, 8), 256, 0, stream>>>(
            ctx, D_, woT, D_, x, D_, bo + i * D_, x, MTOK, D_, D_);

        ln_kernel<<<MTOK, 256, 0, stream>>>(x, ln2g + i * D_, ln2b + i * D_, h);

        // ff = gelu(h @ W1 + b1)
        gemm256<true,true><<<dim3(8, 16), 512, 0, stream>>>(
            h, D_, w1T, D_, ff, F_, b1 + i * F_, MTOK, F_, D_);

        // x = x + ff @ W2 + b2
        gemm_bt<false,true,false><<<dim3(16, 8), 256, 0, stream>>>(
            ff, F_, w2T, F_, x, D_, b2 + i * D_, x, MTOK, D_, F_);
    }

    ln_kernel<<<MTOK, 256, 0, stream>>>(x, fng, fnb, h);
    tconv<<<dim3(1000, 32), 256, 0, stream>>>(Wout, wouT, D_, V_);
    gemm256<false,false><<<dim3(8, 125), 512, 0, stream>>>(
        h, D_, wouT, D_, out, V_, bout, MTOK, V_, D_);
}

// Round 5
// 1873.043 us; speedup vs baseline: 1.4908x; 1.0507x over previous
//
#include <hip/hip_runtime.h>
#include <math.h>

// ---- problem constants ----
#define V_   32000
#define D_   1024
#define H_   16
#define HD_  64
#define L_   6
#define F_   4096
#define S_   1024
#define B_   2
#define MTOK (B_*S_)      // 2048
#define EPSLN 1e-5f

typedef unsigned short ushort_t;
typedef __attribute__((ext_vector_type(8))) short  s16x8;
typedef __attribute__((ext_vector_type(4))) float  f32x4;
typedef __attribute__((ext_vector_type(4))) unsigned short u16x4;

// ---- bf16 helpers (raw ushort) ----
__device__ __forceinline__ float bf2f(unsigned short u) {
    unsigned int x = ((unsigned int)u) << 16;
    return __builtin_bit_cast(float, x);
}
__device__ __forceinline__ unsigned short f2bf(float f) {
    unsigned int x = __builtin_bit_cast(unsigned int, f);
    unsigned int r = (x + 0x7FFFu + ((x >> 16) & 1u)) >> 16;   // RNE
    return (unsigned short)r;
}

// ---- block reductions (256 threads = 4 waves of 64) ----
__device__ __forceinline__ float blk_sum(float v, float* sb) {
    #pragma unroll
    for (int o = 32; o; o >>= 1) v += __shfl_xor(v, o, 64);
    int w = threadIdx.x >> 6;
    __syncthreads();
    if ((threadIdx.x & 63) == 0) sb[w] = v;
    __syncthreads();
    return sb[0] + sb[1] + sb[2] + sb[3];
}

// =====================================================================
// gemm256: 2-phase-per-K-tile pipelined 256x256xBK64 bf16 MFMA GEMM.
// 512 thr = 8 waves (2M x 4N), per-wave 128x64 out. LDS 128 KiB dbuf.
// Phase A: 16 ds_read (af0+bf0+bf1) | stage A(u+1) | bar | lgkm0 | 32 MFMA | bar
// Phase B:  8 ds_read (af1)         | stage B(u+2) | bar | lgkm0 | 32 MFMA |
//           vmcnt(4) | bar            (counted: A(u+1),B(u+1) landed)
// Liveness: B(u+2) overwrites lB[cur] -- all B(cur) reads completed before
// phase A's closing barrier. A(u+1) into lA[nxt] -- tile u-1's af1 reads
// from that buffer completed before u-1's phase-B closing barrier.
// XOR swizzle slot^=(row&7): pre-swizzled global src + swizzled ds_read.
// =====================================================================
template<bool GELU, bool OUTBF>
__global__ __launch_bounds__(512, 2)
void gemm256(const ushort_t* __restrict__ A, int lda,
             const ushort_t* __restrict__ BT, int ldb,
             void* __restrict__ Cv, int ldc,
             const float* __restrict__ bias,
             int M, int N, int K)
{
    int nmt = M >> 8;
    int nwg = gridDim.x * gridDim.y;
    int id  = blockIdx.x + gridDim.x * blockIdx.y;
    int swz = ((nwg & 7) == 0) ? ((id & 7) * (nwg >> 3) + (id >> 3)) : id;
    int m0 = (swz % nmt) << 8;
    int n0 = (swz / nmt) << 8;

    __shared__ __align__(16) ushort_t lA[2][256 * 64];
    __shared__ __align__(16) ushort_t lB[2][256 * 64];

    int tid  = threadIdx.x;
    int lane = tid & 63, wave = tid >> 6;
    int lr = lane & 15, lg = lane >> 4;
    int wm = wave >> 2, wn = wave & 3;

    f32x4 acc[8][4] = {};
    int nkt = K >> 6;

    // stage one half-tile: sel 0=Alo 1=Ahi 2=Blo 3=Bhi (128 rows x 64 k)
    auto stageu = [&](int buf, int kt, int sel) {
        int k0 = kt << 6;
        const ushort_t* src = (sel < 2) ? A : BT;
        int ld    = (sel < 2) ? lda : ldb;
        int rbase = ((sel < 2) ? m0 : n0) + ((sel & 1) << 7);
        ushort_t* dst = ((sel < 2) ? &lA[buf][0] : &lB[buf][0]) + ((sel & 1) << 13);
        #pragma unroll
        for (int r = 0; r < 2; ++r) {
            int e8  = r * 512 + tid;           // 0..1023 (16B units)
            int row = e8 >> 3, slot = e8 & 7;
            int ls  = slot ^ (row & 7);
            const ushort_t* g = src + (size_t)(rbase + row) * ld + k0 + ls * 8;
            __builtin_amdgcn_global_load_lds(
                (const __attribute__((address_space(1))) void*)g,
                (__attribute__((address_space(3))) void*)(dst + e8 * 8), 16, 0, 0);
        }
    };
    auto rdA = [&](int buf, int row, int ks) -> s16x8 {
        int sl = (lg + ks * 4) ^ (row & 7);
        return *(const s16x8*)&lA[buf][row * 64 + sl * 8];
    };
    auto rdB = [&](int buf, int row, int ks) -> s16x8 {
        int sl = (lg + ks * 4) ^ (row & 7);
        return *(const s16x8*)&lB[buf][row * 64 + sl * 8];
    };

    // ---- prologue: A(0), B(0) fully; B(1); wait A(0)+B(0) (B(1) in flight)
    stageu(0, 0, 0); stageu(0, 0, 1); stageu(0, 0, 2); stageu(0, 0, 3);
    if (nkt > 1) {
        stageu(1, 1, 2); stageu(1, 1, 3);
        asm volatile("s_waitcnt vmcnt(4)" ::: "memory");
    } else {
        asm volatile("s_waitcnt vmcnt(0)" ::: "memory");
    }
    __builtin_amdgcn_sched_barrier(0);
    __builtin_amdgcn_s_barrier();

    for (int u = 0; u < nkt; ++u) {
        int cur = u & 1, nxt = cur ^ 1;
        s16x8 af0[4][2], af1[4][2], bf0[2][2], bf1[2][2];

        // ======== Phase A: af0 + bf0 + bf1 reads; stage A(u+1) ========
        #pragma unroll
        for (int mf = 0; mf < 4; ++mf)
            #pragma unroll
            for (int ks = 0; ks < 2; ++ks)
                af0[mf][ks] = rdA(cur, wm * 128 + mf * 16 + lr, ks);
        #pragma unroll
        for (int nf = 0; nf < 2; ++nf)
            #pragma unroll
            for (int ks = 0; ks < 2; ++ks) {
                bf0[nf][ks] = rdB(cur, wn * 64 + nf * 16 + lr, ks);
                bf1[nf][ks] = rdB(cur, wn * 64 + 32 + nf * 16 + lr, ks);
            }
        if (u + 1 < nkt) { stageu(nxt, u + 1, 0); stageu(nxt, u + 1, 1); }
        __builtin_amdgcn_s_barrier();
        asm volatile("s_waitcnt lgkmcnt(0)" ::: "memory");
        __builtin_amdgcn_sched_barrier(0);
        __builtin_amdgcn_s_setprio(1);
        #pragma unroll
        for (int mf = 0; mf < 4; ++mf)
            #pragma unroll
            for (int ks = 0; ks < 2; ++ks) {
                #pragma unroll
                for (int nf = 0; nf < 2; ++nf) {
                    acc[mf][nf]     = __builtin_amdgcn_mfma_f32_16x16x32_bf16(
                        af0[mf][ks], bf0[nf][ks], acc[mf][nf], 0, 0, 0);
                    acc[mf][2 + nf] = __builtin_amdgcn_mfma_f32_16x16x32_bf16(
                        af0[mf][ks], bf1[nf][ks], acc[mf][2 + nf], 0, 0, 0);
                }
            }
        __builtin_amdgcn_s_setprio(0);
        __builtin_amdgcn_s_barrier();

        // ======== Phase B: af1 reads; stage B(u+2) into cur ========
        #pragma unroll
        for (int mf = 0; mf < 4; ++mf)
            #pragma unroll
            for (int ks = 0; ks < 2; ++ks)
                af1[mf][ks] = rdA(cur, wm * 128 + 64 + mf * 16 + lr, ks);
        if (u + 2 < nkt) { stageu(cur, u + 2, 2); stageu(cur, u + 2, 3); }
        __builtin_amdgcn_s_barrier();
        asm volatile("s_waitcnt lgkmcnt(0)" ::: "memory");
        __builtin_amdgcn_sched_barrier(0);
        __builtin_amdgcn_s_setprio(1);
        #pragma unroll
        for (int mf = 0; mf < 4; ++mf)
            #pragma unroll
            for (int ks = 0; ks < 2; ++ks) {
                #pragma unroll
                for (int nf = 0; nf < 2; ++nf) {
                    acc[4 + mf][nf]     = __builtin_amdgcn_mfma_f32_16x16x32_bf16(
                        af1[mf][ks], bf0[nf][ks], acc[4 + mf][nf], 0, 0, 0);
                    acc[4 + mf][2 + nf] = __builtin_amdgcn_mfma_f32_16x16x32_bf16(
                        af1[mf][ks], bf1[nf][ks], acc[4 + mf][2 + nf], 0, 0, 0);
                }
            }
        __builtin_amdgcn_s_setprio(0);
        // counted wait: A(u+1)+B(u+1) resident; B(u+2) (4 loads) stays in flight
        if (u + 2 < nkt) asm volatile("s_waitcnt vmcnt(4)" ::: "memory");
        else             asm volatile("s_waitcnt vmcnt(0)" ::: "memory");
        __builtin_amdgcn_sched_barrier(0);
        __builtin_amdgcn_s_barrier();
    }

    float*    Cf = (float*)Cv;
    ushort_t* Cb = (ushort_t*)Cv;
    #pragma unroll
    for (int mf = 0; mf < 8; ++mf) {
        int gm0 = m0 + wm * 128 + mf * 16 + lg * 4;
        #pragma unroll
        for (int nf = 0; nf < 4; ++nf) {
            int gn = n0 + wn * 64 + nf * 16 + lr;
            float bv = bias ? bias[gn] : 0.f;
            #pragma unroll
            for (int j = 0; j < 4; ++j) {
                float v = acc[mf][nf][j] + bv;
                if (GELU) v = 0.5f * v * (1.0f + erff(v * 0.70710678118f));
                size_t ci = (size_t)(gm0 + j) * ldc + gn;
                if (OUTBF) Cb[ci] = f2bf(v);
                else       Cf[ci] = v;
            }
        }
    }
}

// =====================================================================
// gemm_bt: 128x128xBK32, 2-phase double-buffered + 4-slot XOR swizzle.
// Full-fill kernel for N<=4096 GEMMs (QKV, Wo, FFN1, FFN2).
// =====================================================================
template<bool GELU, bool RES, bool OUTBF>
__global__ __launch_bounds__(256)
void gemm_bt(const ushort_t* __restrict__ A, int lda,
             const ushort_t* __restrict__ BT, int ldb,
             void* __restrict__ Cv, int ldc,
             const float* __restrict__ bias,
             const float* __restrict__ res,
             int M, int N, int K)
{
    const int BK = 32;
    int m0 = blockIdx.x * 128;
    int n0 = blockIdx.y * 128;

    __shared__ __align__(16) ushort_t lA[2][128 * BK];
    __shared__ __align__(16) ushort_t lB[2][128 * BK];

    int tid  = threadIdx.x;
    int lane = tid & 63;
    int wave = tid >> 6;
    int lr = lane & 15, lg = lane >> 4;
    int wr = wave >> 1, wc = wave & 1;

    f32x4 acc[4][4] = {};
    int nkt = K / BK;

    auto stage = [&](int buf, int kt) {
        int k0 = kt * BK;
        #pragma unroll
        for (int i = 0; i < 2; ++i) {
            int e8  = i * 256 + tid;
            int row = e8 >> 2, slot = e8 & 3;
            int ls  = slot ^ (row & 3);
            const ushort_t* g = A + (size_t)(m0 + row) * lda + k0 + ls * 8;
            __builtin_amdgcn_global_load_lds(
                (const __attribute__((address_space(1))) void*)g,
                (__attribute__((address_space(3))) void*)&lA[buf][e8 * 8], 16, 0, 0);
        }
        #pragma unroll
        for (int i = 0; i < 2; ++i) {
            int e8  = i * 256 + tid;
            int row = e8 >> 2, slot = e8 & 3;
            int ls  = slot ^ (row & 3);
            const ushort_t* g = BT + (size_t)(n0 + row) * ldb + k0 + ls * 8;
            __builtin_amdgcn_global_load_lds(
                (const __attribute__((address_space(1))) void*)g,
                (__attribute__((address_space(3))) void*)&lB[buf][e8 * 8], 16, 0, 0);
        }
    };

    stage(0, 0);
    __syncthreads();

    int cur = 0;
    for (int kt = 0; kt < nkt; ++kt) {
        if (kt + 1 < nkt) stage(cur ^ 1, kt + 1);
        __builtin_amdgcn_sched_barrier(0);
        s16x8 af[4], bfr[4];
        #pragma unroll
        for (int m = 0; m < 4; ++m) {
            int row = wr * 64 + m * 16 + lr;
            int sl  = lg ^ (row & 3);
            af[m] = *(const s16x8*)&lA[cur][row * BK + sl * 8];
        }
        #pragma unroll
        for (int n = 0; n < 4; ++n) {
            int row = wc * 64 + n * 16 + lr;
            int sl  = lg ^ (row & 3);
            bfr[n] = *(const s16x8*)&lB[cur][row * BK + sl * 8];
        }
        #pragma unroll
        for (int m = 0; m < 4; ++m)
            #pragma unroll
            for (int n = 0; n < 4; ++n)
                acc[m][n] = __builtin_amdgcn_mfma_f32_16x16x32_bf16(
                    af[m], bfr[n], acc[m][n], 0, 0, 0);
        __syncthreads();
        cur ^= 1;
    }

    float*    Cf = (float*)Cv;
    ushort_t* Cb = (ushort_t*)Cv;
    #pragma unroll
    for (int m = 0; m < 4; ++m) {
        int gm0 = m0 + wr * 64 + m * 16 + lg * 4;
        #pragma unroll
        for (int n = 0; n < 4; ++n) {
            int gn = n0 + wc * 64 + n * 16 + lr;
            #pragma unroll
            for (int j = 0; j < 4; ++j) {
                float v = acc[m][n][j];
                if (bias) v += bias[gn];
                size_t ci = (size_t)(gm0 + j) * ldc + gn;
                if (RES)  v += res[ci];
                if (GELU) v = 0.5f * v * (1.0f + erff(v * 0.70710678118f));
                if (OUTBF) Cb[ci] = f2bf(v);
                else       Cf[ci] = v;
            }
        }
    }
}

// =====================================================================
// Flash attention: one block = (b,h) x 64-row Q tile. 4 waves.
// =====================================================================
__global__ __launch_bounds__(256)
void flash_attn(const ushort_t* __restrict__ qkv,
                const ushort_t* __restrict__ vt,
                ushort_t* __restrict__ ctx)
{
    const int QB = 64, KB = 64;
    int z  = blockIdx.y;            // b*H + h
    int b  = z >> 4, hh = z & 15;
    int q0 = blockIdx.x * QB;

    __shared__ __align__(16) ushort_t Qs[QB * 64];
    __shared__ __align__(16) ushort_t Ks[KB * 64];
    __shared__ __align__(16) ushort_t Vs[64 * KB];     // rows = d
    __shared__ float    Ss[QB][68];
    __shared__ __align__(16) ushort_t Ps[QB][72];
    __shared__ float mrow[QB], lrow[QB], arow[QB];

    int tid  = threadIdx.x;
    int lane = tid & 63, wave = tid >> 6;
    int lr = lane & 15, lg = lane >> 4;

    if (tid < QB) { mrow[tid] = -1e30f; lrow[tid] = 0.f; }

    const ushort_t* qbase = qkv + (size_t)(b * S_ + q0) * 3072 + hh * HD_;
    #pragma unroll
    for (int rnd = 0; rnd < 2; ++rnd) {
        int e8   = rnd * 256 + tid;
        int row  = e8 >> 3;
        int slot = e8 & 7;
        int ls   = slot ^ (row & 7);
        const ushort_t* g = qbase + (size_t)row * 3072 + ls * 8;
        __builtin_amdgcn_global_load_lds(
            (const __attribute__((address_space(1))) void*)g,
            (__attribute__((address_space(3))) void*)&Qs[e8 * 8], 16, 0, 0);
    }
    __syncthreads();

    s16x8 qa[4][2];
    #pragma unroll
    for (int mf = 0; mf < 4; ++mf)
        #pragma unroll
        for (int ks = 0; ks < 2; ++ks) {
            int row = mf * 16 + lr;
            int sl  = (lg + ks * 4) ^ (row & 7);
            qa[mf][ks] = *(const s16x8*)&Qs[row * 64 + sl * 8];
        }

    f32x4 acc[4] = {};
    int r = tid >> 2, p = tid & 3;

    int kv_end = q0 + QB;
    for (int kv0 = 0; kv0 < kv_end; kv0 += KB) {
        const ushort_t* kbase = qkv + (size_t)(b * S_ + kv0) * 3072 + 1024 + hh * HD_;
        const ushort_t* vbase = vt + (size_t)z * HD_ * S_ + kv0;
        #pragma unroll
        for (int rnd = 0; rnd < 2; ++rnd) {
            int e8 = rnd * 256 + tid;
            int row = e8 >> 3, slot = e8 & 7;
            int ls = slot ^ (row & 7);
            const ushort_t* gk = kbase + (size_t)row * 3072 + ls * 8;
            __builtin_amdgcn_global_load_lds(
                (const __attribute__((address_space(1))) void*)gk,
                (__attribute__((address_space(3))) void*)&Ks[e8 * 8], 16, 0, 0);
            const ushort_t* gv = vbase + (size_t)row * S_ + ls * 8;
            __builtin_amdgcn_global_load_lds(
                (const __attribute__((address_space(1))) void*)gv,
                (__attribute__((address_space(3))) void*)&Vs[e8 * 8], 16, 0, 0);
        }
        __syncthreads();

        s16x8 kb[2];
        #pragma unroll
        for (int ks = 0; ks < 2; ++ks) {
            int row = wave * 16 + lr;
            int sl  = (lg + ks * 4) ^ (row & 7);
            kb[ks] = *(const s16x8*)&Ks[row * 64 + sl * 8];
        }
        f32x4 sa[4] = {};
        #pragma unroll
        for (int mf = 0; mf < 4; ++mf)
            #pragma unroll
            for (int ks = 0; ks < 2; ++ks)
                sa[mf] = __builtin_amdgcn_mfma_f32_16x16x32_bf16(
                    qa[mf][ks], kb[ks], sa[mf], 0, 0, 0);

        int ki = kv0 + wave * 16 + lr;
        #pragma unroll
        for (int mf = 0; mf < 4; ++mf)
            #pragma unroll
            for (int j = 0; j < 4; ++j) {
                int qi = q0 + mf * 16 + lg * 4 + j;
                float s = (ki <= qi) ? sa[mf][j] * 0.125f : -1e30f;
                Ss[mf * 16 + lg * 4 + j][wave * 16 + lr] = s;
            }
        __syncthreads();

        float mo = mrow[r];
        float sv[16];
        float pm = -1e30f;
        #pragma unroll
        for (int i = 0; i < 16; ++i) {
            sv[i] = Ss[r][p * 16 + i];
            pm = fmaxf(pm, sv[i]);
        }
        pm = fmaxf(pm, __shfl_xor(pm, 1, 64));
        pm = fmaxf(pm, __shfl_xor(pm, 2, 64));
        float M = fmaxf(mo, pm);
        float sum = 0.f;
        s16x8 pk0, pk1;
        #pragma unroll
        for (int i = 0; i < 8; ++i) {
            float e0 = __expf(sv[i] - M);
            float e1 = __expf(sv[i + 8] - M);
            sum += e0 + e1;
            pk0[i] = (short)f2bf(e0);
            pk1[i] = (short)f2bf(e1);
        }
        *(s16x8*)&Ps[r][p * 16]     = pk0;
        *(s16x8*)&Ps[r][p * 16 + 8] = pk1;
        sum += __shfl_xor(sum, 1, 64);
        sum += __shfl_xor(sum, 2, 64);
        if (p == 0) {
            float al = __expf(mo - M);
            arow[r] = al;
            mrow[r] = M;
            lrow[r] = lrow[r] * al + sum;
        }
        __syncthreads();

        #pragma unroll
        for (int mf = 0; mf < 4; ++mf) {
            #pragma unroll
            for (int j = 0; j < 4; ++j)
                acc[mf][j] *= arow[mf * 16 + lg * 4 + j];
        }
        s16x8 vb[2];
        #pragma unroll
        for (int ks = 0; ks < 2; ++ks) {
            int row = wave * 16 + lr;
            int sl  = (lg + ks * 4) ^ (row & 7);
            vb[ks] = *(const s16x8*)&Vs[row * 64 + sl * 8];
        }
        #pragma unroll
        for (int mf = 0; mf < 4; ++mf)
            #pragma unroll
            for (int ks = 0; ks < 2; ++ks) {
                s16x8 pa = *(const s16x8*)((const char*)&Ps[0][0]
                            + (mf * 16 + lr) * 144 + lg * 16 + ks * 64);
                acc[mf] = __builtin_amdgcn_mfma_f32_16x16x32_bf16(
                    pa, vb[ks], acc[mf], 0, 0, 0);
            }
        __syncthreads();
    }

    #pragma unroll
    for (int mf = 0; mf < 4; ++mf)
        #pragma unroll
        for (int j = 0; j < 4; ++j) {
            int rr = mf * 16 + lg * 4 + j;
            float o = acc[mf][j] / lrow[rr];
            ctx[(size_t)(b * S_ + q0 + rr) * D_ + hh * HD_ + wave * 16 + lr] = f2bf(o);
        }
}

// =====================================================================
// prep_layer: all weight transposes+converts for one layer + qkv bias
// concat in ONE launch. 12291 blocks x 256 thr.
// =====================================================================
__global__ __launch_bounds__(256)
void prep_layer(const float* __restrict__ Wq, const float* __restrict__ Wk,
                const float* __restrict__ Wv, const float* __restrict__ Wo,
                const float* __restrict__ W1, const float* __restrict__ W2,
                const float* __restrict__ bq, const float* __restrict__ bk,
                const float* __restrict__ bv,
                ushort_t* __restrict__ wqkvT, ushort_t* __restrict__ woT,
                ushort_t* __restrict__ w1T, ushort_t* __restrict__ w2T,
                float* __restrict__ qkvb)
{
    int bid = blockIdx.x;
    if (bid >= 12288) {
        int j = bid - 12288;
        const float* bsrc = (j == 0) ? bq : (j == 1) ? bk : bv;
        int c = threadIdx.x * 4;
        *(f32x4*)&qkvb[j * 1024 + c] = *(const f32x4*)&bsrc[c];
        return;
    }
    __shared__ float t[32][33];
    int tx = threadIdx.x & 31, ty = threadIdx.x >> 5;
    const float* src; ushort_t* dst; int R, C, c0, r0;
    if (bid < 4096) {
        int mat = bid >> 10, tnum = bid & 1023;
        src = (mat == 0) ? Wq : (mat == 1) ? Wk : (mat == 2) ? Wv : Wo;
        dst = (mat < 3) ? (wqkvT + (size_t)mat * D_ * D_) : woT;
        R = D_; C = D_;
        c0 = (tnum & 31) * 32; r0 = (tnum >> 5) * 32;
    } else if (bid < 8192) {
        int tnum = bid - 4096;
        src = W1; dst = w1T; R = D_; C = F_;
        c0 = (tnum & 127) * 32; r0 = (tnum >> 7) * 32;
    } else {
        int tnum = bid - 8192;
        src = W2; dst = w2T; R = F_; C = D_;
        c0 = (tnum & 31) * 32; r0 = (tnum >> 5) * 32;
    }
    #pragma unroll
    for (int i = 0; i < 4; ++i)
        t[ty + i * 8][tx] = src[(size_t)(r0 + ty + i * 8) * C + c0 + tx];
    __syncthreads();
    #pragma unroll
    for (int i = 0; i < 4; ++i)
        dst[(size_t)(c0 + ty + i * 8) * R + r0 + tx] = f2bf(t[tx][ty + i * 8]);
}

// ---- f32 [R,C] -> bf16 [C,R] transpose-convert (used for Wout) ----
__global__ __launch_bounds__(256)
void tconv(const float* __restrict__ in, ushort_t* __restrict__ out, int R, int C)
{
    __shared__ float t[32][33];
    int c0 = blockIdx.x * 32, r0 = blockIdx.y * 32;
    int tx = threadIdx.x & 31, ty = threadIdx.x >> 5;
    #pragma unroll
    for (int i = 0; i < 4; ++i)
        t[ty + i * 8][tx] = in[(size_t)(r0 + ty + i * 8) * C + c0 + tx];
    __syncthreads();
    #pragma unroll
    for (int i = 0; i < 4; ++i)
        out[(size_t)(c0 + ty + i * 8) * R + r0 + tx] = f2bf(t[tx][ty + i * 8]);
}

// ---- per-head V transpose: v (qkv cols 2048..3071) -> vt[BH][HD][S] ----
__global__ __launch_bounds__(256)
void vtrans(const ushort_t* __restrict__ v, ushort_t* __restrict__ vt)
{
    int z = blockIdx.z, b = z >> 4, h = z & 15;
    int s0 = blockIdx.x * 32, d0 = blockIdx.y * 32;
    __shared__ ushort_t t[32][33];
    int tx = threadIdx.x & 31, ty = threadIdx.x >> 5;
    #pragma unroll
    for (int i = 0; i < 4; ++i)
        t[ty + i * 8][tx] = v[(size_t)(b * S_ + s0 + ty + i * 8) * 3072 + h * HD_ + d0 + tx];
    __syncthreads();
    #pragma unroll
    for (int i = 0; i < 4; ++i)
        vt[((size_t)z * HD_ + d0 + ty + i * 8) * S_ + s0 + tx] = t[tx][ty + i * 8];
}

// ---- embedding * sqrt(D) + sinusoidal PE -> x (f32) ----
__global__ __launch_bounds__(256)
void embed_pe(const int* __restrict__ ids, const float* __restrict__ emb,
              float* __restrict__ x)
{
    int row = blockIdx.x;
    int s   = row & (S_ - 1);
    int id  = ids[row];
    int d   = threadIdx.x * 4;
    f32x4 ev = *(const f32x4*)&emb[(size_t)id * D_ + d];
    f32x4 o;
    #pragma unroll
    for (int j = 0; j < 4; ++j) {
        int dd = d + j;
        int i  = dd >> 1;
        float div = expf(-(float)(2 * i) * (9.210340371976184f / 1024.0f));
        float arg = (float)s * div;
        float pe  = (dd & 1) ? cosf(arg) : sinf(arg);
        o[j] = ev[j] * 32.0f + pe;
    }
    *(f32x4*)&x[(size_t)row * D_ + d] = o;
}

// ---- LayerNorm row kernel: f32 in -> bf16 out ----
__global__ __launch_bounds__(256)
void ln_kernel(const float* __restrict__ x, const float* __restrict__ g,
               const float* __restrict__ b, ushort_t* __restrict__ out)
{
    __shared__ float sb[4];
    int row = blockIdx.x;
    const float* xr = x + (size_t)row * D_;
    int c = threadIdx.x * 4;
    f32x4 v = *(const f32x4*)&xr[c];
    float s = v[0] + v[1] + v[2] + v[3];
    s = blk_sum(s, sb);
    float mean = s * (1.0f / D_);
    f32x4 dv = v - mean;
    float sq = dv[0]*dv[0] + dv[1]*dv[1] + dv[2]*dv[2] + dv[3]*dv[3];
    sq = blk_sum(sq, sb);
    float rstd = rsqrtf(sq * (1.0f / D_) + EPSLN);
    u16x4 o;
    #pragma unroll
    for (int j = 0; j < 4; ++j)
        o[j] = f2bf(dv[j] * rstd * g[c + j] + b[c + j]);
    *(u16x4*)&out[(size_t)row * D_ + c] = o;
}

__global__ void ws_marker(float* o) { o[threadIdx.x] = -777777.0f; }

// =====================================================================
extern "C" void kernel_launch(void* const* d_in, const int* in_sizes, int n_in,
                              void* d_out, int out_size, void* d_ws, size_t ws_size,
                              hipStream_t stream)
{
    (void)in_sizes; (void)n_in; (void)out_size;
    const int*   ids  = (const int*)d_in[0];
    const float* emb  = (const float*)d_in[1];
    const float* Wq   = (const float*)d_in[2];
    const float* bq   = (const float*)d_in[3];
    const float* Wk   = (const float*)d_in[4];
    const float* bk   = (const float*)d_in[5];
    const float* Wv   = (const float*)d_in[6];
    const float* bv   = (const float*)d_in[7];
    const float* Wo   = (const float*)d_in[8];
    const float* bo   = (const float*)d_in[9];
    const float* ln1g = (const float*)d_in[10];
    const float* ln1b = (const float*)d_in[11];
    const float* ln2g = (const float*)d_in[12];
    const float* ln2b = (const float*)d_in[13];
    const float* W1   = (const float*)d_in[14];
    const float* b1   = (const float*)d_in[15];
    const float* W2   = (const float*)d_in[16];
    const float* b2   = (const float*)d_in[17];
    const float* fng  = (const float*)d_in[18];
    const float* fnb  = (const float*)d_in[19];
    const float* Wout = (const float*)d_in[20];
    const float* bout = (const float*)d_in[21];
    float* out = (float*)d_out;

    // ---- workspace layout ----
    char* base = (char*)d_ws;
    size_t off = 0;
    float*    x    = (float*)(base + off);    off += (size_t)MTOK * D_ * 4;
    ushort_t* h    = (ushort_t*)(base + off); off += (size_t)MTOK * D_ * 2;
    ushort_t* qkv  = (ushort_t*)(base + off); off += (size_t)MTOK * 3 * D_ * 2;
    ushort_t* vt   = (ushort_t*)(base + off); off += (size_t)B_ * H_ * HD_ * S_ * 2;
    ushort_t* ctx  = (ushort_t*)(base + off); off += (size_t)MTOK * D_ * 2;
    ushort_t* ff   = (ushort_t*)(base + off); off += (size_t)MTOK * F_ * 2;
    float*    qkvb = (float*)(base + off);    off += 3072 * 4;
    ushort_t* wqkvT= (ushort_t*)(base + off); off += (size_t)3 * D_ * D_ * 2;
    ushort_t* woT  = (ushort_t*)(base + off); off += (size_t)D_ * D_ * 2;
    ushort_t* w1T  = (ushort_t*)(base + off); off += (size_t)D_ * F_ * 2;
    ushort_t* w2T  = (ushort_t*)(base + off); off += (size_t)F_ * D_ * 2;
    ushort_t* wouT = (ushort_t*)(base + off); off += (size_t)V_ * D_ * 2;
    if (ws_size < off) { ws_marker<<<1, 64, 0, stream>>>(out); return; }

    embed_pe<<<MTOK, 256, 0, stream>>>(ids, emb, x);

    for (int i = 0; i < L_; ++i) {
        prep_layer<<<12291, 256, 0, stream>>>(
            Wq + (size_t)i * D_ * D_, Wk + (size_t)i * D_ * D_,
            Wv + (size_t)i * D_ * D_, Wo + (size_t)i * D_ * D_,
            W1 + (size_t)i * D_ * F_, W2 + (size_t)i * F_ * D_,
            bq + i * D_, bk + i * D_, bv + i * D_,
            wqkvT, woT, w1T, w2T, qkvb);

        ln_kernel<<<MTOK, 256, 0, stream>>>(x, ln1g + i * D_, ln1b + i * D_, h);

        // qkv = h @ [Wq|Wk|Wv] + bias  (M=2048, N=3072, K=1024) -> 384 blocks
        gemm_bt<false,false,true><<<dim3(16, 24), 256, 0, stream>>>(
            h, D_, wqkvT, D_, qkv, 3 * D_, qkvb, nullptr, MTOK, 3 * D_, D_);

        vtrans<<<dim3(32, 2, B_ * H_), 256, 0, stream>>>(qkv + 2 * D_, vt);

        flash_attn<<<dim3(S_ / 64, B_ * H_), 256, 0, stream>>>(qkv, vt, ctx);

        // x = x + ctx @ Wo + bo
        gemm_bt<false,true,false><<<dim3(16, 8), 256, 0, stream>>>(
            ctx, D_, woT, D_, x, D_, bo + i * D_, x, MTOK, D_, D_);

        ln_kernel<<<MTOK, 256, 0, stream>>>(x, ln2g + i * D_, ln2b + i * D_, h);

        // ff = gelu(h @ W1 + b1)  -> 512 blocks
        gemm_bt<true,false,true><<<dim3(16, 32), 256, 0, stream>>>(
            h, D_, w1T, D_, ff, F_, b1 + i * F_, nullptr, MTOK, F_, D_);

        // x = x + ff @ W2 + b2
        gemm_bt<false,true,false><<<dim3(16, 8), 256, 0, stream>>>(
            ff, F_, w2T, F_, x, D_, b2 + i * D_, x, MTOK, D_, F_);
    }

    ln_kernel<<<MTOK, 256, 0, stream>>>(x, fng, fnb, h);
    tconv<<<dim3(1000, 32), 256, 0, stream>>>(Wout, wouT, D_, V_);
    gemm256<false,false><<<dim3(8, 125), 512, 0, stream>>>(
        h, D_, wouT, D_, out, V_, bout, MTOK, V_, D_);
}

// Round 6
// 1639.010 us; speedup vs baseline: 1.7036x; 1.1428x over previous
//
#include <hip/hip_runtime.h>
#include <math.h>

// ---- problem constants ----
#define V_   32000
#define D_   1024
#define H_   16
#define HD_  64
#define L_   6
#define F_   4096
#define S_   1024
#define B_   2
#define MTOK (B_*S_)      // 2048
#define EPSLN 1e-5f

typedef unsigned short ushort_t;
typedef __attribute__((ext_vector_type(8))) short  s16x8;
typedef __attribute__((ext_vector_type(4))) float  f32x4;
typedef __attribute__((ext_vector_type(4))) unsigned short u16x4;

__device__ __forceinline__ float bf2f(unsigned short u) {
    unsigned int x = ((unsigned int)u) << 16;
    return __builtin_bit_cast(float, x);
}
__device__ __forceinline__ unsigned short f2bf(float f) {
    unsigned int x = __builtin_bit_cast(unsigned int, f);
    unsigned int r = (x + 0x7FFFu + ((x >> 16) & 1u)) >> 16;   // RNE
    return (unsigned short)r;
}
__device__ __forceinline__ float gelu_f(float x) {
    // tanh-approx GELU (|err| vs exact erf-GELU ~3e-4, well under threshold)
    float y = 0.7978845608f * (x + 0.044715f * x * x * x);
    float t = 1.0f - 2.0f / (__expf(2.0f * y) + 1.0f);
    return 0.5f * x * (1.0f + t);
}

__device__ __forceinline__ float blk_sum(float v, float* sb) {
    #pragma unroll
    for (int o = 32; o; o >>= 1) v += __shfl_xor(v, o, 64);
    int w = threadIdx.x >> 6;
    __syncthreads();
    if ((threadIdx.x & 63) == 0) sb[w] = v;
    __syncthreads();
    return sb[0] + sb[1] + sb[2] + sb[3];
}

// =====================================================================
// gemm256: m201-style 8-phase 256x256xBK64 bf16 GEMM. 512 thr = 8 waves
// (2M x 4N), per-wave 128x64 out. LDS 128 KiB dbuf. K/64 must be even>=4.
// Iteration processes K-tiles (t buf0, t+1 buf1), 8 phases, each:
//   {ds_read quadrant frags | stage 1 half-tile | bar | lgkm0 | 16 MFMA | bar}
// Stage schedule (liveness-derived): ph1-2 B(t+1)->buf1, ph3-4 A(t+2)->buf0,
// ph5-6 B(t+2)->buf0, ph7-8 A(t+3)->buf1. vmcnt(4) at ph4/ph8 (the 4 newest
// outstanding loads are the A-halves staged 2 tiles ahead); vmcnt(0) at end.
// =====================================================================
template<bool GELU, bool OUTBF>
__global__ __launch_bounds__(512, 2)
void gemm256(const ushort_t* __restrict__ A, int lda,
             const ushort_t* __restrict__ BT, int ldb,
             void* __restrict__ Cv, int ldc,
             const float* __restrict__ bias,
             int M, int N, int K)
{
    int nmt = M >> 8;
    int nwg = gridDim.x * gridDim.y;
    int id  = blockIdx.x + gridDim.x * blockIdx.y;
    int swz = ((nwg & 7) == 0) ? ((id & 7) * (nwg >> 3) + (id >> 3)) : id;
    int m0 = (swz % nmt) << 8;
    int n0 = (swz / nmt) << 8;

    __shared__ __align__(16) ushort_t lA[2][256 * 64];
    __shared__ __align__(16) ushort_t lB[2][256 * 64];

    int tid  = threadIdx.x;
    int lane = tid & 63, wave = tid >> 6;
    int lr = lane & 15, lg = lane >> 4;
    int wm = wave >> 2, wn = wave & 3;

    f32x4 acc[8][4] = {};
    int nkt    = K >> 6;
    int npairs = nkt >> 1;

    // stage one half-tile: sel 0=Alo 1=Ahi 2=Blo 3=Bhi (128 rows x 64 k)
    auto stageu = [&](int buf, int kt, int sel) {
        int k0 = kt << 6;
        const ushort_t* src = (sel < 2) ? A : BT;
        int ld    = (sel < 2) ? lda : ldb;
        int rbase = ((sel < 2) ? m0 : n0) + ((sel & 1) << 7);
        ushort_t* dst = ((sel < 2) ? &lA[buf][0] : &lB[buf][0]) + ((sel & 1) << 13);
        #pragma unroll
        for (int r = 0; r < 2; ++r) {
            int e8  = r * 512 + tid;
            int row = e8 >> 3, slot = e8 & 7;
            int ls  = slot ^ (row & 7);
            const ushort_t* g = src + (size_t)(rbase + row) * ld + k0 + ls * 8;
            __builtin_amdgcn_global_load_lds(
                (const __attribute__((address_space(1))) void*)g,
                (__attribute__((address_space(3))) void*)(dst + e8 * 8), 16, 0, 0);
        }
    };
    auto rdA = [&](int buf, int row, int ks) -> s16x8 {
        int sl = (lg + ks * 4) ^ (row & 7);
        return *(const s16x8*)&lA[buf][row * 64 + sl * 8];
    };
    auto rdB = [&](int buf, int row, int ks) -> s16x8 {
        int sl = (lg + ks * 4) ^ (row & 7);
        return *(const s16x8*)&lB[buf][row * 64 + sl * 8];
    };

    // ---- prologue: A(0),B(0) full + A(1); wait A(0)+B(0) (A(1) in flight)
    stageu(0, 0, 0); stageu(0, 0, 1); stageu(0, 0, 2); stageu(0, 0, 3);
    stageu(1, 1, 0); stageu(1, 1, 1);
    asm volatile("s_waitcnt vmcnt(4)" ::: "memory");
    __builtin_amdgcn_sched_barrier(0);
    __builtin_amdgcn_s_barrier();

    for (int i = 0; i < npairs; ++i) {
        int t = 2 * i;
        bool more = (i + 1 < npairs);
        s16x8 af0[4][2], af1[4][2], bf0[2][2], bf1[2][2];

        // ==== ph1: reads af0(t)+bf0(t) [buf0]; stage Blo(t+1)->buf1
        #pragma unroll
        for (int mf = 0; mf < 4; ++mf)
            #pragma unroll
            for (int ks = 0; ks < 2; ++ks)
                af0[mf][ks] = rdA(0, wm * 128 + mf * 16 + lr, ks);
        #pragma unroll
        for (int nf = 0; nf < 2; ++nf)
            #pragma unroll
            for (int ks = 0; ks < 2; ++ks)
                bf0[nf][ks] = rdB(0, wn * 64 + nf * 16 + lr, ks);
        stageu(1, t + 1, 2);
        asm volatile("s_waitcnt lgkmcnt(8)" ::: "memory");
        __builtin_amdgcn_s_barrier();
        asm volatile("s_waitcnt lgkmcnt(0)" ::: "memory");
        __builtin_amdgcn_sched_barrier(0);
        __builtin_amdgcn_s_setprio(1);
        #pragma unroll
        for (int mf = 0; mf < 4; ++mf)
            #pragma unroll
            for (int nf = 0; nf < 2; ++nf)
                #pragma unroll
                for (int ks = 0; ks < 2; ++ks)
                    acc[mf][nf] = __builtin_amdgcn_mfma_f32_16x16x32_bf16(
                        af0[mf][ks], bf0[nf][ks], acc[mf][nf], 0, 0, 0);
        __builtin_amdgcn_s_setprio(0);
        __builtin_amdgcn_s_barrier();

        // ==== ph2: reads af1(t); stage Bhi(t+1)->buf1
        #pragma unroll
        for (int mf = 0; mf < 4; ++mf)
            #pragma unroll
            for (int ks = 0; ks < 2; ++ks)
                af1[mf][ks] = rdA(0, wm * 128 + 64 + mf * 16 + lr, ks);
        stageu(1, t + 1, 3);
        __builtin_amdgcn_s_barrier();
        asm volatile("s_waitcnt lgkmcnt(0)" ::: "memory");
        __builtin_amdgcn_sched_barrier(0);
        __builtin_amdgcn_s_setprio(1);
        #pragma unroll
        for (int mf = 0; mf < 4; ++mf)
            #pragma unroll
            for (int nf = 0; nf < 2; ++nf)
                #pragma unroll
                for (int ks = 0; ks < 2; ++ks)
                    acc[4 + mf][nf] = __builtin_amdgcn_mfma_f32_16x16x32_bf16(
                        af1[mf][ks], bf0[nf][ks], acc[4 + mf][nf], 0, 0, 0);
        __builtin_amdgcn_s_setprio(0);
        __builtin_amdgcn_s_barrier();

        // ==== ph3: reads bf1(t); stage Alo(t+2)->buf0 (A buf0 free after ph2)
        #pragma unroll
        for (int nf = 0; nf < 2; ++nf)
            #pragma unroll
            for (int ks = 0; ks < 2; ++ks)
                bf1[nf][ks] = rdB(0, wn * 64 + 32 + nf * 16 + lr, ks);
        if (more) stageu(0, t + 2, 0);
        __builtin_amdgcn_s_barrier();
        asm volatile("s_waitcnt lgkmcnt(0)" ::: "memory");
        __builtin_amdgcn_sched_barrier(0);
        __builtin_amdgcn_s_setprio(1);
        #pragma unroll
        for (int mf = 0; mf < 4; ++mf)
            #pragma unroll
            for (int nf = 0; nf < 2; ++nf)
                #pragma unroll
                for (int ks = 0; ks < 2; ++ks)
                    acc[mf][2 + nf] = __builtin_amdgcn_mfma_f32_16x16x32_bf16(
                        af0[mf][ks], bf1[nf][ks], acc[mf][2 + nf], 0, 0, 0);
        __builtin_amdgcn_s_setprio(0);
        __builtin_amdgcn_s_barrier();

        // ==== ph4: stage Ahi(t+2)->buf0; MFMA af1xbf1; vmcnt(4): A(t+1),B(t+1) in
        if (more) stageu(0, t + 2, 1);
        __builtin_amdgcn_s_barrier();
        __builtin_amdgcn_s_setprio(1);
        #pragma unroll
        for (int mf = 0; mf < 4; ++mf)
            #pragma unroll
            for (int nf = 0; nf < 2; ++nf)
                #pragma unroll
                for (int ks = 0; ks < 2; ++ks)
                    acc[4 + mf][2 + nf] = __builtin_amdgcn_mfma_f32_16x16x32_bf16(
                        af1[mf][ks], bf1[nf][ks], acc[4 + mf][2 + nf], 0, 0, 0);
        __builtin_amdgcn_s_setprio(0);
        if (more) asm volatile("s_waitcnt vmcnt(4)" ::: "memory");
        else      asm volatile("s_waitcnt vmcnt(0)" ::: "memory");
        __builtin_amdgcn_sched_barrier(0);
        __builtin_amdgcn_s_barrier();

        // ==== ph5: reads af0(t+1)+bf0(t+1) [buf1]; stage Blo(t+2)->buf0
        #pragma unroll
        for (int mf = 0; mf < 4; ++mf)
            #pragma unroll
            for (int ks = 0; ks < 2; ++ks)
                af0[mf][ks] = rdA(1, wm * 128 + mf * 16 + lr, ks);
        #pragma unroll
        for (int nf = 0; nf < 2; ++nf)
            #pragma unroll
            for (int ks = 0; ks < 2; ++ks)
                bf0[nf][ks] = rdB(1, wn * 64 + nf * 16 + lr, ks);
        if (more) stageu(0, t + 2, 2);
        asm volatile("s_waitcnt lgkmcnt(8)" ::: "memory");
        __builtin_amdgcn_s_barrier();
        asm volatile("s_waitcnt lgkmcnt(0)" ::: "memory");
        __builtin_amdgcn_sched_barrier(0);
        __builtin_amdgcn_s_setprio(1);
        #pragma unroll
        for (int mf = 0; mf < 4; ++mf)
            #pragma unroll
            for (int nf = 0; nf < 2; ++nf)
                #pragma unroll
                for (int ks = 0; ks < 2; ++ks)
                    acc[mf][nf] = __builtin_amdgcn_mfma_f32_16x16x32_bf16(
                        af0[mf][ks], bf0[nf][ks], acc[mf][nf], 0, 0, 0);
        __builtin_amdgcn_s_setprio(0);
        __builtin_amdgcn_s_barrier();

        // ==== ph6: reads af1(t+1); stage Bhi(t+2)->buf0
        #pragma unroll
        for (int mf = 0; mf < 4; ++mf)
            #pragma unroll
            for (int ks = 0; ks < 2; ++ks)
                af1[mf][ks] = rdA(1, wm * 128 + 64 + mf * 16 + lr, ks);
        if (more) stageu(0, t + 2, 3);
        __builtin_amdgcn_s_barrier();
        asm volatile("s_waitcnt lgkmcnt(0)" ::: "memory");
        __builtin_amdgcn_sched_barrier(0);
        __builtin_amdgcn_s_setprio(1);
        #pragma unroll
        for (int mf = 0; mf < 4; ++mf)
            #pragma unroll
            for (int nf = 0; nf < 2; ++nf)
                #pragma unroll
                for (int ks = 0; ks < 2; ++ks)
                    acc[4 + mf][nf] = __builtin_amdgcn_mfma_f32_16x16x32_bf16(
                        af1[mf][ks], bf0[nf][ks], acc[4 + mf][nf], 0, 0, 0);
        __builtin_amdgcn_s_setprio(0);
        __builtin_amdgcn_s_barrier();

        // ==== ph7: reads bf1(t+1); stage Alo(t+3)->buf1 (A buf1 free after ph6)
        #pragma unroll
        for (int nf = 0; nf < 2; ++nf)
            #pragma unroll
            for (int ks = 0; ks < 2; ++ks)
                bf1[nf][ks] = rdB(1, wn * 64 + 32 + nf * 16 + lr, ks);
        if (more) stageu(1, t + 3, 0);
        __builtin_amdgcn_s_barrier();
        asm volatile("s_waitcnt lgkmcnt(0)" ::: "memory");
        __builtin_amdgcn_sched_barrier(0);
        __builtin_amdgcn_s_setprio(1);
        #pragma unroll
        for (int mf = 0; mf < 4; ++mf)
            #pragma unroll
            for (int nf = 0; nf < 2; ++nf)
                #pragma unroll
                for (int ks = 0; ks < 2; ++ks)
                    acc[mf][2 + nf] = __builtin_amdgcn_mfma_f32_16x16x32_bf16(
                        af0[mf][ks], bf1[nf][ks], acc[mf][2 + nf], 0, 0, 0);
        __builtin_amdgcn_s_setprio(0);
        __builtin_amdgcn_s_barrier();

        // ==== ph8: stage Ahi(t+3)->buf1; MFMA; vmcnt(4): A(t+2),B(t+2) in
        if (more) stageu(1, t + 3, 1);
        __builtin_amdgcn_s_barrier();
        __builtin_amdgcn_s_setprio(1);
        #pragma unroll
        for (int mf = 0; mf < 4; ++mf)
            #pragma unroll
            for (int nf = 0; nf < 2; ++nf)
                #pragma unroll
                for (int ks = 0; ks < 2; ++ks)
                    acc[4 + mf][2 + nf] = __builtin_amdgcn_mfma_f32_16x16x32_bf16(
                        af1[mf][ks], bf1[nf][ks], acc[4 + mf][2 + nf], 0, 0, 0);
        __builtin_amdgcn_s_setprio(0);
        if (more) asm volatile("s_waitcnt vmcnt(4)" ::: "memory");
        else      asm volatile("s_waitcnt vmcnt(0)" ::: "memory");
        __builtin_amdgcn_sched_barrier(0);
        __builtin_amdgcn_s_barrier();
    }

    float*    Cf = (float*)Cv;
    ushort_t* Cb = (ushort_t*)Cv;
    #pragma unroll
    for (int mf = 0; mf < 8; ++mf) {
        int gm0 = m0 + wm * 128 + mf * 16 + lg * 4;
        #pragma unroll
        for (int nf = 0; nf < 4; ++nf) {
            int gn = n0 + wn * 64 + nf * 16 + lr;
            float bv = bias ? bias[gn] : 0.f;
            #pragma unroll
            for (int j = 0; j < 4; ++j) {
                float v = acc[mf][nf][j] + bv;
                if (GELU) v = gelu_f(v);
                size_t ci = (size_t)(gm0 + j) * ldc + gn;
                if (OUTBF) Cb[ci] = f2bf(v);
                else       Cf[ci] = v;
            }
        }
    }
}

// =====================================================================
// gemm_bt: 128xBNxBK32, 2-phase dbuf + 4-slot XOR swizzle. BN in {64,128}.
// VOUT: for QKV, also scatter V columns (gn>=2048) into vt[BH][HD][S].
// =====================================================================
template<int BN, bool GELU, bool RES, bool OUTBF, bool VOUT>
__global__ __launch_bounds__(256)
void gemm_bt(const ushort_t* __restrict__ A, int lda,
             const ushort_t* __restrict__ BT, int ldb,
             void* __restrict__ Cv, int ldc,
             const float* __restrict__ bias,
             const float* __restrict__ res,
             int M, int N, int K, ushort_t* __restrict__ vtp)
{
    const int BK = 32;
    const int NF = BN / 32;          // n-frags per wave
    int m0 = blockIdx.x * 128;
    int n0 = blockIdx.y * BN;

    __shared__ __align__(16) ushort_t lA[2][128 * BK];
    __shared__ __align__(16) ushort_t lB[2][BN * BK];

    int tid  = threadIdx.x;
    int lane = tid & 63;
    int wave = tid >> 6;
    int lr = lane & 15, lg = lane >> 4;
    int wr = wave >> 1, wc = wave & 1;

    f32x4 acc[4][NF] = {};
    int nkt = K / BK;

    auto stage = [&](int buf, int kt) {
        int k0 = kt * BK;
        #pragma unroll
        for (int i = 0; i < 2; ++i) {
            int e8  = i * 256 + tid;
            int row = e8 >> 2, slot = e8 & 3;
            int ls  = slot ^ (row & 3);
            const ushort_t* g = A + (size_t)(m0 + row) * lda + k0 + ls * 8;
            __builtin_amdgcn_global_load_lds(
                (const __attribute__((address_space(1))) void*)g,
                (__attribute__((address_space(3))) void*)&lA[buf][e8 * 8], 16, 0, 0);
        }
        #pragma unroll
        for (int i = 0; i < BN / 64; ++i) {
            int e8  = i * 256 + tid;
            int row = e8 >> 2, slot = e8 & 3;
            int ls  = slot ^ (row & 3);
            const ushort_t* g = BT + (size_t)(n0 + row) * ldb + k0 + ls * 8;
            __builtin_amdgcn_global_load_lds(
                (const __attribute__((address_space(1))) void*)g,
                (__attribute__((address_space(3))) void*)&lB[buf][e8 * 8], 16, 0, 0);
        }
    };

    stage(0, 0);
    __syncthreads();

    int cur = 0;
    for (int kt = 0; kt < nkt; ++kt) {
        if (kt + 1 < nkt) stage(cur ^ 1, kt + 1);
        __builtin_amdgcn_sched_barrier(0);
        s16x8 af[4], bfr[NF];
        #pragma unroll
        for (int m = 0; m < 4; ++m) {
            int row = wr * 64 + m * 16 + lr;
            int sl  = lg ^ (row & 3);
            af[m] = *(const s16x8*)&lA[cur][row * BK + sl * 8];
        }
        #pragma unroll
        for (int n = 0; n < NF; ++n) {
            int row = wc * (BN / 2) + n * 16 + lr;
            int sl  = lg ^ (row & 3);
            bfr[n] = *(const s16x8*)&lB[cur][row * BK + sl * 8];
        }
        #pragma unroll
        for (int m = 0; m < 4; ++m)
            #pragma unroll
            for (int n = 0; n < NF; ++n)
                acc[m][n] = __builtin_amdgcn_mfma_f32_16x16x32_bf16(
                    af[m], bfr[n], acc[m][n], 0, 0, 0);
        __syncthreads();
        cur ^= 1;
    }

    float*    Cf = (float*)Cv;
    ushort_t* Cb = (ushort_t*)Cv;
    #pragma unroll
    for (int m = 0; m < 4; ++m) {
        int gm0 = m0 + wr * 64 + m * 16 + lg * 4;
        #pragma unroll
        for (int n = 0; n < NF; ++n) {
            int gn = n0 + wc * (BN / 2) + n * 16 + lr;
            #pragma unroll
            for (int j = 0; j < 4; ++j) {
                float v = acc[m][n][j];
                if (bias) v += bias[gn];
                size_t ci = (size_t)(gm0 + j) * ldc + gn;
                if (RES)  v += res[ci];
                if (GELU) v = gelu_f(v);
                if (OUTBF) Cb[ci] = f2bf(v);
                else       Cf[ci] = v;
                if (VOUT && gn >= 2048) {
                    int hv = gn - 2048;
                    int mm = gm0 + j;
                    vtp[((size_t)(((mm >> 10) << 4) + (hv >> 6)) * 64
                         + (hv & 63)) * 1024 + (mm & 1023)] = f2bf(v);
                }
            }
        }
    }
}

// =====================================================================
// Flash attention: one block = (b,h) x 64-row Q tile. 4 waves.
// =====================================================================
__global__ __launch_bounds__(256)
void flash_attn(const ushort_t* __restrict__ qkv,
                const ushort_t* __restrict__ vt,
                ushort_t* __restrict__ ctx)
{
    const int QB = 64, KB = 64;
    int z  = blockIdx.y;            // b*H + h
    int b  = z >> 4, hh = z & 15;
    int q0 = blockIdx.x * QB;

    __shared__ __align__(16) ushort_t Qs[QB * 64];
    __shared__ __align__(16) ushort_t Ks[KB * 64];
    __shared__ __align__(16) ushort_t Vs[64 * KB];
    __shared__ float    Ss[QB][68];
    __shared__ __align__(16) ushort_t Ps[QB][72];
    __shared__ float mrow[QB], lrow[QB], arow[QB];

    int tid  = threadIdx.x;
    int lane = tid & 63, wave = tid >> 6;
    int lr = lane & 15, lg = lane >> 4;

    if (tid < QB) { mrow[tid] = -1e30f; lrow[tid] = 0.f; }

    const ushort_t* qbase = qkv + (size_t)(b * S_ + q0) * 3072 + hh * HD_;
    #pragma unroll
    for (int rnd = 0; rnd < 2; ++rnd) {
        int e8   = rnd * 256 + tid;
        int row  = e8 >> 3;
        int slot = e8 & 7;
        int ls   = slot ^ (row & 7);
        const ushort_t* g = qbase + (size_t)row * 3072 + ls * 8;
        __builtin_amdgcn_global_load_lds(
            (const __attribute__((address_space(1))) void*)g,
            (__attribute__((address_space(3))) void*)&Qs[e8 * 8], 16, 0, 0);
    }
    __syncthreads();

    s16x8 qa[4][2];
    #pragma unroll
    for (int mf = 0; mf < 4; ++mf)
        #pragma unroll
        for (int ks = 0; ks < 2; ++ks) {
            int row = mf * 16 + lr;
            int sl  = (lg + ks * 4) ^ (row & 7);
            qa[mf][ks] = *(const s16x8*)&Qs[row * 64 + sl * 8];
        }

    f32x4 acc[4] = {};
    int r = tid >> 2, p = tid & 3;

    int kv_end = q0 + QB;
    for (int kv0 = 0; kv0 < kv_end; kv0 += KB) {
        const ushort_t* kbase = qkv + (size_t)(b * S_ + kv0) * 3072 + 1024 + hh * HD_;
        const ushort_t* vbase = vt + (size_t)z * HD_ * S_ + kv0;
        #pragma unroll
        for (int rnd = 0; rnd < 2; ++rnd) {
            int e8 = rnd * 256 + tid;
            int row = e8 >> 3, slot = e8 & 7;
            int ls = slot ^ (row & 7);
            const ushort_t* gk = kbase + (size_t)row * 3072 + ls * 8;
            __builtin_amdgcn_global_load_lds(
                (const __attribute__((address_space(1))) void*)gk,
                (__attribute__((address_space(3))) void*)&Ks[e8 * 8], 16, 0, 0);
            const ushort_t* gv = vbase + (size_t)row * S_ + ls * 8;
            __builtin_amdgcn_global_load_lds(
                (const __attribute__((address_space(1))) void*)gv,
                (__attribute__((address_space(3))) void*)&Vs[e8 * 8], 16, 0, 0);
        }
        __syncthreads();

        s16x8 kb[2];
        #pragma unroll
        for (int ks = 0; ks < 2; ++ks) {
            int row = wave * 16 + lr;
            int sl  = (lg + ks * 4) ^ (row & 7);
            kb[ks] = *(const s16x8*)&Ks[row * 64 + sl * 8];
        }
        f32x4 sa[4] = {};
        #pragma unroll
        for (int mf = 0; mf < 4; ++mf)
            #pragma unroll
            for (int ks = 0; ks < 2; ++ks)
                sa[mf] = __builtin_amdgcn_mfma_f32_16x16x32_bf16(
                    qa[mf][ks], kb[ks], sa[mf], 0, 0, 0);

        int ki = kv0 + wave * 16 + lr;
        #pragma unroll
        for (int mf = 0; mf < 4; ++mf)
            #pragma unroll
            for (int j = 0; j < 4; ++j) {
                int qi = q0 + mf * 16 + lg * 4 + j;
                float s = (ki <= qi) ? sa[mf][j] * 0.125f : -1e30f;
                Ss[mf * 16 + lg * 4 + j][wave * 16 + lr] = s;
            }
        __syncthreads();

        float mo = mrow[r];
        float sv[16];
        float pm = -1e30f;
        #pragma unroll
        for (int i = 0; i < 16; ++i) {
            sv[i] = Ss[r][p * 16 + i];
            pm = fmaxf(pm, sv[i]);
        }
        pm = fmaxf(pm, __shfl_xor(pm, 1, 64));
        pm = fmaxf(pm, __shfl_xor(pm, 2, 64));
        float M = fmaxf(mo, pm);
        float sum = 0.f;
        s16x8 pk0, pk1;
        #pragma unroll
        for (int i = 0; i < 8; ++i) {
            float e0 = __expf(sv[i] - M);
            float e1 = __expf(sv[i + 8] - M);
            sum += e0 + e1;
            pk0[i] = (short)f2bf(e0);
            pk1[i] = (short)f2bf(e1);
        }
        *(s16x8*)&Ps[r][p * 16]     = pk0;
        *(s16x8*)&Ps[r][p * 16 + 8] = pk1;
        sum += __shfl_xor(sum, 1, 64);
        sum += __shfl_xor(sum, 2, 64);
        if (p == 0) {
            float al = __expf(mo - M);
            arow[r] = al;
            mrow[r] = M;
            lrow[r] = lrow[r] * al + sum;
        }
        __syncthreads();

        #pragma unroll
        for (int mf = 0; mf < 4; ++mf) {
            #pragma unroll
            for (int j = 0; j < 4; ++j)
                acc[mf][j] *= arow[mf * 16 + lg * 4 + j];
        }
        s16x8 vb[2];
        #pragma unroll
        for (int ks = 0; ks < 2; ++ks) {
            int row = wave * 16 + lr;
            int sl  = (lg + ks * 4) ^ (row & 7);
            vb[ks] = *(const s16x8*)&Vs[row * 64 + sl * 8];
        }
        #pragma unroll
        for (int mf = 0; mf < 4; ++mf)
            #pragma unroll
            for (int ks = 0; ks < 2; ++ks) {
                s16x8 pa = *(const s16x8*)((const char*)&Ps[0][0]
                            + (mf * 16 + lr) * 144 + lg * 16 + ks * 64);
                acc[mf] = __builtin_amdgcn_mfma_f32_16x16x32_bf16(
                    pa, vb[ks], acc[mf], 0, 0, 0);
            }
        __syncthreads();
    }

    #pragma unroll
    for (int mf = 0; mf < 4; ++mf)
        #pragma unroll
        for (int j = 0; j < 4; ++j) {
            int rr = mf * 16 + lg * 4 + j;
            float o = acc[mf][j] / lrow[rr];
            ctx[(size_t)(b * S_ + q0 + rr) * D_ + hh * HD_ + wave * 16 + lr] = f2bf(o);
        }
}

// =====================================================================
// prep_layer: all weight transposes+converts for one layer + qkv bias
// concat in ONE launch. 12291 blocks x 256 thr.
// =====================================================================
__global__ __launch_bounds__(256)
void prep_layer(const float* __restrict__ Wq, const float* __restrict__ Wk,
                const float* __restrict__ Wv, const float* __restrict__ Wo,
                const float* __restrict__ W1, const float* __restrict__ W2,
                const float* __restrict__ bq, const float* __restrict__ bk,
                const float* __restrict__ bv,
                ushort_t* __restrict__ wqkvT, ushort_t* __restrict__ woT,
                ushort_t* __restrict__ w1T, ushort_t* __restrict__ w2T,
                float* __restrict__ qkvb)
{
    int bid = blockIdx.x;
    if (bid >= 12288) {
        int j = bid - 12288;
        const float* bsrc = (j == 0) ? bq : (j == 1) ? bk : bv;
        int c = threadIdx.x * 4;
        *(f32x4*)&qkvb[j * 1024 + c] = *(const f32x4*)&bsrc[c];
        return;
    }
    __shared__ float t[32][33];
    int tx = threadIdx.x & 31, ty = threadIdx.x >> 5;
    const float* src; ushort_t* dst; int R, C, c0, r0;
    if (bid < 4096) {
        int mat = bid >> 10, tnum = bid & 1023;
        src = (mat == 0) ? Wq : (mat == 1) ? Wk : (mat == 2) ? Wv : Wo;
        dst = (mat < 3) ? (wqkvT + (size_t)mat * D_ * D_) : woT;
        R = D_; C = D_;
        c0 = (tnum & 31) * 32; r0 = (tnum >> 5) * 32;
    } else if (bid < 8192) {
        int tnum = bid - 4096;
        src = W1; dst = w1T; R = D_; C = F_;
        c0 = (tnum & 127) * 32; r0 = (tnum >> 7) * 32;
    } else {
        int tnum = bid - 8192;
        src = W2; dst = w2T; R = F_; C = D_;
        c0 = (tnum & 31) * 32; r0 = (tnum >> 5) * 32;
    }
    #pragma unroll
    for (int i = 0; i < 4; ++i)
        t[ty + i * 8][tx] = src[(size_t)(r0 + ty + i * 8) * C + c0 + tx];
    __syncthreads();
    #pragma unroll
    for (int i = 0; i < 4; ++i)
        dst[(size_t)(c0 + ty + i * 8) * R + r0 + tx] = f2bf(t[tx][ty + i * 8]);
}

// ---- f32 [R,C] -> bf16 [C,R] transpose-convert (Wout) ----
__global__ __launch_bounds__(256)
void tconv(const float* __restrict__ in, ushort_t* __restrict__ out, int R, int C)
{
    __shared__ float t[32][33];
    int c0 = blockIdx.x * 32, r0 = blockIdx.y * 32;
    int tx = threadIdx.x & 31, ty = threadIdx.x >> 5;
    #pragma unroll
    for (int i = 0; i < 4; ++i)
        t[ty + i * 8][tx] = in[(size_t)(r0 + ty + i * 8) * C + c0 + tx];
    __syncthreads();
    #pragma unroll
    for (int i = 0; i < 4; ++i)
        out[(size_t)(c0 + ty + i * 8) * R + r0 + tx] = f2bf(t[tx][ty + i * 8]);
}

// ---- embedding * sqrt(D) + sinusoidal PE -> x (f32) ----
__global__ __launch_bounds__(256)
void embed_pe(const int* __restrict__ ids, const float* __restrict__ emb,
              float* __restrict__ x)
{
    int row = blockIdx.x;
    int s   = row & (S_ - 1);
    int id  = ids[row];
    int d   = threadIdx.x * 4;
    f32x4 ev = *(const f32x4*)&emb[(size_t)id * D_ + d];
    f32x4 o;
    #pragma unroll
    for (int j = 0; j < 4; ++j) {
        int dd = d + j;
        int i  = dd >> 1;
        float div = expf(-(float)(2 * i) * (9.210340371976184f / 1024.0f));
        float arg = (float)s * div;
        float pe  = (dd & 1) ? cosf(arg) : sinf(arg);
        o[j] = ev[j] * 32.0f + pe;
    }
    *(f32x4*)&x[(size_t)row * D_ + d] = o;
}

// ---- LayerNorm row kernel: f32 in -> bf16 out ----
__global__ __launch_bounds__(256)
void ln_kernel(const float* __restrict__ x, const float* __restrict__ g,
               const float* __restrict__ b, ushort_t* __restrict__ out)
{
    __shared__ float sb[4];
    int row = blockIdx.x;
    const float* xr = x + (size_t)row * D_;
    int c = threadIdx.x * 4;
    f32x4 v = *(const f32x4*)&xr[c];
    float s = v[0] + v[1] + v[2] + v[3];
    s = blk_sum(s, sb);
    float mean = s * (1.0f / D_);
    f32x4 dv = v - mean;
    float sq = dv[0]*dv[0] + dv[1]*dv[1] + dv[2]*dv[2] + dv[3]*dv[3];
    sq = blk_sum(sq, sb);
    float rstd = rsqrtf(sq * (1.0f / D_) + EPSLN);
    u16x4 o;
    #pragma unroll
    for (int j = 0; j < 4; ++j)
        o[j] = f2bf(dv[j] * rstd * g[c + j] + b[c + j]);
    *(u16x4*)&out[(size_t)row * D_ + c] = o;
}

__global__ void ws_marker(float* o) { o[threadIdx.x] = -777777.0f; }

// =====================================================================
extern "C" void kernel_launch(void* const* d_in, const int* in_sizes, int n_in,
                              void* d_out, int out_size, void* d_ws, size_t ws_size,
                              hipStream_t stream)
{
    (void)in_sizes; (void)n_in; (void)out_size;
    const int*   ids  = (const int*)d_in[0];
    const float* emb  = (const float*)d_in[1];
    const float* Wq   = (const float*)d_in[2];
    const float* bq   = (const float*)d_in[3];
    const float* Wk   = (const float*)d_in[4];
    const float* bk   = (const float*)d_in[5];
    const float* Wv   = (const float*)d_in[6];
    const float* bv   = (const float*)d_in[7];
    const float* Wo   = (const float*)d_in[8];
    const float* bo   = (const float*)d_in[9];
    const float* ln1g = (const float*)d_in[10];
    const float* ln1b = (const float*)d_in[11];
    const float* ln2g = (const float*)d_in[12];
    const float* ln2b = (const float*)d_in[13];
    const float* W1   = (const float*)d_in[14];
    const float* b1   = (const float*)d_in[15];
    const float* W2   = (const float*)d_in[16];
    const float* b2   = (const float*)d_in[17];
    const float* fng  = (const float*)d_in[18];
    const float* fnb  = (const float*)d_in[19];
    const float* Wout = (const float*)d_in[20];
    const float* bout = (const float*)d_in[21];
    float* out = (float*)d_out;

    // ---- workspace layout ----
    char* base = (char*)d_ws;
    size_t off = 0;
    float*    x    = (float*)(base + off);    off += (size_t)MTOK * D_ * 4;
    ushort_t* h    = (ushort_t*)(base + off); off += (size_t)MTOK * D_ * 2;
    ushort_t* qkv  = (ushort_t*)(base + off); off += (size_t)MTOK * 3 * D_ * 2;
    ushort_t* vt   = (ushort_t*)(base + off); off += (size_t)B_ * H_ * HD_ * S_ * 2;
    ushort_t* ctx  = (ushort_t*)(base + off); off += (size_t)MTOK * D_ * 2;
    ushort_t* ff   = (ushort_t*)(base + off); off += (size_t)MTOK * F_ * 2;
    float*    qkvb = (float*)(base + off);    off += 3072 * 4;
    ushort_t* wqkvT= (ushort_t*)(base + off); off += (size_t)3 * D_ * D_ * 2;
    ushort_t* woT  = (ushort_t*)(base + off); off += (size_t)D_ * D_ * 2;
    ushort_t* w1T  = (ushort_t*)(base + off); off += (size_t)D_ * F_ * 2;
    ushort_t* w2T  = (ushort_t*)(base + off); off += (size_t)F_ * D_ * 2;
    ushort_t* wouT = (ushort_t*)(base + off); off += (size_t)V_ * D_ * 2;
    if (ws_size < off) { ws_marker<<<1, 64, 0, stream>>>(out); return; }

    embed_pe<<<MTOK, 256, 0, stream>>>(ids, emb, x);

    for (int i = 0; i < L_; ++i) {
        prep_layer<<<12291, 256, 0, stream>>>(
            Wq + (size_t)i * D_ * D_, Wk + (size_t)i * D_ * D_,
            Wv + (size_t)i * D_ * D_, Wo + (size_t)i * D_ * D_,
            W1 + (size_t)i * D_ * F_, W2 + (size_t)i * F_ * D_,
            bq + i * D_, bk + i * D_, bv + i * D_,
            wqkvT, woT, w1T, w2T, qkvb);

        ln_kernel<<<MTOK, 256, 0, stream>>>(x, ln1g + i * D_, ln1b + i * D_, h);

        // qkv = h @ [Wq|Wk|Wv] + bias; V cols also scattered into vt
        gemm_bt<128,false,false,true,true><<<dim3(16, 24), 256, 0, stream>>>(
            h, D_, wqkvT, D_, qkv, 3 * D_, qkvb, nullptr, MTOK, 3 * D_, D_, vt);

        flash_attn<<<dim3(S_ / 64, B_ * H_), 256, 0, stream>>>(qkv, vt, ctx);

        // x = x + ctx @ Wo + bo   (BN=64 -> 256 blocks, full fill)
        gemm_bt<64,false,true,false,false><<<dim3(16, 16), 256, 0, stream>>>(
            ctx, D_, woT, D_, x, D_, bo + i * D_, x, MTOK, D_, D_, nullptr);

        ln_kernel<<<MTOK, 256, 0, stream>>>(x, ln2g + i * D_, ln2b + i * D_, h);

        // ff = gelu(h @ W1 + b1)
        gemm_bt<128,true,false,true,false><<<dim3(16, 32), 256, 0, stream>>>(
            h, D_, w1T, D_, ff, F_, b1 + i * F_, nullptr, MTOK, F_, D_, nullptr);

        // x = x + ff @ W2 + b2   (BN=64 -> 256 blocks, full fill)
        gemm_bt<64,false,true,false,false><<<dim3(16, 16), 256, 0, stream>>>(
            ff, F_, w2T, F_, x, D_, b2 + i * D_, x, MTOK, D_, F_, nullptr);
    }

    ln_kernel<<<MTOK, 256, 0, stream>>>(x, fng, fnb, h);
    tconv<<<dim3(1000, 32), 256, 0, stream>>>(Wout, wouT, D_, V_);
    gemm256<false,false><<<dim3(8, 125), 512, 0, stream>>>(
        h, D_, wouT, D_, out, V_, bout, MTOK, V_, D_);
}

// Round 7
// 1604.027 us; speedup vs baseline: 1.7408x; 1.0218x over previous
//
#include <hip/hip_runtime.h>
#include <math.h>

// ---- problem constants ----
#define V_   32000
#define D_   1024
#define H_   16
#define HD_  64
#define L_   6
#define F_   4096
#define S_   1024
#define B_   2
#define MTOK (B_*S_)      // 2048
#define EPSLN 1e-5f

typedef unsigned short ushort_t;
typedef __attribute__((ext_vector_type(8))) short  s16x8;
typedef __attribute__((ext_vector_type(4))) float  f32x4;
typedef __attribute__((ext_vector_type(4))) unsigned short u16x4;

__device__ __forceinline__ float bf2f(unsigned short u) {
    unsigned int x = ((unsigned int)u) << 16;
    return __builtin_bit_cast(float, x);
}
__device__ __forceinline__ unsigned short f2bf(float f) {
    unsigned int x = __builtin_bit_cast(unsigned int, f);
    unsigned int r = (x + 0x7FFFu + ((x >> 16) & 1u)) >> 16;   // RNE
    return (unsigned short)r;
}
__device__ __forceinline__ float gelu_f(float x) {
    float y = 0.7978845608f * (x + 0.044715f * x * x * x);
    float t = 1.0f - 2.0f / (__expf(2.0f * y) + 1.0f);
    return 0.5f * x * (1.0f + t);
}

__device__ __forceinline__ float blk_sum(float v, float* sb) {
    #pragma unroll
    for (int o = 32; o; o >>= 1) v += __shfl_xor(v, o, 64);
    int w = threadIdx.x >> 6;
    __syncthreads();
    if ((threadIdx.x & 63) == 0) sb[w] = v;
    __syncthreads();
    return sb[0] + sb[1] + sb[2] + sb[3];
}

// =====================================================================
// gemm256: 2-phase-per-K-tile pipelined 256x256xBK64 bf16 MFMA GEMM.
// (round-5 measured-best structure: 177us on logits)
// =====================================================================
template<bool GELU, bool OUTBF>
__global__ __launch_bounds__(512, 2)
void gemm256(const ushort_t* __restrict__ A, int lda,
             const ushort_t* __restrict__ BT, int ldb,
             void* __restrict__ Cv, int ldc,
             const float* __restrict__ bias,
             int M, int N, int K)
{
    int nmt = M >> 8;
    int nwg = gridDim.x * gridDim.y;
    int id  = blockIdx.x + gridDim.x * blockIdx.y;
    int swz = ((nwg & 7) == 0) ? ((id & 7) * (nwg >> 3) + (id >> 3)) : id;
    int m0 = (swz % nmt) << 8;
    int n0 = (swz / nmt) << 8;

    __shared__ __align__(16) ushort_t lA[2][256 * 64];
    __shared__ __align__(16) ushort_t lB[2][256 * 64];

    int tid  = threadIdx.x;
    int lane = tid & 63, wave = tid >> 6;
    int lr = lane & 15, lg = lane >> 4;
    int wm = wave >> 2, wn = wave & 3;

    f32x4 acc[8][4] = {};
    int nkt = K >> 6;

    auto stageu = [&](int buf, int kt, int sel) {
        int k0 = kt << 6;
        const ushort_t* src = (sel < 2) ? A : BT;
        int ld    = (sel < 2) ? lda : ldb;
        int rbase = ((sel < 2) ? m0 : n0) + ((sel & 1) << 7);
        ushort_t* dst = ((sel < 2) ? &lA[buf][0] : &lB[buf][0]) + ((sel & 1) << 13);
        #pragma unroll
        for (int r = 0; r < 2; ++r) {
            int e8  = r * 512 + tid;
            int row = e8 >> 3, slot = e8 & 7;
            int ls  = slot ^ (row & 7);
            const ushort_t* g = src + (size_t)(rbase + row) * ld + k0 + ls * 8;
            __builtin_amdgcn_global_load_lds(
                (const __attribute__((address_space(1))) void*)g,
                (__attribute__((address_space(3))) void*)(dst + e8 * 8), 16, 0, 0);
        }
    };
    auto rdA = [&](int buf, int row, int ks) -> s16x8 {
        int sl = (lg + ks * 4) ^ (row & 7);
        return *(const s16x8*)&lA[buf][row * 64 + sl * 8];
    };
    auto rdB = [&](int buf, int row, int ks) -> s16x8 {
        int sl = (lg + ks * 4) ^ (row & 7);
        return *(const s16x8*)&lB[buf][row * 64 + sl * 8];
    };

    // ---- prologue: A(0), B(0) fully; B(1); wait A(0)+B(0) (B(1) in flight)
    stageu(0, 0, 0); stageu(0, 0, 1); stageu(0, 0, 2); stageu(0, 0, 3);
    if (nkt > 1) {
        stageu(1, 1, 2); stageu(1, 1, 3);
        asm volatile("s_waitcnt vmcnt(4)" ::: "memory");
    } else {
        asm volatile("s_waitcnt vmcnt(0)" ::: "memory");
    }
    __builtin_amdgcn_sched_barrier(0);
    __builtin_amdgcn_s_barrier();

    for (int u = 0; u < nkt; ++u) {
        int cur = u & 1, nxt = cur ^ 1;
        s16x8 af0[4][2], af1[4][2], bf0[2][2], bf1[2][2];

        // ======== Phase A: af0 + bf0 + bf1 reads; stage A(u+1) ========
        #pragma unroll
        for (int mf = 0; mf < 4; ++mf)
            #pragma unroll
            for (int ks = 0; ks < 2; ++ks)
                af0[mf][ks] = rdA(cur, wm * 128 + mf * 16 + lr, ks);
        #pragma unroll
        for (int nf = 0; nf < 2; ++nf)
            #pragma unroll
            for (int ks = 0; ks < 2; ++ks) {
                bf0[nf][ks] = rdB(cur, wn * 64 + nf * 16 + lr, ks);
                bf1[nf][ks] = rdB(cur, wn * 64 + 32 + nf * 16 + lr, ks);
            }
        if (u + 1 < nkt) { stageu(nxt, u + 1, 0); stageu(nxt, u + 1, 1); }
        __builtin_amdgcn_s_barrier();
        asm volatile("s_waitcnt lgkmcnt(0)" ::: "memory");
        __builtin_amdgcn_sched_barrier(0);
        __builtin_amdgcn_s_setprio(1);
        #pragma unroll
        for (int mf = 0; mf < 4; ++mf)
            #pragma unroll
            for (int ks = 0; ks < 2; ++ks) {
                #pragma unroll
                for (int nf = 0; nf < 2; ++nf) {
                    acc[mf][nf]     = __builtin_amdgcn_mfma_f32_16x16x32_bf16(
                        af0[mf][ks], bf0[nf][ks], acc[mf][nf], 0, 0, 0);
                    acc[mf][2 + nf] = __builtin_amdgcn_mfma_f32_16x16x32_bf16(
                        af0[mf][ks], bf1[nf][ks], acc[mf][2 + nf], 0, 0, 0);
                }
            }
        __builtin_amdgcn_s_setprio(0);
        __builtin_amdgcn_s_barrier();

        // ======== Phase B: af1 reads; stage B(u+2) into cur ========
        #pragma unroll
        for (int mf = 0; mf < 4; ++mf)
            #pragma unroll
            for (int ks = 0; ks < 2; ++ks)
                af1[mf][ks] = rdA(cur, wm * 128 + 64 + mf * 16 + lr, ks);
        if (u + 2 < nkt) { stageu(cur, u + 2, 2); stageu(cur, u + 2, 3); }
        __builtin_amdgcn_s_barrier();
        asm volatile("s_waitcnt lgkmcnt(0)" ::: "memory");
        __builtin_amdgcn_sched_barrier(0);
        __builtin_amdgcn_s_setprio(1);
        #pragma unroll
        for (int mf = 0; mf < 4; ++mf)
            #pragma unroll
            for (int ks = 0; ks < 2; ++ks) {
                #pragma unroll
                for (int nf = 0; nf < 2; ++nf) {
                    acc[4 + mf][nf]     = __builtin_amdgcn_mfma_f32_16x16x32_bf16(
                        af1[mf][ks], bf0[nf][ks], acc[4 + mf][nf], 0, 0, 0);
                    acc[4 + mf][2 + nf] = __builtin_amdgcn_mfma_f32_16x16x32_bf16(
                        af1[mf][ks], bf1[nf][ks], acc[4 + mf][2 + nf], 0, 0, 0);
                }
            }
        __builtin_amdgcn_s_setprio(0);
        if (u + 2 < nkt) asm volatile("s_waitcnt vmcnt(4)" ::: "memory");
        else             asm volatile("s_waitcnt vmcnt(0)" ::: "memory");
        __builtin_amdgcn_sched_barrier(0);
        __builtin_amdgcn_s_barrier();
    }

    float*    Cf = (float*)Cv;
    ushort_t* Cb = (ushort_t*)Cv;
    #pragma unroll
    for (int mf = 0; mf < 8; ++mf) {
        int gm0 = m0 + wm * 128 + mf * 16 + lg * 4;
        #pragma unroll
        for (int nf = 0; nf < 4; ++nf) {
            int gn = n0 + wn * 64 + nf * 16 + lr;
            float bv = bias ? bias[gn] : 0.f;
            #pragma unroll
            for (int j = 0; j < 4; ++j) {
                float v = acc[mf][nf][j] + bv;
                if (GELU) v = gelu_f(v);
                size_t ci = (size_t)(gm0 + j) * ldc + gn;
                if (OUTBF) Cb[ci] = f2bf(v);
                else       Cf[ci] = v;
            }
        }
    }
}

// =====================================================================
// gemm_bt: 128xBNxBK32, 2-phase dbuf + 4-slot XOR swizzle. BN in {64,128}.
// VOUT: for QKV, also scatter V columns (gn>=2048) into vt[BH][HD][S].
// =====================================================================
template<int BN, bool GELU, bool RES, bool OUTBF, bool VOUT>
__global__ __launch_bounds__(256)
void gemm_bt(const ushort_t* __restrict__ A, int lda,
             const ushort_t* __restrict__ BT, int ldb,
             void* __restrict__ Cv, int ldc,
             const float* __restrict__ bias,
             const float* __restrict__ res,
             int M, int N, int K, ushort_t* __restrict__ vtp)
{
    const int BK = 32;
    const int NF = BN / 32;
    int m0 = blockIdx.x * 128;
    int n0 = blockIdx.y * BN;

    __shared__ __align__(16) ushort_t lA[2][128 * BK];
    __shared__ __align__(16) ushort_t lB[2][BN * BK];

    int tid  = threadIdx.x;
    int lane = tid & 63;
    int wave = tid >> 6;
    int lr = lane & 15, lg = lane >> 4;
    int wr = wave >> 1, wc = wave & 1;

    f32x4 acc[4][NF] = {};
    int nkt = K / BK;

    auto stage = [&](int buf, int kt) {
        int k0 = kt * BK;
        #pragma unroll
        for (int i = 0; i < 2; ++i) {
            int e8  = i * 256 + tid;
            int row = e8 >> 2, slot = e8 & 3;
            int ls  = slot ^ (row & 3);
            const ushort_t* g = A + (size_t)(m0 + row) * lda + k0 + ls * 8;
            __builtin_amdgcn_global_load_lds(
                (const __attribute__((address_space(1))) void*)g,
                (__attribute__((address_space(3))) void*)&lA[buf][e8 * 8], 16, 0, 0);
        }
        #pragma unroll
        for (int i = 0; i < BN / 64; ++i) {
            int e8  = i * 256 + tid;
            int row = e8 >> 2, slot = e8 & 3;
            int ls  = slot ^ (row & 3);
            const ushort_t* g = BT + (size_t)(n0 + row) * ldb + k0 + ls * 8;
            __builtin_amdgcn_global_load_lds(
                (const __attribute__((address_space(1))) void*)g,
                (__attribute__((address_space(3))) void*)&lB[buf][e8 * 8], 16, 0, 0);
        }
    };

    stage(0, 0);
    __syncthreads();

    int cur = 0;
    for (int kt = 0; kt < nkt; ++kt) {
        if (kt + 1 < nkt) stage(cur ^ 1, kt + 1);
        __builtin_amdgcn_sched_barrier(0);
        s16x8 af[4], bfr[NF];
        #pragma unroll
        for (int m = 0; m < 4; ++m) {
            int row = wr * 64 + m * 16 + lr;
            int sl  = lg ^ (row & 3);
            af[m] = *(const s16x8*)&lA[cur][row * BK + sl * 8];
        }
        #pragma unroll
        for (int n = 0; n < NF; ++n) {
            int row = wc * (BN / 2) + n * 16 + lr;
            int sl  = lg ^ (row & 3);
            bfr[n] = *(const s16x8*)&lB[cur][row * BK + sl * 8];
        }
        #pragma unroll
        for (int m = 0; m < 4; ++m)
            #pragma unroll
            for (int n = 0; n < NF; ++n)
                acc[m][n] = __builtin_amdgcn_mfma_f32_16x16x32_bf16(
                    af[m], bfr[n], acc[m][n], 0, 0, 0);
        __syncthreads();
        cur ^= 1;
    }

    float*    Cf = (float*)Cv;
    ushort_t* Cb = (ushort_t*)Cv;
    #pragma unroll
    for (int m = 0; m < 4; ++m) {
        int gm0 = m0 + wr * 64 + m * 16 + lg * 4;
        #pragma unroll
        for (int n = 0; n < NF; ++n) {
            int gn = n0 + wc * (BN / 2) + n * 16 + lr;
            #pragma unroll
            for (int j = 0; j < 4; ++j) {
                float v = acc[m][n][j];
                if (bias) v += bias[gn];
                size_t ci = (size_t)(gm0 + j) * ldc + gn;
                if (RES)  v += res[ci];
                if (GELU) v = gelu_f(v);
                if (OUTBF) Cb[ci] = f2bf(v);
                else       Cf[ci] = v;
                if (VOUT && gn >= 2048) {
                    int hv = gn - 2048;
                    int mm = gm0 + j;
                    vtp[((size_t)(((mm >> 10) << 4) + (hv >> 6)) * 64
                         + (hv & 63)) * 1024 + (mm & 1023)] = f2bf(v);
                }
            }
        }
    }
}

// =====================================================================
// Flash attention: one block = (b,h) x 64-row Q tile. 4 waves.
// K/V double-buffered in LDS; next tile prefetched at iteration top so
// the end-of-iter barrier drain is free (loads land under softmax+PV).
// =====================================================================
__global__ __launch_bounds__(256)
void flash_attn(const ushort_t* __restrict__ qkv,
                const ushort_t* __restrict__ vt,
                ushort_t* __restrict__ ctx)
{
    const int QB = 64, KB = 64;
    int z  = blockIdx.y;            // b*H + h
    int b  = z >> 4, hh = z & 15;
    int q0 = blockIdx.x * QB;

    __shared__ __align__(16) ushort_t Qs[QB * 64];
    __shared__ __align__(16) ushort_t Ks[2][KB * 64];
    __shared__ __align__(16) ushort_t Vs[2][64 * KB];
    __shared__ float    Ss[QB][68];
    __shared__ __align__(16) ushort_t Ps[QB][72];
    __shared__ float mrow[QB], lrow[QB], arow[QB];

    int tid  = threadIdx.x;
    int lane = tid & 63, wave = tid >> 6;
    int lr = lane & 15, lg = lane >> 4;

    if (tid < QB) { mrow[tid] = -1e30f; lrow[tid] = 0.f; }

    auto stageKV = [&](int buf, int kv0) {
        const ushort_t* kbase = qkv + (size_t)(b * S_ + kv0) * 3072 + 1024 + hh * HD_;
        const ushort_t* vbase = vt + (size_t)z * HD_ * S_ + kv0;
        #pragma unroll
        for (int rnd = 0; rnd < 2; ++rnd) {
            int e8 = rnd * 256 + tid;
            int row = e8 >> 3, slot = e8 & 7;
            int ls = slot ^ (row & 7);
            const ushort_t* gk = kbase + (size_t)row * 3072 + ls * 8;
            __builtin_amdgcn_global_load_lds(
                (const __attribute__((address_space(1))) void*)gk,
                (__attribute__((address_space(3))) void*)&Ks[buf][e8 * 8], 16, 0, 0);
            const ushort_t* gv = vbase + (size_t)row * S_ + ls * 8;
            __builtin_amdgcn_global_load_lds(
                (const __attribute__((address_space(1))) void*)gv,
                (__attribute__((address_space(3))) void*)&Vs[buf][e8 * 8], 16, 0, 0);
        }
    };

    // ---- prologue: Q tile + KV tile 0 ----
    const ushort_t* qbase = qkv + (size_t)(b * S_ + q0) * 3072 + hh * HD_;
    #pragma unroll
    for (int rnd = 0; rnd < 2; ++rnd) {
        int e8   = rnd * 256 + tid;
        int row  = e8 >> 3;
        int slot = e8 & 7;
        int ls   = slot ^ (row & 7);
        const ushort_t* g = qbase + (size_t)row * 3072 + ls * 8;
        __builtin_amdgcn_global_load_lds(
            (const __attribute__((address_space(1))) void*)g,
            (__attribute__((address_space(3))) void*)&Qs[e8 * 8], 16, 0, 0);
    }
    stageKV(0, 0);
    __syncthreads();

    s16x8 qa[4][2];
    #pragma unroll
    for (int mf = 0; mf < 4; ++mf)
        #pragma unroll
        for (int ks = 0; ks < 2; ++ks) {
            int row = mf * 16 + lr;
            int sl  = (lg + ks * 4) ^ (row & 7);
            qa[mf][ks] = *(const s16x8*)&Qs[row * 64 + sl * 8];
        }

    f32x4 acc[4] = {};
    int r = tid >> 2, p = tid & 3;

    int kv_end = q0 + QB;
    int cur = 0;
    for (int kv0 = 0; kv0 < kv_end; kv0 += KB) {
        // prefetch next KV tile into the alternate buffer (lands during compute)
        if (kv0 + KB < kv_end) stageKV(cur ^ 1, kv0 + KB);

        s16x8 kb[2];
        #pragma unroll
        for (int ks = 0; ks < 2; ++ks) {
            int row = wave * 16 + lr;
            int sl  = (lg + ks * 4) ^ (row & 7);
            kb[ks] = *(const s16x8*)&Ks[cur][row * 64 + sl * 8];
        }
        f32x4 sa[4] = {};
        __builtin_amdgcn_s_setprio(1);
        #pragma unroll
        for (int mf = 0; mf < 4; ++mf)
            #pragma unroll
            for (int ks = 0; ks < 2; ++ks)
                sa[mf] = __builtin_amdgcn_mfma_f32_16x16x32_bf16(
                    qa[mf][ks], kb[ks], sa[mf], 0, 0, 0);
        __builtin_amdgcn_s_setprio(0);

        int ki = kv0 + wave * 16 + lr;
        #pragma unroll
        for (int mf = 0; mf < 4; ++mf)
            #pragma unroll
            for (int j = 0; j < 4; ++j) {
                int qi = q0 + mf * 16 + lg * 4 + j;
                float s = (ki <= qi) ? sa[mf][j] * 0.125f : -1e30f;
                Ss[mf * 16 + lg * 4 + j][wave * 16 + lr] = s;
            }
        __syncthreads();

        float mo = mrow[r];
        float sv[16];
        float pm = -1e30f;
        #pragma unroll
        for (int i = 0; i < 16; ++i) {
            sv[i] = Ss[r][p * 16 + i];
            pm = fmaxf(pm, sv[i]);
        }
        pm = fmaxf(pm, __shfl_xor(pm, 1, 64));
        pm = fmaxf(pm, __shfl_xor(pm, 2, 64));
        float M = fmaxf(mo, pm);
        float sum = 0.f;
        s16x8 pk0, pk1;
        #pragma unroll
        for (int i = 0; i < 8; ++i) {
            float e0 = __expf(sv[i] - M);
            float e1 = __expf(sv[i + 8] - M);
            sum += e0 + e1;
            pk0[i] = (short)f2bf(e0);
            pk1[i] = (short)f2bf(e1);
        }
        *(s16x8*)&Ps[r][p * 16]     = pk0;
        *(s16x8*)&Ps[r][p * 16 + 8] = pk1;
        sum += __shfl_xor(sum, 1, 64);
        sum += __shfl_xor(sum, 2, 64);
        if (p == 0) {
            float al = __expf(mo - M);
            arow[r] = al;
            mrow[r] = M;
            lrow[r] = lrow[r] * al + sum;
        }
        __syncthreads();

        #pragma unroll
        for (int mf = 0; mf < 4; ++mf) {
            #pragma unroll
            for (int j = 0; j < 4; ++j)
                acc[mf][j] *= arow[mf * 16 + lg * 4 + j];
        }
        s16x8 vb[2];
        #pragma unroll
        for (int ks = 0; ks < 2; ++ks) {
            int row = wave * 16 + lr;
            int sl  = (lg + ks * 4) ^ (row & 7);
            vb[ks] = *(const s16x8*)&Vs[cur][row * 64 + sl * 8];
        }
        __builtin_amdgcn_s_setprio(1);
        #pragma unroll
        for (int mf = 0; mf < 4; ++mf)
            #pragma unroll
            for (int ks = 0; ks < 2; ++ks) {
                s16x8 pa = *(const s16x8*)((const char*)&Ps[0][0]
                            + (mf * 16 + lr) * 144 + lg * 16 + ks * 64);
                acc[mf] = __builtin_amdgcn_mfma_f32_16x16x32_bf16(
                    pa, vb[ks], acc[mf], 0, 0, 0);
            }
        __builtin_amdgcn_s_setprio(0);
        __syncthreads();       // drains prefetch (already landed) + protects Ss/Ps
        cur ^= 1;
    }

    #pragma unroll
    for (int mf = 0; mf < 4; ++mf)
        #pragma unroll
        for (int j = 0; j < 4; ++j) {
            int rr = mf * 16 + lg * 4 + j;
            float o = acc[mf][j] / lrow[rr];
            ctx[(size_t)(b * S_ + q0 + rr) * D_ + hh * HD_ + wave * 16 + lr] = f2bf(o);
        }
}

// =====================================================================
// prep_layer: all weight transposes+converts for one layer + qkv bias
// concat. 64x64 tiles: 256B-coalesced reads, 128B packed bf16x2 writes.
// 3075 blocks x 256 thr: [0,1024) Wq/Wk/Wv/Wo; [1024,2048) W1;
// [2048,3072) W2; [3072,3075) bias concat.
// =====================================================================
__global__ __launch_bounds__(256)
void prep_layer(const float* __restrict__ Wq, const float* __restrict__ Wk,
                const float* __restrict__ Wv, const float* __restrict__ Wo,
                const float* __restrict__ W1, const float* __restrict__ W2,
                const float* __restrict__ bq, const float* __restrict__ bk,
                const float* __restrict__ bv,
                ushort_t* __restrict__ wqkvT, ushort_t* __restrict__ woT,
                ushort_t* __restrict__ w1T, ushort_t* __restrict__ w2T,
                float* __restrict__ qkvb)
{
    int bid = blockIdx.x;
    if (bid >= 3072) {
        int j = bid - 3072;
        const float* bsrc = (j == 0) ? bq : (j == 1) ? bk : bv;
        int c = threadIdx.x * 4;
        *(f32x4*)&qkvb[j * 1024 + c] = *(const f32x4*)&bsrc[c];
        return;
    }
    __shared__ float t[64][65];
    int tid = threadIdx.x;
    int tx = tid & 63, ty = tid >> 6;
    const float* src; ushort_t* dst; int R, C, c0, r0;
    if (bid < 1024) {
        int mat = bid >> 8, tnum = bid & 255;
        src = (mat == 0) ? Wq : (mat == 1) ? Wk : (mat == 2) ? Wv : Wo;
        dst = (mat < 3) ? (wqkvT + (size_t)mat * D_ * D_) : woT;
        R = D_; C = D_;
        c0 = (tnum & 15) * 64; r0 = (tnum >> 4) * 64;
    } else if (bid < 2048) {
        int tnum = bid - 1024;
        src = W1; dst = w1T; R = D_; C = F_;
        c0 = (tnum & 63) * 64; r0 = (tnum >> 6) * 64;
    } else {
        int tnum = bid - 2048;
        src = W2; dst = w2T; R = F_; C = D_;
        c0 = (tnum & 15) * 64; r0 = (tnum >> 4) * 64;
    }
    #pragma unroll
    for (int i = 0; i < 16; ++i)
        t[ty + i * 4][tx] = src[(size_t)(r0 + ty + i * 4) * C + c0 + tx];
    __syncthreads();
    int u = tid & 31, v = tid >> 5;
    #pragma unroll
    for (int i = 0; i < 8; ++i) {
        int cc = v + i * 8;
        unsigned int val = (unsigned int)f2bf(t[u * 2][cc])
                         | ((unsigned int)f2bf(t[u * 2 + 1][cc]) << 16);
        *(unsigned int*)&dst[(size_t)(c0 + cc) * R + r0 + u * 2] = val;
    }
}

// ---- f32 [R,C] -> bf16 [C,R] transpose-convert, 64x64 tiles (Wout) ----
__global__ __launch_bounds__(256)
void tconv(const float* __restrict__ in, ushort_t* __restrict__ out, int R, int C)
{
    __shared__ float t[64][65];
    int c0 = blockIdx.x * 64, r0 = blockIdx.y * 64;
    int tid = threadIdx.x;
    int tx = tid & 63, ty = tid >> 6;
    #pragma unroll
    for (int i = 0; i < 16; ++i)
        t[ty + i * 4][tx] = in[(size_t)(r0 + ty + i * 4) * C + c0 + tx];
    __syncthreads();
    int u = tid & 31, v = tid >> 5;
    #pragma unroll
    for (int i = 0; i < 8; ++i) {
        int cc = v + i * 8;
        unsigned int val = (unsigned int)f2bf(t[u * 2][cc])
                         | ((unsigned int)f2bf(t[u * 2 + 1][cc]) << 16);
        *(unsigned int*)&out[(size_t)(c0 + cc) * R + r0 + u * 2] = val;
    }
}

// ---- embedding * sqrt(D) + sinusoidal PE -> x (f32) ----
__global__ __launch_bounds__(256)
void embed_pe(const int* __restrict__ ids, const float* __restrict__ emb,
              float* __restrict__ x)
{
    int row = blockIdx.x;
    int s   = row & (S_ - 1);
    int id  = ids[row];
    int d   = threadIdx.x * 4;
    f32x4 ev = *(const f32x4*)&emb[(size_t)id * D_ + d];
    f32x4 o;
    #pragma unroll
    for (int j = 0; j < 4; ++j) {
        int dd = d + j;
        int i  = dd >> 1;
        float div = expf(-(float)(2 * i) * (9.210340371976184f / 1024.0f));
        float arg = (float)s * div;
        float pe  = (dd & 1) ? cosf(arg) : sinf(arg);
        o[j] = ev[j] * 32.0f + pe;
    }
    *(f32x4*)&x[(size_t)row * D_ + d] = o;
}

// ---- LayerNorm row kernel: f32 in -> bf16 out ----
__global__ __launch_bounds__(256)
void ln_kernel(const float* __restrict__ x, const float* __restrict__ g,
               const float* __restrict__ b, ushort_t* __restrict__ out)
{
    __shared__ float sb[4];
    int row = blockIdx.x;
    const float* xr = x + (size_t)row * D_;
    int c = threadIdx.x * 4;
    f32x4 v = *(const f32x4*)&xr[c];
    float s = v[0] + v[1] + v[2] + v[3];
    s = blk_sum(s, sb);
    float mean = s * (1.0f / D_);
    f32x4 dv = v - mean;
    float sq = dv[0]*dv[0] + dv[1]*dv[1] + dv[2]*dv[2] + dv[3]*dv[3];
    sq = blk_sum(sq, sb);
    float rstd = rsqrtf(sq * (1.0f / D_) + EPSLN);
    u16x4 o;
    #pragma unroll
    for (int j = 0; j < 4; ++j)
        o[j] = f2bf(dv[j] * rstd * g[c + j] + b[c + j]);
    *(u16x4*)&out[(size_t)row * D_ + c] = o;
}

__global__ void ws_marker(float* o) { o[threadIdx.x] = -777777.0f; }

// =====================================================================
extern "C" void kernel_launch(void* const* d_in, const int* in_sizes, int n_in,
                              void* d_out, int out_size, void* d_ws, size_t ws_size,
                              hipStream_t stream)
{
    (void)in_sizes; (void)n_in; (void)out_size;
    const int*   ids  = (const int*)d_in[0];
    const float* emb  = (const float*)d_in[1];
    const float* Wq   = (const float*)d_in[2];
    const float* bq   = (const float*)d_in[3];
    const float* Wk   = (const float*)d_in[4];
    const float* bk   = (const float*)d_in[5];
    const float* Wv   = (const float*)d_in[6];
    const float* bv   = (const float*)d_in[7];
    const float* Wo   = (const float*)d_in[8];
    const float* bo   = (const float*)d_in[9];
    const float* ln1g = (const float*)d_in[10];
    const float* ln1b = (const float*)d_in[11];
    const float* ln2g = (const float*)d_in[12];
    const float* ln2b = (const float*)d_in[13];
    const float* W1   = (const float*)d_in[14];
    const float* b1   = (const float*)d_in[15];
    const float* W2   = (const float*)d_in[16];
    const float* b2   = (const float*)d_in[17];
    const float* fng  = (const float*)d_in[18];
    const float* fnb  = (const float*)d_in[19];
    const float* Wout = (const float*)d_in[20];
    const float* bout = (const float*)d_in[21];
    float* out = (float*)d_out;

    // ---- workspace layout ----
    char* base = (char*)d_ws;
    size_t off = 0;
    float*    x    = (float*)(base + off);    off += (size_t)MTOK * D_ * 4;
    ushort_t* h    = (ushort_t*)(base + off); off += (size_t)MTOK * D_ * 2;
    ushort_t* qkv  = (ushort_t*)(base + off); off += (size_t)MTOK * 3 * D_ * 2;
    ushort_t* vt   = (ushort_t*)(base + off); off += (size_t)B_ * H_ * HD_ * S_ * 2;
    ushort_t* ctx  = (ushort_t*)(base + off); off += (size_t)MTOK * D_ * 2;
    ushort_t* ff   = (ushort_t*)(base + off); off += (size_t)MTOK * F_ * 2;
    float*    qkvb = (float*)(base + off);    off += 3072 * 4;
    ushort_t* wqkvT= (ushort_t*)(base + off); off += (size_t)3 * D_ * D_ * 2;
    ushort_t* woT  = (ushort_t*)(base + off); off += (size_t)D_ * D_ * 2;
    ushort_t* w1T  = (ushort_t*)(base + off); off += (size_t)D_ * F_ * 2;
    ushort_t* w2T  = (ushort_t*)(base + off); off += (size_t)F_ * D_ * 2;
    ushort_t* wouT = (ushort_t*)(base + off); off += (size_t)V_ * D_ * 2;
    if (ws_size < off) { ws_marker<<<1, 64, 0, stream>>>(out); return; }

    embed_pe<<<MTOK, 256, 0, stream>>>(ids, emb, x);

    for (int i = 0; i < L_; ++i) {
        prep_layer<<<3075, 256, 0, stream>>>(
            Wq + (size_t)i * D_ * D_, Wk + (size_t)i * D_ * D_,
            Wv + (size_t)i * D_ * D_, Wo + (size_t)i * D_ * D_,
            W1 + (size_t)i * D_ * F_, W2 + (size_t)i * F_ * D_,
            bq + i * D_, bk + i * D_, bv + i * D_,
            wqkvT, woT, w1T, w2T, qkvb);

        ln_kernel<<<MTOK, 256, 0, stream>>>(x, ln1g + i * D_, ln1b + i * D_, h);

        // qkv = h @ [Wq|Wk|Wv] + bias; V cols also scattered into vt
        gemm_bt<128,false,false,true,true><<<dim3(16, 24), 256, 0, stream>>>(
            h, D_, wqkvT, D_, qkv, 3 * D_, qkvb, nullptr, MTOK, 3 * D_, D_, vt);

        flash_attn<<<dim3(S_ / 64, B_ * H_), 256, 0, stream>>>(qkv, vt, ctx);

        // x = x + ctx @ Wo + bo   (BN=64 -> 256 blocks, full fill)
        gemm_bt<64,false,true,false,false><<<dim3(16, 16), 256, 0, stream>>>(
            ctx, D_, woT, D_, x, D_, bo + i * D_, x, MTOK, D_, D_, nullptr);

        ln_kernel<<<MTOK, 256, 0, stream>>>(x, ln2g + i * D_, ln2b + i * D_, h);

        // ff = gelu(h @ W1 + b1)
        gemm_bt<128,true,false,true,false><<<dim3(16, 32), 256, 0, stream>>>(
            h, D_, w1T, D_, ff, F_, b1 + i * F_, nullptr, MTOK, F_, D_, nullptr);

        // x = x + ff @ W2 + b2   (BN=64 -> 256 blocks, full fill)
        gemm_bt<64,false,true,false,false><<<dim3(16, 16), 256, 0, stream>>>(
            ff, F_, w2T, F_, x, D_, b2 + i * D_, x, MTOK, D_, F_, nullptr);
    }

    ln_kernel<<<MTOK, 256, 0, stream>>>(x, fng, fnb, h);
    tconv<<<dim3(500, 16), 256, 0, stream>>>(Wout, wouT, D_, V_);
    gemm256<false,false><<<dim3(8, 125), 512, 0, stream>>>(
        h, D_, wouT, D_, out, V_, bout, MTOK, V_, D_);
}

// Round 8
// 1582.139 us; speedup vs baseline: 1.7649x; 1.0138x over previous
//
#include <hip/hip_runtime.h>
#include <math.h>

// ---- problem constants ----
#define V_   32000
#define D_   1024
#define H_   16
#define HD_  64
#define L_   6
#define F_   4096
#define S_   1024
#define B_   2
#define MTOK (B_*S_)      // 2048
#define EPSLN 1e-5f

typedef unsigned short ushort_t;
typedef __attribute__((ext_vector_type(8))) short  s16x8;
typedef __attribute__((ext_vector_type(4))) float  f32x4;
typedef __attribute__((ext_vector_type(4))) unsigned short u16x4;

__device__ __forceinline__ float bf2f(unsigned short u) {
    unsigned int x = ((unsigned int)u) << 16;
    return __builtin_bit_cast(float, x);
}
__device__ __forceinline__ unsigned short f2bf(float f) {
    unsigned int x = __builtin_bit_cast(unsigned int, f);
    unsigned int r = (x + 0x7FFFu + ((x >> 16) & 1u)) >> 16;   // RNE
    return (unsigned short)r;
}
__device__ __forceinline__ float gelu_f(float x) {
    float y = 0.7978845608f * (x + 0.044715f * x * x * x);
    float t = 1.0f - 2.0f / (__expf(2.0f * y) + 1.0f);
    return 0.5f * x * (1.0f + t);
}

__device__ __forceinline__ float blk_sum(float v, float* sb) {
    #pragma unroll
    for (int o = 32; o; o >>= 1) v += __shfl_xor(v, o, 64);
    int w = threadIdx.x >> 6;
    __syncthreads();
    if ((threadIdx.x & 63) == 0) sb[w] = v;
    __syncthreads();
    return sb[0] + sb[1] + sb[2] + sb[3];
}

// =====================================================================
// gemm256: 2-phase-per-K-tile pipelined 256x256xBK64 bf16 MFMA GEMM.
// (round-5 measured-best structure: 177us on logits)
// =====================================================================
template<bool GELU, bool OUTBF>
__global__ __launch_bounds__(512, 2)
void gemm256(const ushort_t* __restrict__ A, int lda,
             const ushort_t* __restrict__ BT, int ldb,
             void* __restrict__ Cv, int ldc,
             const float* __restrict__ bias,
             int M, int N, int K)
{
    int nmt = M >> 8;
    int nwg = gridDim.x * gridDim.y;
    int id  = blockIdx.x + gridDim.x * blockIdx.y;
    int swz = ((nwg & 7) == 0) ? ((id & 7) * (nwg >> 3) + (id >> 3)) : id;
    int m0 = (swz % nmt) << 8;
    int n0 = (swz / nmt) << 8;

    __shared__ __align__(16) ushort_t lA[2][256 * 64];
    __shared__ __align__(16) ushort_t lB[2][256 * 64];

    int tid  = threadIdx.x;
    int lane = tid & 63, wave = tid >> 6;
    int lr = lane & 15, lg = lane >> 4;
    int wm = wave >> 2, wn = wave & 3;

    f32x4 acc[8][4] = {};
    int nkt = K >> 6;

    auto stageu = [&](int buf, int kt, int sel) {
        int k0 = kt << 6;
        const ushort_t* src = (sel < 2) ? A : BT;
        int ld    = (sel < 2) ? lda : ldb;
        int rbase = ((sel < 2) ? m0 : n0) + ((sel & 1) << 7);
        ushort_t* dst = ((sel < 2) ? &lA[buf][0] : &lB[buf][0]) + ((sel & 1) << 13);
        #pragma unroll
        for (int r = 0; r < 2; ++r) {
            int e8  = r * 512 + tid;
            int row = e8 >> 3, slot = e8 & 7;
            int ls  = slot ^ (row & 7);
            const ushort_t* g = src + (size_t)(rbase + row) * ld + k0 + ls * 8;
            __builtin_amdgcn_global_load_lds(
                (const __attribute__((address_space(1))) void*)g,
                (__attribute__((address_space(3))) void*)(dst + e8 * 8), 16, 0, 0);
        }
    };
    auto rdA = [&](int buf, int row, int ks) -> s16x8 {
        int sl = (lg + ks * 4) ^ (row & 7);
        return *(const s16x8*)&lA[buf][row * 64 + sl * 8];
    };
    auto rdB = [&](int buf, int row, int ks) -> s16x8 {
        int sl = (lg + ks * 4) ^ (row & 7);
        return *(const s16x8*)&lB[buf][row * 64 + sl * 8];
    };

    stageu(0, 0, 0); stageu(0, 0, 1); stageu(0, 0, 2); stageu(0, 0, 3);
    if (nkt > 1) {
        stageu(1, 1, 2); stageu(1, 1, 3);
        asm volatile("s_waitcnt vmcnt(4)" ::: "memory");
    } else {
        asm volatile("s_waitcnt vmcnt(0)" ::: "memory");
    }
    __builtin_amdgcn_sched_barrier(0);
    __builtin_amdgcn_s_barrier();

    for (int u = 0; u < nkt; ++u) {
        int cur = u & 1, nxt = cur ^ 1;
        s16x8 af0[4][2], af1[4][2], bf0[2][2], bf1[2][2];

        // ======== Phase A: af0 + bf0 + bf1 reads; stage A(u+1) ========
        #pragma unroll
        for (int mf = 0; mf < 4; ++mf)
            #pragma unroll
            for (int ks = 0; ks < 2; ++ks)
                af0[mf][ks] = rdA(cur, wm * 128 + mf * 16 + lr, ks);
        #pragma unroll
        for (int nf = 0; nf < 2; ++nf)
            #pragma unroll
            for (int ks = 0; ks < 2; ++ks) {
                bf0[nf][ks] = rdB(cur, wn * 64 + nf * 16 + lr, ks);
                bf1[nf][ks] = rdB(cur, wn * 64 + 32 + nf * 16 + lr, ks);
            }
        if (u + 1 < nkt) { stageu(nxt, u + 1, 0); stageu(nxt, u + 1, 1); }
        __builtin_amdgcn_s_barrier();
        asm volatile("s_waitcnt lgkmcnt(0)" ::: "memory");
        __builtin_amdgcn_sched_barrier(0);
        __builtin_amdgcn_s_setprio(1);
        #pragma unroll
        for (int mf = 0; mf < 4; ++mf)
            #pragma unroll
            for (int ks = 0; ks < 2; ++ks) {
                #pragma unroll
                for (int nf = 0; nf < 2; ++nf) {
                    acc[mf][nf]     = __builtin_amdgcn_mfma_f32_16x16x32_bf16(
                        af0[mf][ks], bf0[nf][ks], acc[mf][nf], 0, 0, 0);
                    acc[mf][2 + nf] = __builtin_amdgcn_mfma_f32_16x16x32_bf16(
                        af0[mf][ks], bf1[nf][ks], acc[mf][2 + nf], 0, 0, 0);
                }
            }
        __builtin_amdgcn_s_setprio(0);
        __builtin_amdgcn_s_barrier();

        // ======== Phase B: af1 reads; stage B(u+2) into cur ========
        #pragma unroll
        for (int mf = 0; mf < 4; ++mf)
            #pragma unroll
            for (int ks = 0; ks < 2; ++ks)
                af1[mf][ks] = rdA(cur, wm * 128 + 64 + mf * 16 + lr, ks);
        if (u + 2 < nkt) { stageu(cur, u + 2, 2); stageu(cur, u + 2, 3); }
        __builtin_amdgcn_s_barrier();
        asm volatile("s_waitcnt lgkmcnt(0)" ::: "memory");
        __builtin_amdgcn_sched_barrier(0);
        __builtin_amdgcn_s_setprio(1);
        #pragma unroll
        for (int mf = 0; mf < 4; ++mf)
            #pragma unroll
            for (int ks = 0; ks < 2; ++ks) {
                #pragma unroll
                for (int nf = 0; nf < 2; ++nf) {
                    acc[4 + mf][nf]     = __builtin_amdgcn_mfma_f32_16x16x32_bf16(
                        af1[mf][ks], bf0[nf][ks], acc[4 + mf][nf], 0, 0, 0);
                    acc[4 + mf][2 + nf] = __builtin_amdgcn_mfma_f32_16x16x32_bf16(
                        af1[mf][ks], bf1[nf][ks], acc[4 + mf][2 + nf], 0, 0, 0);
                }
            }
        __builtin_amdgcn_s_setprio(0);
        if (u + 2 < nkt) asm volatile("s_waitcnt vmcnt(4)" ::: "memory");
        else             asm volatile("s_waitcnt vmcnt(0)" ::: "memory");
        __builtin_amdgcn_sched_barrier(0);
        __builtin_amdgcn_s_barrier();
    }

    float*    Cf = (float*)Cv;
    ushort_t* Cb = (ushort_t*)Cv;
    #pragma unroll
    for (int mf = 0; mf < 8; ++mf) {
        int gm0 = m0 + wm * 128 + mf * 16 + lg * 4;
        #pragma unroll
        for (int nf = 0; nf < 4; ++nf) {
            int gn = n0 + wn * 64 + nf * 16 + lr;
            float bv = bias ? bias[gn] : 0.f;
            #pragma unroll
            for (int j = 0; j < 4; ++j) {
                float v = acc[mf][nf][j] + bv;
                if (GELU) v = gelu_f(v);
                size_t ci = (size_t)(gm0 + j) * ldc + gn;
                if (OUTBF) Cb[ci] = f2bf(v);
                else       Cf[ci] = v;
            }
        }
    }
}

// =====================================================================
// gemm_bt: 128xBNxBK32, 2-phase dbuf + 4-slot XOR swizzle. BN in {64,128}.
// VOUT: for QKV, also scatter V columns (gn>=2048) into vt[BH][HD][S].
// =====================================================================
template<int BN, bool GELU, bool RES, bool OUTBF, bool VOUT>
__global__ __launch_bounds__(256)
void gemm_bt(const ushort_t* __restrict__ A, int lda,
             const ushort_t* __restrict__ BT, int ldb,
             void* __restrict__ Cv, int ldc,
             const float* __restrict__ bias,
             const float* __restrict__ res,
             int M, int N, int K, ushort_t* __restrict__ vtp)
{
    const int BK = 32;
    const int NF = BN / 32;
    int m0 = blockIdx.x * 128;
    int n0 = blockIdx.y * BN;

    __shared__ __align__(16) ushort_t lA[2][128 * BK];
    __shared__ __align__(16) ushort_t lB[2][BN * BK];

    int tid  = threadIdx.x;
    int lane = tid & 63;
    int wave = tid >> 6;
    int lr = lane & 15, lg = lane >> 4;
    int wr = wave >> 1, wc = wave & 1;

    f32x4 acc[4][NF] = {};
    int nkt = K / BK;

    auto stage = [&](int buf, int kt) {
        int k0 = kt * BK;
        #pragma unroll
        for (int i = 0; i < 2; ++i) {
            int e8  = i * 256 + tid;
            int row = e8 >> 2, slot = e8 & 3;
            int ls  = slot ^ (row & 3);
            const ushort_t* g = A + (size_t)(m0 + row) * lda + k0 + ls * 8;
            __builtin_amdgcn_global_load_lds(
                (const __attribute__((address_space(1))) void*)g,
                (__attribute__((address_space(3))) void*)&lA[buf][e8 * 8], 16, 0, 0);
        }
        #pragma unroll
        for (int i = 0; i < BN / 64; ++i) {
            int e8  = i * 256 + tid;
            int row = e8 >> 2, slot = e8 & 3;
            int ls  = slot ^ (row & 3);
            const ushort_t* g = BT + (size_t)(n0 + row) * ldb + k0 + ls * 8;
            __builtin_amdgcn_global_load_lds(
                (const __attribute__((address_space(1))) void*)g,
                (__attribute__((address_space(3))) void*)&lB[buf][e8 * 8], 16, 0, 0);
        }
    };

    stage(0, 0);
    __syncthreads();

    int cur = 0;
    for (int kt = 0; kt < nkt; ++kt) {
        if (kt + 1 < nkt) stage(cur ^ 1, kt + 1);
        __builtin_amdgcn_sched_barrier(0);
        s16x8 af[4], bfr[NF];
        #pragma unroll
        for (int m = 0; m < 4; ++m) {
            int row = wr * 64 + m * 16 + lr;
            int sl  = lg ^ (row & 3);
            af[m] = *(const s16x8*)&lA[cur][row * BK + sl * 8];
        }
        #pragma unroll
        for (int n = 0; n < NF; ++n) {
            int row = wc * (BN / 2) + n * 16 + lr;
            int sl  = lg ^ (row & 3);
            bfr[n] = *(const s16x8*)&lB[cur][row * BK + sl * 8];
        }
        #pragma unroll
        for (int m = 0; m < 4; ++m)
            #pragma unroll
            for (int n = 0; n < NF; ++n)
                acc[m][n] = __builtin_amdgcn_mfma_f32_16x16x32_bf16(
                    af[m], bfr[n], acc[m][n], 0, 0, 0);
        __syncthreads();
        cur ^= 1;
    }

    float*    Cf = (float*)Cv;
    ushort_t* Cb = (ushort_t*)Cv;
    #pragma unroll
    for (int m = 0; m < 4; ++m) {
        int gm0 = m0 + wr * 64 + m * 16 + lg * 4;
        #pragma unroll
        for (int n = 0; n < NF; ++n) {
            int gn = n0 + wc * (BN / 2) + n * 16 + lr;
            #pragma unroll
            for (int j = 0; j < 4; ++j) {
                float v = acc[m][n][j];
                if (bias) v += bias[gn];
                size_t ci = (size_t)(gm0 + j) * ldc + gn;
                if (RES)  v += res[ci];
                if (GELU) v = gelu_f(v);
                if (OUTBF) Cb[ci] = f2bf(v);
                else       Cf[ci] = v;
                if (VOUT && gn >= 2048) {
                    int hv = gn - 2048;
                    int mm = gm0 + j;
                    vtp[((size_t)(((mm >> 10) << 4) + (hv >> 6)) * 64
                         + (hv & 63)) * 1024 + (mm & 1023)] = f2bf(v);
                }
            }
        }
    }
}

// =====================================================================
// Flash attention, LOAD-BALANCED: grid (8, BH). Block x processes
// q-tiles {x, 15-x}: (x+1)+(16-x) = 17 KV-iters for EVERY block,
// uniform regardless of dispatch->CU mapping. K/V double-buffered with
// top-of-iter prefetch; setprio around MFMA clusters.
// =====================================================================
__global__ __launch_bounds__(256)
void flash_attn(const ushort_t* __restrict__ qkv,
                const ushort_t* __restrict__ vt,
                ushort_t* __restrict__ ctx)
{
    const int QB = 64, KB = 64;
    int z  = blockIdx.y;            // b*H + h
    int b  = z >> 4, hh = z & 15;

    __shared__ __align__(16) ushort_t Qs[QB * 64];
    __shared__ __align__(16) ushort_t Ks[2][KB * 64];
    __shared__ __align__(16) ushort_t Vs[2][64 * KB];
    __shared__ float    Ss[QB][68];
    __shared__ __align__(16) ushort_t Ps[QB][72];
    __shared__ float mrow[QB], lrow[QB], arow[QB];

    int tid  = threadIdx.x;
    int lane = tid & 63, wave = tid >> 6;
    int lr = lane & 15, lg = lane >> 4;
    int r = tid >> 2, p = tid & 3;

    auto stageKV = [&](int buf, int kv0) {
        const ushort_t* kbase = qkv + (size_t)(b * S_ + kv0) * 3072 + 1024 + hh * HD_;
        const ushort_t* vbase = vt + (size_t)z * HD_ * S_ + kv0;
        #pragma unroll
        for (int rnd = 0; rnd < 2; ++rnd) {
            int e8 = rnd * 256 + tid;
            int row = e8 >> 3, slot = e8 & 7;
            int ls = slot ^ (row & 7);
            const ushort_t* gk = kbase + (size_t)row * 3072 + ls * 8;
            __builtin_amdgcn_global_load_lds(
                (const __attribute__((address_space(1))) void*)gk,
                (__attribute__((address_space(3))) void*)&Ks[buf][e8 * 8], 16, 0, 0);
            const ushort_t* gv = vbase + (size_t)row * S_ + ls * 8;
            __builtin_amdgcn_global_load_lds(
                (const __attribute__((address_space(1))) void*)gv,
                (__attribute__((address_space(3))) void*)&Vs[buf][e8 * 8], 16, 0, 0);
        }
    };

    #pragma unroll
    for (int half = 0; half < 2; ++half) {
        int qt = half ? (15 - (int)blockIdx.x) : (int)blockIdx.x;
        int q0 = qt * QB;

        // ---- per-half init + Q tile + KV tile 0 ----
        if (tid < QB) { mrow[tid] = -1e30f; lrow[tid] = 0.f; }
        const ushort_t* qbase = qkv + (size_t)(b * S_ + q0) * 3072 + hh * HD_;
        #pragma unroll
        for (int rnd = 0; rnd < 2; ++rnd) {
            int e8   = rnd * 256 + tid;
            int row  = e8 >> 3;
            int slot = e8 & 7;
            int ls   = slot ^ (row & 7);
            const ushort_t* g = qbase + (size_t)row * 3072 + ls * 8;
            __builtin_amdgcn_global_load_lds(
                (const __attribute__((address_space(1))) void*)g,
                (__attribute__((address_space(3))) void*)&Qs[e8 * 8], 16, 0, 0);
        }
        stageKV(0, 0);
        __syncthreads();

        s16x8 qa[4][2];
        #pragma unroll
        for (int mf = 0; mf < 4; ++mf)
            #pragma unroll
            for (int ks = 0; ks < 2; ++ks) {
                int row = mf * 16 + lr;
                int sl  = (lg + ks * 4) ^ (row & 7);
                qa[mf][ks] = *(const s16x8*)&Qs[row * 64 + sl * 8];
            }

        f32x4 acc[4] = {};
        int kv_end = q0 + QB;
        int cur = 0;
        for (int kv0 = 0; kv0 < kv_end; kv0 += KB) {
            if (kv0 + KB < kv_end) stageKV(cur ^ 1, kv0 + KB);

            s16x8 kb[2];
            #pragma unroll
            for (int ks = 0; ks < 2; ++ks) {
                int row = wave * 16 + lr;
                int sl  = (lg + ks * 4) ^ (row & 7);
                kb[ks] = *(const s16x8*)&Ks[cur][row * 64 + sl * 8];
            }
            f32x4 sa[4] = {};
            __builtin_amdgcn_s_setprio(1);
            #pragma unroll
            for (int mf = 0; mf < 4; ++mf)
                #pragma unroll
                for (int ks = 0; ks < 2; ++ks)
                    sa[mf] = __builtin_amdgcn_mfma_f32_16x16x32_bf16(
                        qa[mf][ks], kb[ks], sa[mf], 0, 0, 0);
            __builtin_amdgcn_s_setprio(0);

            int ki = kv0 + wave * 16 + lr;
            #pragma unroll
            for (int mf = 0; mf < 4; ++mf)
                #pragma unroll
                for (int j = 0; j < 4; ++j) {
                    int qi = q0 + mf * 16 + lg * 4 + j;
                    float s = (ki <= qi) ? sa[mf][j] * 0.125f : -1e30f;
                    Ss[mf * 16 + lg * 4 + j][wave * 16 + lr] = s;
                }
            __syncthreads();

            float mo = mrow[r];
            float sv[16];
            float pm = -1e30f;
            #pragma unroll
            for (int i = 0; i < 16; ++i) {
                sv[i] = Ss[r][p * 16 + i];
                pm = fmaxf(pm, sv[i]);
            }
            pm = fmaxf(pm, __shfl_xor(pm, 1, 64));
            pm = fmaxf(pm, __shfl_xor(pm, 2, 64));
            float M = fmaxf(mo, pm);
            float sum = 0.f;
            s16x8 pk0, pk1;
            #pragma unroll
            for (int i = 0; i < 8; ++i) {
                float e0 = __expf(sv[i] - M);
                float e1 = __expf(sv[i + 8] - M);
                sum += e0 + e1;
                pk0[i] = (short)f2bf(e0);
                pk1[i] = (short)f2bf(e1);
            }
            *(s16x8*)&Ps[r][p * 16]     = pk0;
            *(s16x8*)&Ps[r][p * 16 + 8] = pk1;
            sum += __shfl_xor(sum, 1, 64);
            sum += __shfl_xor(sum, 2, 64);
            if (p == 0) {
                float al = __expf(mo - M);
                arow[r] = al;
                mrow[r] = M;
                lrow[r] = lrow[r] * al + sum;
            }
            __syncthreads();

            #pragma unroll
            for (int mf = 0; mf < 4; ++mf) {
                #pragma unroll
                for (int j = 0; j < 4; ++j)
                    acc[mf][j] *= arow[mf * 16 + lg * 4 + j];
            }
            s16x8 vb[2];
            #pragma unroll
            for (int ks = 0; ks < 2; ++ks) {
                int row = wave * 16 + lr;
                int sl  = (lg + ks * 4) ^ (row & 7);
                vb[ks] = *(const s16x8*)&Vs[cur][row * 64 + sl * 8];
            }
            __builtin_amdgcn_s_setprio(1);
            #pragma unroll
            for (int mf = 0; mf < 4; ++mf)
                #pragma unroll
                for (int ks = 0; ks < 2; ++ks) {
                    s16x8 pa = *(const s16x8*)((const char*)&Ps[0][0]
                                + (mf * 16 + lr) * 144 + lg * 16 + ks * 64);
                    acc[mf] = __builtin_amdgcn_mfma_f32_16x16x32_bf16(
                        pa, vb[ks], acc[mf], 0, 0, 0);
                }
            __builtin_amdgcn_s_setprio(0);
            __syncthreads();
            cur ^= 1;
        }

        #pragma unroll
        for (int mf = 0; mf < 4; ++mf)
            #pragma unroll
            for (int j = 0; j < 4; ++j) {
                int rr = mf * 16 + lg * 4 + j;
                float o = acc[mf][j] / lrow[rr];
                ctx[(size_t)(b * S_ + q0 + rr) * D_ + hh * HD_ + wave * 16 + lr] = f2bf(o);
            }
        __syncthreads();   // protect Qs/Ks/Vs/state before next half
    }
}

// =====================================================================
// prep_layer: weight transposes+converts for one layer + qkv bias concat.
// 64x64 tiles: 256B-coalesced reads, 128B packed bf16x2 writes.
// =====================================================================
__global__ __launch_bounds__(256)
void prep_layer(const float* __restrict__ Wq, const float* __restrict__ Wk,
                const float* __restrict__ Wv, const float* __restrict__ Wo,
                const float* __restrict__ W1, const float* __restrict__ W2,
                const float* __restrict__ bq, const float* __restrict__ bk,
                const float* __restrict__ bv,
                ushort_t* __restrict__ wqkvT, ushort_t* __restrict__ woT,
                ushort_t* __restrict__ w1T, ushort_t* __restrict__ w2T,
                float* __restrict__ qkvb)
{
    int bid = blockIdx.x;
    if (bid >= 3072) {
        int j = bid - 3072;
        const float* bsrc = (j == 0) ? bq : (j == 1) ? bk : bv;
        int c = threadIdx.x * 4;
        *(f32x4*)&qkvb[j * 1024 + c] = *(const f32x4*)&bsrc[c];
        return;
    }
    __shared__ float t[64][65];
    int tid = threadIdx.x;
    int tx = tid & 63, ty = tid >> 6;
    const float* src; ushort_t* dst; int R, C, c0, r0;
    if (bid < 1024) {
        int mat = bid >> 8, tnum = bid & 255;
        src = (mat == 0) ? Wq : (mat == 1) ? Wk : (mat == 2) ? Wv : Wo;
        dst = (mat < 3) ? (wqkvT + (size_t)mat * D_ * D_) : woT;
        R = D_; C = D_;
        c0 = (tnum & 15) * 64; r0 = (tnum >> 4) * 64;
    } else if (bid < 2048) {
        int tnum = bid - 1024;
        src = W1; dst = w1T; R = D_; C = F_;
        c0 = (tnum & 63) * 64; r0 = (tnum >> 6) * 64;
    } else {
        int tnum = bid - 2048;
        src = W2; dst = w2T; R = F_; C = D_;
        c0 = (tnum & 15) * 64; r0 = (tnum >> 4) * 64;
    }
    #pragma unroll
    for (int i = 0; i < 16; ++i)
        t[ty + i * 4][tx] = src[(size_t)(r0 + ty + i * 4) * C + c0 + tx];
    __syncthreads();
    int u = tid & 31, v = tid >> 5;
    #pragma unroll
    for (int i = 0; i < 8; ++i) {
        int cc = v + i * 8;
        unsigned int val = (unsigned int)f2bf(t[u * 2][cc])
                         | ((unsigned int)f2bf(t[u * 2 + 1][cc]) << 16);
        *(unsigned int*)&dst[(size_t)(c0 + cc) * R + r0 + u * 2] = val;
    }
}

// ---- f32 [R,C] -> bf16 [C,R] transpose-convert, 64x64 tiles (Wout) ----
__global__ __launch_bounds__(256)
void tconv(const float* __restrict__ in, ushort_t* __restrict__ out, int R, int C)
{
    __shared__ float t[64][65];
    int c0 = blockIdx.x * 64, r0 = blockIdx.y * 64;
    int tid = threadIdx.x;
    int tx = tid & 63, ty = tid >> 6;
    #pragma unroll
    for (int i = 0; i < 16; ++i)
        t[ty + i * 4][tx] = in[(size_t)(r0 + ty + i * 4) * C + c0 + tx];
    __syncthreads();
    int u = tid & 31, v = tid >> 5;
    #pragma unroll
    for (int i = 0; i < 8; ++i) {
        int cc = v + i * 8;
        unsigned int val = (unsigned int)f2bf(t[u * 2][cc])
                         | ((unsigned int)f2bf(t[u * 2 + 1][cc]) << 16);
        *(unsigned int*)&out[(size_t)(c0 + cc) * R + r0 + u * 2] = val;
    }
}

// ---- embedding * sqrt(D) + sinusoidal PE -> x (f32) ----
__global__ __launch_bounds__(256)
void embed_pe(const int* __restrict__ ids, const float* __restrict__ emb,
              float* __restrict__ x)
{
    int row = blockIdx.x;
    int s   = row & (S_ - 1);
    int id  = ids[row];
    int d   = threadIdx.x * 4;
    f32x4 ev = *(const f32x4*)&emb[(size_t)id * D_ + d];
    f32x4 o;
    #pragma unroll
    for (int j = 0; j < 4; ++j) {
        int dd = d + j;
        int i  = dd >> 1;
        float div = expf(-(float)(2 * i) * (9.210340371976184f / 1024.0f));
        float arg = (float)s * div;
        float pe  = (dd & 1) ? cosf(arg) : sinf(arg);
        o[j] = ev[j] * 32.0f + pe;
    }
    *(f32x4*)&x[(size_t)row * D_ + d] = o;
}

// ---- LayerNorm row kernel: f32 in -> bf16 out ----
__global__ __launch_bounds__(256)
void ln_kernel(const float* __restrict__ x, const float* __restrict__ g,
               const float* __restrict__ b, ushort_t* __restrict__ out)
{
    __shared__ float sb[4];
    int row = blockIdx.x;
    const float* xr = x + (size_t)row * D_;
    int c = threadIdx.x * 4;
    f32x4 v = *(const f32x4*)&xr[c];
    float s = v[0] + v[1] + v[2] + v[3];
    s = blk_sum(s, sb);
    float mean = s * (1.0f / D_);
    f32x4 dv = v - mean;
    float sq = dv[0]*dv[0] + dv[1]*dv[1] + dv[2]*dv[2] + dv[3]*dv[3];
    sq = blk_sum(sq, sb);
    float rstd = rsqrtf(sq * (1.0f / D_) + EPSLN);
    u16x4 o;
    #pragma unroll
    for (int j = 0; j < 4; ++j)
        o[j] = f2bf(dv[j] * rstd * g[c + j] + b[c + j]);
    *(u16x4*)&out[(size_t)row * D_ + c] = o;
}

__global__ void ws_marker(float* o) { o[threadIdx.x] = -777777.0f; }

// =====================================================================
extern "C" void kernel_launch(void* const* d_in, const int* in_sizes, int n_in,
                              void* d_out, int out_size, void* d_ws, size_t ws_size,
                              hipStream_t stream)
{
    (void)in_sizes; (void)n_in; (void)out_size;
    const int*   ids  = (const int*)d_in[0];
    const float* emb  = (const float*)d_in[1];
    const float* Wq   = (const float*)d_in[2];
    const float* bq   = (const float*)d_in[3];
    const float* Wk   = (const float*)d_in[4];
    const float* bk   = (const float*)d_in[5];
    const float* Wv   = (const float*)d_in[6];
    const float* bv   = (const float*)d_in[7];
    const float* Wo   = (const float*)d_in[8];
    const float* bo   = (const float*)d_in[9];
    const float* ln1g = (const float*)d_in[10];
    const float* ln1b = (const float*)d_in[11];
    const float* ln2g = (const float*)d_in[12];
    const float* ln2b = (const float*)d_in[13];
    const float* W1   = (const float*)d_in[14];
    const float* b1   = (const float*)d_in[15];
    const float* W2   = (const float*)d_in[16];
    const float* b2   = (const float*)d_in[17];
    const float* fng  = (const float*)d_in[18];
    const float* fnb  = (const float*)d_in[19];
    const float* Wout = (const float*)d_in[20];
    const float* bout = (const float*)d_in[21];
    float* out = (float*)d_out;

    // ---- workspace layout ----
    char* base = (char*)d_ws;
    size_t off = 0;
    float*    x    = (float*)(base + off);    off += (size_t)MTOK * D_ * 4;
    ushort_t* h    = (ushort_t*)(base + off); off += (size_t)MTOK * D_ * 2;
    ushort_t* qkv  = (ushort_t*)(base + off); off += (size_t)MTOK * 3 * D_ * 2;
    ushort_t* vt   = (ushort_t*)(base + off); off += (size_t)B_ * H_ * HD_ * S_ * 2;
    ushort_t* ctx  = (ushort_t*)(base + off); off += (size_t)MTOK * D_ * 2;
    ushort_t* ff   = (ushort_t*)(base + off); off += (size_t)MTOK * F_ * 2;
    float*    qkvb = (float*)(base + off);    off += 3072 * 4;
    ushort_t* wqkvT= (ushort_t*)(base + off); off += (size_t)3 * D_ * D_ * 2;
    ushort_t* woT  = (ushort_t*)(base + off); off += (size_t)D_ * D_ * 2;
    ushort_t* w1T  = (ushort_t*)(base + off); off += (size_t)D_ * F_ * 2;
    ushort_t* w2T  = (ushort_t*)(base + off); off += (size_t)F_ * D_ * 2;
    ushort_t* wouT = (ushort_t*)(base + off); off += (size_t)V_ * D_ * 2;
    if (ws_size < off) { ws_marker<<<1, 64, 0, stream>>>(out); return; }

    embed_pe<<<MTOK, 256, 0, stream>>>(ids, emb, x);

    for (int i = 0; i < L_; ++i) {
        prep_layer<<<3075, 256, 0, stream>>>(
            Wq + (size_t)i * D_ * D_, Wk + (size_t)i * D_ * D_,
            Wv + (size_t)i * D_ * D_, Wo + (size_t)i * D_ * D_,
            W1 + (size_t)i * D_ * F_, W2 + (size_t)i * F_ * D_,
            bq + i * D_, bk + i * D_, bv + i * D_,
            wqkvT, woT, w1T, w2T, qkvb);

        ln_kernel<<<MTOK, 256, 0, stream>>>(x, ln1g + i * D_, ln1b + i * D_, h);

        // qkv = h @ [Wq|Wk|Wv] + bias; V cols also scattered into vt
        gemm_bt<128,false,false,true,true><<<dim3(16, 24), 256, 0, stream>>>(
            h, D_, wqkvT, D_, qkv, 3 * D_, qkvb, nullptr, MTOK, 3 * D_, D_, vt);

        flash_attn<<<dim3(8, B_ * H_), 256, 0, stream>>>(qkv, vt, ctx);

        // x = x + ctx @ Wo + bo   (BN=64 -> 256 blocks, full fill)
        gemm_bt<64,false,true,false,false><<<dim3(16, 16), 256, 0, stream>>>(
            ctx, D_, woT, D_, x, D_, bo + i * D_, x, MTOK, D_, D_, nullptr);

        ln_kernel<<<MTOK, 256, 0, stream>>>(x, ln2g + i * D_, ln2b + i * D_, h);

        // ff = gelu(h @ W1 + b1)
        gemm_bt<128,true,false,true,false><<<dim3(16, 32), 256, 0, stream>>>(
            h, D_, w1T, D_, ff, F_, b1 + i * F_, nullptr, MTOK, F_, D_, nullptr);

        // x = x + ff @ W2 + b2   (BN=64 -> 256 blocks, full fill)
        gemm_bt<64,false,true,false,false><<<dim3(16, 16), 256, 0, stream>>>(
            ff, F_, w2T, F_, x, D_, b2 + i * D_, x, MTOK, D_, F_, nullptr);
    }

    ln_kernel<<<MTOK, 256, 0, stream>>>(x, fng, fnb, h);
    tconv<<<dim3(500, 16), 256, 0, stream>>>(Wout, wouT, D_, V_);
    gemm256<false,false><<<dim3(8, 125), 512, 0, stream>>>(
        h, D_, wouT, D_, out, V_, bout, MTOK, V_, D_);
}

// Round 9
// 1562.281 us; speedup vs baseline: 1.7873x; 1.0127x over previous
//
#include <hip/hip_runtime.h>
#include <math.h>

// ---- problem constants ----
#define V_   32000
#define D_   1024
#define H_   16
#define HD_  64
#define L_   6
#define F_   4096
#define S_   1024
#define B_   2
#define MTOK (B_*S_)      // 2048
#define EPSLN 1e-5f

typedef unsigned short ushort_t;
typedef __attribute__((ext_vector_type(8))) short  s16x8;
typedef __attribute__((ext_vector_type(4))) float  f32x4;
typedef __attribute__((ext_vector_type(4))) unsigned short u16x4;

__device__ __forceinline__ float bf2f(unsigned short u) {
    unsigned int x = ((unsigned int)u) << 16;
    return __builtin_bit_cast(float, x);
}
__device__ __forceinline__ unsigned short f2bf(float f) {
    unsigned int x = __builtin_bit_cast(unsigned int, f);
    unsigned int r = (x + 0x7FFFu + ((x >> 16) & 1u)) >> 16;   // RNE
    return (unsigned short)r;
}
__device__ __forceinline__ float gelu_f(float x) {
    float y = 0.7978845608f * (x + 0.044715f * x * x * x);
    float t = 1.0f - 2.0f / (__expf(2.0f * y) + 1.0f);
    return 0.5f * x * (1.0f + t);
}

__device__ __forceinline__ float blk_sum(float v, float* sb) {
    #pragma unroll
    for (int o = 32; o; o >>= 1) v += __shfl_xor(v, o, 64);
    int w = threadIdx.x >> 6;
    __syncthreads();
    if ((threadIdx.x & 63) == 0) sb[w] = v;
    __syncthreads();
    return sb[0] + sb[1] + sb[2] + sb[3];
}

// =====================================================================
// gemm_bt: 128xBNxBK64, 2-phase dbuf + 8-slot XOR swizzle. BN in {64,128}.
// BK=64 halves barrier count vs BK=32 (32 MFMA between barriers @BN=128).
// XCD-chunked block swizzle (grids %8==0): each XCD gets a contiguous
// n-panel range -> B-panels fetched ~once per XCD L2, not 8x.
// VOUT: for QKV, also scatter V columns (gn>=2048) into vt[BH][HD][S].
// =====================================================================
template<int BN, bool GELU, bool RES, bool OUTBF, bool VOUT>
__global__ __launch_bounds__(256)
void gemm_bt(const ushort_t* __restrict__ A, int lda,
             const ushort_t* __restrict__ BT, int ldb,
             void* __restrict__ Cv, int ldc,
             const float* __restrict__ bias,
             const float* __restrict__ res,
             int M, int N, int K, ushort_t* __restrict__ vtp)
{
    const int BK = 64;
    const int NF = BN / 32;          // n-frags per wave
    int nwg = gridDim.x * gridDim.y;
    int id  = blockIdx.x + gridDim.x * blockIdx.y;
    int swz = ((nwg & 7) == 0) ? ((id & 7) * (nwg >> 3) + (id >> 3)) : id;
    int m0 = (swz % gridDim.x) * 128;
    int n0 = (swz / gridDim.x) * BN;

    __shared__ __align__(16) ushort_t lA[2][128 * BK];
    __shared__ __align__(16) ushort_t lB[2][BN * BK];

    int tid  = threadIdx.x;
    int lane = tid & 63;
    int wave = tid >> 6;
    int lr = lane & 15, lg = lane >> 4;
    int wr = wave >> 1, wc = wave & 1;

    f32x4 acc[4][NF] = {};
    int nkt = K / BK;

    auto stage = [&](int buf, int kt) {
        int k0 = kt * BK;
        #pragma unroll
        for (int i = 0; i < 4; ++i) {
            int e8  = i * 256 + tid;           // 16B units, 0..1023
            int row = e8 >> 3, slot = e8 & 7;
            int ls  = slot ^ (row & 7);
            const ushort_t* g = A + (size_t)(m0 + row) * lda + k0 + ls * 8;
            __builtin_amdgcn_global_load_lds(
                (const __attribute__((address_space(1))) void*)g,
                (__attribute__((address_space(3))) void*)&lA[buf][e8 * 8], 16, 0, 0);
        }
        #pragma unroll
        for (int i = 0; i < BN / 32; ++i) {
            int e8  = i * 256 + tid;
            int row = e8 >> 3, slot = e8 & 7;
            int ls  = slot ^ (row & 7);
            const ushort_t* g = BT + (size_t)(n0 + row) * ldb + k0 + ls * 8;
            __builtin_amdgcn_global_load_lds(
                (const __attribute__((address_space(1))) void*)g,
                (__attribute__((address_space(3))) void*)&lB[buf][e8 * 8], 16, 0, 0);
        }
    };

    stage(0, 0);
    __syncthreads();

    int cur = 0;
    for (int kt = 0; kt < nkt; ++kt) {
        if (kt + 1 < nkt) stage(cur ^ 1, kt + 1);
        __builtin_amdgcn_sched_barrier(0);
        s16x8 af[4][2], bfr[NF][2];
        #pragma unroll
        for (int m = 0; m < 4; ++m) {
            int row = wr * 64 + m * 16 + lr;
            #pragma unroll
            for (int ks = 0; ks < 2; ++ks) {
                int sl = (lg + ks * 4) ^ (row & 7);
                af[m][ks] = *(const s16x8*)&lA[cur][row * BK + sl * 8];
            }
        }
        #pragma unroll
        for (int n = 0; n < NF; ++n) {
            int row = wc * (BN / 2) + n * 16 + lr;
            #pragma unroll
            for (int ks = 0; ks < 2; ++ks) {
                int sl = (lg + ks * 4) ^ (row & 7);
                bfr[n][ks] = *(const s16x8*)&lB[cur][row * BK + sl * 8];
            }
        }
        __builtin_amdgcn_s_setprio(1);
        #pragma unroll
        for (int m = 0; m < 4; ++m)
            #pragma unroll
            for (int n = 0; n < NF; ++n)
                #pragma unroll
                for (int ks = 0; ks < 2; ++ks)
                    acc[m][n] = __builtin_amdgcn_mfma_f32_16x16x32_bf16(
                        af[m][ks], bfr[n][ks], acc[m][n], 0, 0, 0);
        __builtin_amdgcn_s_setprio(0);
        __syncthreads();
        cur ^= 1;
    }

    float*    Cf = (float*)Cv;
    ushort_t* Cb = (ushort_t*)Cv;
    #pragma unroll
    for (int m = 0; m < 4; ++m) {
        int gm0 = m0 + wr * 64 + m * 16 + lg * 4;
        #pragma unroll
        for (int n = 0; n < NF; ++n) {
            int gn = n0 + wc * (BN / 2) + n * 16 + lr;
            #pragma unroll
            for (int j = 0; j < 4; ++j) {
                float v = acc[m][n][j];
                if (bias) v += bias[gn];
                size_t ci = (size_t)(gm0 + j) * ldc + gn;
                if (RES)  v += res[ci];
                if (GELU) v = gelu_f(v);
                if (OUTBF) Cb[ci] = f2bf(v);
                else       Cf[ci] = v;
                if (VOUT && gn >= 2048) {
                    int hv = gn - 2048;
                    int mm = gm0 + j;
                    vtp[((size_t)(((mm >> 10) << 4) + (hv >> 6)) * 64
                         + (hv & 63)) * 1024 + (mm & 1023)] = f2bf(v);
                }
            }
        }
    }
}

// =====================================================================
// Flash attention, LOAD-BALANCED: grid (8, BH). Block x processes
// q-tiles {x, 15-x}: 17 KV-iters for EVERY block. K/V double-buffered
// with top-of-iter prefetch; setprio around MFMA clusters.
// =====================================================================
__global__ __launch_bounds__(256)
void flash_attn(const ushort_t* __restrict__ qkv,
                const ushort_t* __restrict__ vt,
                ushort_t* __restrict__ ctx)
{
    const int QB = 64, KB = 64;
    int z  = blockIdx.y;            // b*H + h
    int b  = z >> 4, hh = z & 15;

    __shared__ __align__(16) ushort_t Qs[QB * 64];
    __shared__ __align__(16) ushort_t Ks[2][KB * 64];
    __shared__ __align__(16) ushort_t Vs[2][64 * KB];
    __shared__ float    Ss[QB][68];
    __shared__ __align__(16) ushort_t Ps[QB][72];
    __shared__ float mrow[QB], lrow[QB], arow[QB];

    int tid  = threadIdx.x;
    int lane = tid & 63, wave = tid >> 6;
    int lr = lane & 15, lg = lane >> 4;
    int r = tid >> 2, p = tid & 3;

    auto stageKV = [&](int buf, int kv0) {
        const ushort_t* kbase = qkv + (size_t)(b * S_ + kv0) * 3072 + 1024 + hh * HD_;
        const ushort_t* vbase = vt + (size_t)z * HD_ * S_ + kv0;
        #pragma unroll
        for (int rnd = 0; rnd < 2; ++rnd) {
            int e8 = rnd * 256 + tid;
            int row = e8 >> 3, slot = e8 & 7;
            int ls = slot ^ (row & 7);
            const ushort_t* gk = kbase + (size_t)row * 3072 + ls * 8;
            __builtin_amdgcn_global_load_lds(
                (const __attribute__((address_space(1))) void*)gk,
                (__attribute__((address_space(3))) void*)&Ks[buf][e8 * 8], 16, 0, 0);
            const ushort_t* gv = vbase + (size_t)row * S_ + ls * 8;
            __builtin_amdgcn_global_load_lds(
                (const __attribute__((address_space(1))) void*)gv,
                (__attribute__((address_space(3))) void*)&Vs[buf][e8 * 8], 16, 0, 0);
        }
    };

    #pragma unroll
    for (int half = 0; half < 2; ++half) {
        int qt = half ? (15 - (int)blockIdx.x) : (int)blockIdx.x;
        int q0 = qt * QB;

        if (tid < QB) { mrow[tid] = -1e30f; lrow[tid] = 0.f; }
        const ushort_t* qbase = qkv + (size_t)(b * S_ + q0) * 3072 + hh * HD_;
        #pragma unroll
        for (int rnd = 0; rnd < 2; ++rnd) {
            int e8   = rnd * 256 + tid;
            int row  = e8 >> 3;
            int slot = e8 & 7;
            int ls   = slot ^ (row & 7);
            const ushort_t* g = qbase + (size_t)row * 3072 + ls * 8;
            __builtin_amdgcn_global_load_lds(
                (const __attribute__((address_space(1))) void*)g,
                (__attribute__((address_space(3))) void*)&Qs[e8 * 8], 16, 0, 0);
        }
        stageKV(0, 0);
        __syncthreads();

        s16x8 qa[4][2];
        #pragma unroll
        for (int mf = 0; mf < 4; ++mf)
            #pragma unroll
            for (int ks = 0; ks < 2; ++ks) {
                int row = mf * 16 + lr;
                int sl  = (lg + ks * 4) ^ (row & 7);
                qa[mf][ks] = *(const s16x8*)&Qs[row * 64 + sl * 8];
            }

        f32x4 acc[4] = {};
        int kv_end = q0 + QB;
        int cur = 0;
        for (int kv0 = 0; kv0 < kv_end; kv0 += KB) {
            if (kv0 + KB < kv_end) stageKV(cur ^ 1, kv0 + KB);

            s16x8 kb[2];
            #pragma unroll
            for (int ks = 0; ks < 2; ++ks) {
                int row = wave * 16 + lr;
                int sl  = (lg + ks * 4) ^ (row & 7);
                kb[ks] = *(const s16x8*)&Ks[cur][row * 64 + sl * 8];
            }
            f32x4 sa[4] = {};
            __builtin_amdgcn_s_setprio(1);
            #pragma unroll
            for (int mf = 0; mf < 4; ++mf)
                #pragma unroll
                for (int ks = 0; ks < 2; ++ks)
                    sa[mf] = __builtin_amdgcn_mfma_f32_16x16x32_bf16(
                        qa[mf][ks], kb[ks], sa[mf], 0, 0, 0);
            __builtin_amdgcn_s_setprio(0);

            int ki = kv0 + wave * 16 + lr;
            #pragma unroll
            for (int mf = 0; mf < 4; ++mf)
                #pragma unroll
                for (int j = 0; j < 4; ++j) {
                    int qi = q0 + mf * 16 + lg * 4 + j;
                    float s = (ki <= qi) ? sa[mf][j] * 0.125f : -1e30f;
                    Ss[mf * 16 + lg * 4 + j][wave * 16 + lr] = s;
                }
            __syncthreads();

            float mo = mrow[r];
            float sv[16];
            float pm = -1e30f;
            #pragma unroll
            for (int i = 0; i < 16; ++i) {
                sv[i] = Ss[r][p * 16 + i];
                pm = fmaxf(pm, sv[i]);
            }
            pm = fmaxf(pm, __shfl_xor(pm, 1, 64));
            pm = fmaxf(pm, __shfl_xor(pm, 2, 64));
            float M = fmaxf(mo, pm);
            float sum = 0.f;
            s16x8 pk0, pk1;
            #pragma unroll
            for (int i = 0; i < 8; ++i) {
                float e0 = __expf(sv[i] - M);
                float e1 = __expf(sv[i + 8] - M);
                sum += e0 + e1;
                pk0[i] = (short)f2bf(e0);
                pk1[i] = (short)f2bf(e1);
            }
            *(s16x8*)&Ps[r][p * 16]     = pk0;
            *(s16x8*)&Ps[r][p * 16 + 8] = pk1;
            sum += __shfl_xor(sum, 1, 64);
            sum += __shfl_xor(sum, 2, 64);
            if (p == 0) {
                float al = __expf(mo - M);
                arow[r] = al;
                mrow[r] = M;
                lrow[r] = lrow[r] * al + sum;
            }
            __syncthreads();

            #pragma unroll
            for (int mf = 0; mf < 4; ++mf) {
                #pragma unroll
                for (int j = 0; j < 4; ++j)
                    acc[mf][j] *= arow[mf * 16 + lg * 4 + j];
            }
            s16x8 vb[2];
            #pragma unroll
            for (int ks = 0; ks < 2; ++ks) {
                int row = wave * 16 + lr;
                int sl  = (lg + ks * 4) ^ (row & 7);
                vb[ks] = *(const s16x8*)&Vs[cur][row * 64 + sl * 8];
            }
            __builtin_amdgcn_s_setprio(1);
            #pragma unroll
            for (int mf = 0; mf < 4; ++mf)
                #pragma unroll
                for (int ks = 0; ks < 2; ++ks) {
                    s16x8 pa = *(const s16x8*)((const char*)&Ps[0][0]
                                + (mf * 16 + lr) * 144 + lg * 16 + ks * 64);
                    acc[mf] = __builtin_amdgcn_mfma_f32_16x16x32_bf16(
                        pa, vb[ks], acc[mf], 0, 0, 0);
                }
            __builtin_amdgcn_s_setprio(0);
            __syncthreads();
            cur ^= 1;
        }

        #pragma unroll
        for (int mf = 0; mf < 4; ++mf)
            #pragma unroll
            for (int j = 0; j < 4; ++j) {
                int rr = mf * 16 + lg * 4 + j;
                float o = acc[mf][j] / lrow[rr];
                ctx[(size_t)(b * S_ + q0 + rr) * D_ + hh * HD_ + wave * 16 + lr] = f2bf(o);
            }
        __syncthreads();   // protect Qs/Ks/Vs/state before next half
    }
}

// =====================================================================
// prep_layer: weight transposes+converts for one layer + qkv bias concat.
// 64x64 tiles: 256B-coalesced reads, 128B packed bf16x2 writes.
// =====================================================================
__global__ __launch_bounds__(256)
void prep_layer(const float* __restrict__ Wq, const float* __restrict__ Wk,
                const float* __restrict__ Wv, const float* __restrict__ Wo,
                const float* __restrict__ W1, const float* __restrict__ W2,
                const float* __restrict__ bq, const float* __restrict__ bk,
                const float* __restrict__ bv,
                ushort_t* __restrict__ wqkvT, ushort_t* __restrict__ woT,
                ushort_t* __restrict__ w1T, ushort_t* __restrict__ w2T,
                float* __restrict__ qkvb)
{
    int bid = blockIdx.x;
    if (bid >= 3072) {
        int j = bid - 3072;
        const float* bsrc = (j == 0) ? bq : (j == 1) ? bk : bv;
        int c = threadIdx.x * 4;
        *(f32x4*)&qkvb[j * 1024 + c] = *(const f32x4*)&bsrc[c];
        return;
    }
    __shared__ float t[64][65];
    int tid = threadIdx.x;
    int tx = tid & 63, ty = tid >> 6;
    const float* src; ushort_t* dst; int R, C, c0, r0;
    if (bid < 1024) {
        int mat = bid >> 8, tnum = bid & 255;
        src = (mat == 0) ? Wq : (mat == 1) ? Wk : (mat == 2) ? Wv : Wo;
        dst = (mat < 3) ? (wqkvT + (size_t)mat * D_ * D_) : woT;
        R = D_; C = D_;
        c0 = (tnum & 15) * 64; r0 = (tnum >> 4) * 64;
    } else if (bid < 2048) {
        int tnum = bid - 1024;
        src = W1; dst = w1T; R = D_; C = F_;
        c0 = (tnum & 63) * 64; r0 = (tnum >> 6) * 64;
    } else {
        int tnum = bid - 2048;
        src = W2; dst = w2T; R = F_; C = D_;
        c0 = (tnum & 15) * 64; r0 = (tnum >> 4) * 64;
    }
    #pragma unroll
    for (int i = 0; i < 16; ++i)
        t[ty + i * 4][tx] = src[(size_t)(r0 + ty + i * 4) * C + c0 + tx];
    __syncthreads();
    int u = tid & 31, v = tid >> 5;
    #pragma unroll
    for (int i = 0; i < 8; ++i) {
        int cc = v + i * 8;
        unsigned int val = (unsigned int)f2bf(t[u * 2][cc])
                         | ((unsigned int)f2bf(t[u * 2 + 1][cc]) << 16);
        *(unsigned int*)&dst[(size_t)(c0 + cc) * R + r0 + u * 2] = val;
    }
}

// ---- f32 [R,C] -> bf16 [C,R] transpose-convert, 64x64 tiles (Wout) ----
__global__ __launch_bounds__(256)
void tconv(const float* __restrict__ in, ushort_t* __restrict__ out, int R, int C)
{
    __shared__ float t[64][65];
    int c0 = blockIdx.x * 64, r0 = blockIdx.y * 64;
    int tid = threadIdx.x;
    int tx = tid & 63, ty = tid >> 6;
    #pragma unroll
    for (int i = 0; i < 16; ++i)
        t[ty + i * 4][tx] = in[(size_t)(r0 + ty + i * 4) * C + c0 + tx];
    __syncthreads();
    int u = tid & 31, v = tid >> 5;
    #pragma unroll
    for (int i = 0; i < 8; ++i) {
        int cc = v + i * 8;
        unsigned int val = (unsigned int)f2bf(t[u * 2][cc])
                         | ((unsigned int)f2bf(t[u * 2 + 1][cc]) << 16);
        *(unsigned int*)&out[(size_t)(c0 + cc) * R + r0 + u * 2] = val;
    }
}

// ---- embedding * sqrt(D) + sinusoidal PE -> x (f32) ----
__global__ __launch_bounds__(256)
void embed_pe(const int* __restrict__ ids, const float* __restrict__ emb,
              float* __restrict__ x)
{
    int row = blockIdx.x;
    int s   = row & (S_ - 1);
    int id  = ids[row];
    int d   = threadIdx.x * 4;
    f32x4 ev = *(const f32x4*)&emb[(size_t)id * D_ + d];
    f32x4 o;
    #pragma unroll
    for (int j = 0; j < 4; ++j) {
        int dd = d + j;
        int i  = dd >> 1;
        float div = expf(-(float)(2 * i) * (9.210340371976184f / 1024.0f));
        float arg = (float)s * div;
        float pe  = (dd & 1) ? cosf(arg) : sinf(arg);
        o[j] = ev[j] * 32.0f + pe;
    }
    *(f32x4*)&x[(size_t)row * D_ + d] = o;
}

// ---- LayerNorm row kernel: f32 in -> bf16 out ----
__global__ __launch_bounds__(256)
void ln_kernel(const float* __restrict__ x, const float* __restrict__ g,
               const float* __restrict__ b, ushort_t* __restrict__ out)
{
    __shared__ float sb[4];
    int row = blockIdx.x;
    const float* xr = x + (size_t)row * D_;
    int c = threadIdx.x * 4;
    f32x4 v = *(const f32x4*)&xr[c];
    float s = v[0] + v[1] + v[2] + v[3];
    s = blk_sum(s, sb);
    float mean = s * (1.0f / D_);
    f32x4 dv = v - mean;
    float sq = dv[0]*dv[0] + dv[1]*dv[1] + dv[2]*dv[2] + dv[3]*dv[3];
    sq = blk_sum(sq, sb);
    float rstd = rsqrtf(sq * (1.0f / D_) + EPSLN);
    u16x4 o;
    #pragma unroll
    for (int j = 0; j < 4; ++j)
        o[j] = f2bf(dv[j] * rstd * g[c + j] + b[c + j]);
    *(u16x4*)&out[(size_t)row * D_ + c] = o;
}

__global__ void ws_marker(float* o) { o[threadIdx.x] = -777777.0f; }

// =====================================================================
extern "C" void kernel_launch(void* const* d_in, const int* in_sizes, int n_in,
                              void* d_out, int out_size, void* d_ws, size_t ws_size,
                              hipStream_t stream)
{
    (void)in_sizes; (void)n_in; (void)out_size;
    const int*   ids  = (const int*)d_in[0];
    const float* emb  = (const float*)d_in[1];
    const float* Wq   = (const float*)d_in[2];
    const float* bq   = (const float*)d_in[3];
    const float* Wk   = (const float*)d_in[4];
    const float* bk   = (const float*)d_in[5];
    const float* Wv   = (const float*)d_in[6];
    const float* bv   = (const float*)d_in[7];
    const float* Wo   = (const float*)d_in[8];
    const float* bo   = (const float*)d_in[9];
    const float* ln1g = (const float*)d_in[10];
    const float* ln1b = (const float*)d_in[11];
    const float* ln2g = (const float*)d_in[12];
    const float* ln2b = (const float*)d_in[13];
    const float* W1   = (const float*)d_in[14];
    const float* b1   = (const float*)d_in[15];
    const float* W2   = (const float*)d_in[16];
    const float* b2   = (const float*)d_in[17];
    const float* fng  = (const float*)d_in[18];
    const float* fnb  = (const float*)d_in[19];
    const float* Wout = (const float*)d_in[20];
    const float* bout = (const float*)d_in[21];
    float* out = (float*)d_out;

    // ---- workspace layout ----
    char* base = (char*)d_ws;
    size_t off = 0;
    float*    x    = (float*)(base + off);    off += (size_t)MTOK * D_ * 4;
    ushort_t* h    = (ushort_t*)(base + off); off += (size_t)MTOK * D_ * 2;
    ushort_t* qkv  = (ushort_t*)(base + off); off += (size_t)MTOK * 3 * D_ * 2;
    ushort_t* vt   = (ushort_t*)(base + off); off += (size_t)B_ * H_ * HD_ * S_ * 2;
    ushort_t* ctx  = (ushort_t*)(base + off); off += (size_t)MTOK * D_ * 2;
    ushort_t* ff   = (ushort_t*)(base + off); off += (size_t)MTOK * F_ * 2;
    float*    qkvb = (float*)(base + off);    off += 3072 * 4;
    ushort_t* wqkvT= (ushort_t*)(base + off); off += (size_t)3 * D_ * D_ * 2;
    ushort_t* woT  = (ushort_t*)(base + off); off += (size_t)D_ * D_ * 2;
    ushort_t* w1T  = (ushort_t*)(base + off); off += (size_t)D_ * F_ * 2;
    ushort_t* w2T  = (ushort_t*)(base + off); off += (size_t)F_ * D_ * 2;
    ushort_t* wouT = (ushort_t*)(base + off); off += (size_t)V_ * D_ * 2;
    if (ws_size < off) { ws_marker<<<1, 64, 0, stream>>>(out); return; }

    embed_pe<<<MTOK, 256, 0, stream>>>(ids, emb, x);

    for (int i = 0; i < L_; ++i) {
        prep_layer<<<3075, 256, 0, stream>>>(
            Wq + (size_t)i * D_ * D_, Wk + (size_t)i * D_ * D_,
            Wv + (size_t)i * D_ * D_, Wo + (size_t)i * D_ * D_,
            W1 + (size_t)i * D_ * F_, W2 + (size_t)i * F_ * D_,
            bq + i * D_, bk + i * D_, bv + i * D_,
            wqkvT, woT, w1T, w2T, qkvb);

        ln_kernel<<<MTOK, 256, 0, stream>>>(x, ln1g + i * D_, ln1b + i * D_, h);

        // qkv = h @ [Wq|Wk|Wv] + bias; V cols also scattered into vt
        gemm_bt<128,false,false,true,true><<<dim3(16, 24), 256, 0, stream>>>(
            h, D_, wqkvT, D_, qkv, 3 * D_, qkvb, nullptr, MTOK, 3 * D_, D_, vt);

        flash_attn<<<dim3(8, B_ * H_), 256, 0, stream>>>(qkv, vt, ctx);

        // x = x + ctx @ Wo + bo   (BN=64 -> 256 blocks, full fill)
        gemm_bt<64,false,true,false,false><<<dim3(16, 16), 256, 0, stream>>>(
            ctx, D_, woT, D_, x, D_, bo + i * D_, x, MTOK, D_, D_, nullptr);

        ln_kernel<<<MTOK, 256, 0, stream>>>(x, ln2g + i * D_, ln2b + i * D_, h);

        // ff = gelu(h @ W1 + b1)
        gemm_bt<128,true,false,true,false><<<dim3(16, 32), 256, 0, stream>>>(
            h, D_, w1T, D_, ff, F_, b1 + i * F_, nullptr, MTOK, F_, D_, nullptr);

        // x = x + ff @ W2 + b2   (BN=64 -> 256 blocks, full fill; 64 K-iters)
        gemm_bt<64,false,true,false,false><<<dim3(16, 16), 256, 0, stream>>>(
            ff, F_, w2T, F_, x, D_, b2 + i * D_, x, MTOK, D_, F_, nullptr);
    }

    ln_kernel<<<MTOK, 256, 0, stream>>>(x, fng, fnb, h);
    tconv<<<dim3(500, 16), 256, 0, stream>>>(Wout, wouT, D_, V_);
    // logits: 128x128 BK64 tiles, m-fast grid + XCD chunking, 4000 blocks
    gemm_bt<128,false,false,false,false><<<dim3(16, 250), 256, 0, stream>>>(
        h, D_, wouT, D_, out, V_, bout, nullptr, MTOK, V_, D_, nullptr);
}

// Round 10
// 1477.766 us; speedup vs baseline: 1.8895x; 1.0572x over previous
//
#include <hip/hip_runtime.h>
#include <math.h>

// ---- problem constants ----
#define V_   32000
#define D_   1024
#define H_   16
#define HD_  64
#define L_   6
#define F_   4096
#define S_   1024
#define B_   2
#define MTOK (B_*S_)      // 2048
#define EPSLN 1e-5f

typedef unsigned short ushort_t;
typedef __attribute__((ext_vector_type(8))) short  s16x8;
typedef __attribute__((ext_vector_type(4))) float  f32x4;
typedef __attribute__((ext_vector_type(4))) unsigned short u16x4;

__device__ __forceinline__ float bf2f(unsigned short u) {
    unsigned int x = ((unsigned int)u) << 16;
    return __builtin_bit_cast(float, x);
}
__device__ __forceinline__ unsigned short f2bf(float f) {
    unsigned int x = __builtin_bit_cast(unsigned int, f);
    unsigned int r = (x + 0x7FFFu + ((x >> 16) & 1u)) >> 16;   // RNE
    return (unsigned short)r;
}
__device__ __forceinline__ float gelu_f(float x) {
    float y = 0.7978845608f * (x + 0.044715f * x * x * x);
    float t = 1.0f - 2.0f / (__expf(2.0f * y) + 1.0f);
    return 0.5f * x * (1.0f + t);
}

__device__ __forceinline__ float blk_sum(float v, float* sb) {
    #pragma unroll
    for (int o = 32; o; o >>= 1) v += __shfl_xor(v, o, 64);
    int w = threadIdx.x >> 6;
    __syncthreads();
    if ((threadIdx.x & 63) == 0) sb[w] = v;
    __syncthreads();
    return sb[0] + sb[1] + sb[2] + sb[3];
}

// =====================================================================
// gemm256: 2-phase-per-K-tile pipelined 256x256xBK64 bf16 MFMA GEMM.
// Measured-best for the N=32000 logits shape (177us, 740 TF): the 256^2
// tile's 2x arithmetic intensity keeps the 65MB B-stream L2-resident
// per XCD, where 128^2 tiles tipped it memory-bound (r9: 270us).
// =====================================================================
template<bool GELU, bool OUTBF>
__global__ __launch_bounds__(512, 2)
void gemm256(const ushort_t* __restrict__ A, int lda,
             const ushort_t* __restrict__ BT, int ldb,
             void* __restrict__ Cv, int ldc,
             const float* __restrict__ bias,
             int M, int N, int K)
{
    int nmt = M >> 8;
    int nwg = gridDim.x * gridDim.y;
    int id  = blockIdx.x + gridDim.x * blockIdx.y;
    int swz = ((nwg & 7) == 0) ? ((id & 7) * (nwg >> 3) + (id >> 3)) : id;
    int m0 = (swz % nmt) << 8;
    int n0 = (swz / nmt) << 8;

    __shared__ __align__(16) ushort_t lA[2][256 * 64];
    __shared__ __align__(16) ushort_t lB[2][256 * 64];

    int tid  = threadIdx.x;
    int lane = tid & 63, wave = tid >> 6;
    int lr = lane & 15, lg = lane >> 4;
    int wm = wave >> 2, wn = wave & 3;

    f32x4 acc[8][4] = {};
    int nkt = K >> 6;

    auto stageu = [&](int buf, int kt, int sel) {
        int k0 = kt << 6;
        const ushort_t* src = (sel < 2) ? A : BT;
        int ld    = (sel < 2) ? lda : ldb;
        int rbase = ((sel < 2) ? m0 : n0) + ((sel & 1) << 7);
        ushort_t* dst = ((sel < 2) ? &lA[buf][0] : &lB[buf][0]) + ((sel & 1) << 13);
        #pragma unroll
        for (int r = 0; r < 2; ++r) {
            int e8  = r * 512 + tid;
            int row = e8 >> 3, slot = e8 & 7;
            int ls  = slot ^ (row & 7);
            const ushort_t* g = src + (size_t)(rbase + row) * ld + k0 + ls * 8;
            __builtin_amdgcn_global_load_lds(
                (const __attribute__((address_space(1))) void*)g,
                (__attribute__((address_space(3))) void*)(dst + e8 * 8), 16, 0, 0);
        }
    };
    auto rdA = [&](int buf, int row, int ks) -> s16x8 {
        int sl = (lg + ks * 4) ^ (row & 7);
        return *(const s16x8*)&lA[buf][row * 64 + sl * 8];
    };
    auto rdB = [&](int buf, int row, int ks) -> s16x8 {
        int sl = (lg + ks * 4) ^ (row & 7);
        return *(const s16x8*)&lB[buf][row * 64 + sl * 8];
    };

    stageu(0, 0, 0); stageu(0, 0, 1); stageu(0, 0, 2); stageu(0, 0, 3);
    if (nkt > 1) {
        stageu(1, 1, 2); stageu(1, 1, 3);
        asm volatile("s_waitcnt vmcnt(4)" ::: "memory");
    } else {
        asm volatile("s_waitcnt vmcnt(0)" ::: "memory");
    }
    __builtin_amdgcn_sched_barrier(0);
    __builtin_amdgcn_s_barrier();

    for (int u = 0; u < nkt; ++u) {
        int cur = u & 1, nxt = cur ^ 1;
        s16x8 af0[4][2], af1[4][2], bf0[2][2], bf1[2][2];

        // ======== Phase A: af0 + bf0 + bf1 reads; stage A(u+1) ========
        #pragma unroll
        for (int mf = 0; mf < 4; ++mf)
            #pragma unroll
            for (int ks = 0; ks < 2; ++ks)
                af0[mf][ks] = rdA(cur, wm * 128 + mf * 16 + lr, ks);
        #pragma unroll
        for (int nf = 0; nf < 2; ++nf)
            #pragma unroll
            for (int ks = 0; ks < 2; ++ks) {
                bf0[nf][ks] = rdB(cur, wn * 64 + nf * 16 + lr, ks);
                bf1[nf][ks] = rdB(cur, wn * 64 + 32 + nf * 16 + lr, ks);
            }
        if (u + 1 < nkt) { stageu(nxt, u + 1, 0); stageu(nxt, u + 1, 1); }
        __builtin_amdgcn_s_barrier();
        asm volatile("s_waitcnt lgkmcnt(0)" ::: "memory");
        __builtin_amdgcn_sched_barrier(0);
        __builtin_amdgcn_s_setprio(1);
        #pragma unroll
        for (int mf = 0; mf < 4; ++mf)
            #pragma unroll
            for (int ks = 0; ks < 2; ++ks) {
                #pragma unroll
                for (int nf = 0; nf < 2; ++nf) {
                    acc[mf][nf]     = __builtin_amdgcn_mfma_f32_16x16x32_bf16(
                        af0[mf][ks], bf0[nf][ks], acc[mf][nf], 0, 0, 0);
                    acc[mf][2 + nf] = __builtin_amdgcn_mfma_f32_16x16x32_bf16(
                        af0[mf][ks], bf1[nf][ks], acc[mf][2 + nf], 0, 0, 0);
                }
            }
        __builtin_amdgcn_s_setprio(0);
        __builtin_amdgcn_s_barrier();

        // ======== Phase B: af1 reads; stage B(u+2) into cur ========
        #pragma unroll
        for (int mf = 0; mf < 4; ++mf)
            #pragma unroll
            for (int ks = 0; ks < 2; ++ks)
                af1[mf][ks] = rdA(cur, wm * 128 + 64 + mf * 16 + lr, ks);
        if (u + 2 < nkt) { stageu(cur, u + 2, 2); stageu(cur, u + 2, 3); }
        __builtin_amdgcn_s_barrier();
        asm volatile("s_waitcnt lgkmcnt(0)" ::: "memory");
        __builtin_amdgcn_sched_barrier(0);
        __builtin_amdgcn_s_setprio(1);
        #pragma unroll
        for (int mf = 0; mf < 4; ++mf)
            #pragma unroll
            for (int ks = 0; ks < 2; ++ks) {
                #pragma unroll
                for (int nf = 0; nf < 2; ++nf) {
                    acc[4 + mf][nf]     = __builtin_amdgcn_mfma_f32_16x16x32_bf16(
                        af1[mf][ks], bf0[nf][ks], acc[4 + mf][nf], 0, 0, 0);
                    acc[4 + mf][2 + nf] = __builtin_amdgcn_mfma_f32_16x16x32_bf16(
                        af1[mf][ks], bf1[nf][ks], acc[4 + mf][2 + nf], 0, 0, 0);
                }
            }
        __builtin_amdgcn_s_setprio(0);
        if (u + 2 < nkt) asm volatile("s_waitcnt vmcnt(4)" ::: "memory");
        else             asm volatile("s_waitcnt vmcnt(0)" ::: "memory");
        __builtin_amdgcn_sched_barrier(0);
        __builtin_amdgcn_s_barrier();
    }

    float*    Cf = (float*)Cv;
    ushort_t* Cb = (ushort_t*)Cv;
    #pragma unroll
    for (int mf = 0; mf < 8; ++mf) {
        int gm0 = m0 + wm * 128 + mf * 16 + lg * 4;
        #pragma unroll
        for (int nf = 0; nf < 4; ++nf) {
            int gn = n0 + wn * 64 + nf * 16 + lr;
            float bv = bias ? bias[gn] : 0.f;
            #pragma unroll
            for (int j = 0; j < 4; ++j) {
                float v = acc[mf][nf][j] + bv;
                if (GELU) v = gelu_f(v);
                size_t ci = (size_t)(gm0 + j) * ldc + gn;
                if (OUTBF) Cb[ci] = f2bf(v);
                else       Cf[ci] = v;
            }
        }
    }
}

// =====================================================================
// gemm_bt: 128xBNxBK64, 2-phase dbuf + 8-slot XOR swizzle. BN in {64,128}.
// BK=64 halves barrier count vs BK=32 (r9: -115us across layer GEMMs).
// XCD-chunked block swizzle. NOT for the logits shape (r9: memory-bound).
// VOUT: for QKV, also scatter V columns (gn>=2048) into vt[BH][HD][S].
// =====================================================================
template<int BN, bool GELU, bool RES, bool OUTBF, bool VOUT>
__global__ __launch_bounds__(256)
void gemm_bt(const ushort_t* __restrict__ A, int lda,
             const ushort_t* __restrict__ BT, int ldb,
             void* __restrict__ Cv, int ldc,
             const float* __restrict__ bias,
             const float* __restrict__ res,
             int M, int N, int K, ushort_t* __restrict__ vtp)
{
    const int BK = 64;
    const int NF = BN / 32;          // n-frags per wave
    int nwg = gridDim.x * gridDim.y;
    int id  = blockIdx.x + gridDim.x * blockIdx.y;
    int swz = ((nwg & 7) == 0) ? ((id & 7) * (nwg >> 3) + (id >> 3)) : id;
    int m0 = (swz % gridDim.x) * 128;
    int n0 = (swz / gridDim.x) * BN;

    __shared__ __align__(16) ushort_t lA[2][128 * BK];
    __shared__ __align__(16) ushort_t lB[2][BN * BK];

    int tid  = threadIdx.x;
    int lane = tid & 63;
    int wave = tid >> 6;
    int lr = lane & 15, lg = lane >> 4;
    int wr = wave >> 1, wc = wave & 1;

    f32x4 acc[4][NF] = {};
    int nkt = K / BK;

    auto stage = [&](int buf, int kt) {
        int k0 = kt * BK;
        #pragma unroll
        for (int i = 0; i < 4; ++i) {
            int e8  = i * 256 + tid;           // 16B units, 0..1023
            int row = e8 >> 3, slot = e8 & 7;
            int ls  = slot ^ (row & 7);
            const ushort_t* g = A + (size_t)(m0 + row) * lda + k0 + ls * 8;
            __builtin_amdgcn_global_load_lds(
                (const __attribute__((address_space(1))) void*)g,
                (__attribute__((address_space(3))) void*)&lA[buf][e8 * 8], 16, 0, 0);
        }
        #pragma unroll
        for (int i = 0; i < BN / 32; ++i) {
            int e8  = i * 256 + tid;
            int row = e8 >> 3, slot = e8 & 7;
            int ls  = slot ^ (row & 7);
            const ushort_t* g = BT + (size_t)(n0 + row) * ldb + k0 + ls * 8;
            __builtin_amdgcn_global_load_lds(
                (const __attribute__((address_space(1))) void*)g,
                (__attribute__((address_space(3))) void*)&lB[buf][e8 * 8], 16, 0, 0);
        }
    };

    stage(0, 0);
    __syncthreads();

    int cur = 0;
    for (int kt = 0; kt < nkt; ++kt) {
        if (kt + 1 < nkt) stage(cur ^ 1, kt + 1);
        __builtin_amdgcn_sched_barrier(0);
        s16x8 af[4][2], bfr[NF][2];
        #pragma unroll
        for (int m = 0; m < 4; ++m) {
            int row = wr * 64 + m * 16 + lr;
            #pragma unroll
            for (int ks = 0; ks < 2; ++ks) {
                int sl = (lg + ks * 4) ^ (row & 7);
                af[m][ks] = *(const s16x8*)&lA[cur][row * BK + sl * 8];
            }
        }
        #pragma unroll
        for (int n = 0; n < NF; ++n) {
            int row = wc * (BN / 2) + n * 16 + lr;
            #pragma unroll
            for (int ks = 0; ks < 2; ++ks) {
                int sl = (lg + ks * 4) ^ (row & 7);
                bfr[n][ks] = *(const s16x8*)&lB[cur][row * BK + sl * 8];
            }
        }
        __builtin_amdgcn_s_setprio(1);
        #pragma unroll
        for (int m = 0; m < 4; ++m)
            #pragma unroll
            for (int n = 0; n < NF; ++n)
                #pragma unroll
                for (int ks = 0; ks < 2; ++ks)
                    acc[m][n] = __builtin_amdgcn_mfma_f32_16x16x32_bf16(
                        af[m][ks], bfr[n][ks], acc[m][n], 0, 0, 0);
        __builtin_amdgcn_s_setprio(0);
        __syncthreads();
        cur ^= 1;
    }

    float*    Cf = (float*)Cv;
    ushort_t* Cb = (ushort_t*)Cv;
    #pragma unroll
    for (int m = 0; m < 4; ++m) {
        int gm0 = m0 + wr * 64 + m * 16 + lg * 4;
        #pragma unroll
        for (int n = 0; n < NF; ++n) {
            int gn = n0 + wc * (BN / 2) + n * 16 + lr;
            #pragma unroll
            for (int j = 0; j < 4; ++j) {
                float v = acc[m][n][j];
                if (bias) v += bias[gn];
                size_t ci = (size_t)(gm0 + j) * ldc + gn;
                if (RES)  v += res[ci];
                if (GELU) v = gelu_f(v);
                if (OUTBF) Cb[ci] = f2bf(v);
                else       Cf[ci] = v;
                if (VOUT && gn >= 2048) {
                    int hv = gn - 2048;
                    int mm = gm0 + j;
                    vtp[((size_t)(((mm >> 10) << 4) + (hv >> 6)) * 64
                         + (hv & 63)) * 1024 + (mm & 1023)] = f2bf(v);
                }
            }
        }
    }
}

// =====================================================================
// Flash attention, LOAD-BALANCED: grid (8, BH). Block x processes
// q-tiles {x, 15-x}: 17 KV-iters for EVERY block. K/V double-buffered
// with top-of-iter prefetch; setprio around MFMA clusters.
// =====================================================================
__global__ __launch_bounds__(256)
void flash_attn(const ushort_t* __restrict__ qkv,
                const ushort_t* __restrict__ vt,
                ushort_t* __restrict__ ctx)
{
    const int QB = 64, KB = 64;
    int z  = blockIdx.y;            // b*H + h
    int b  = z >> 4, hh = z & 15;

    __shared__ __align__(16) ushort_t Qs[QB * 64];
    __shared__ __align__(16) ushort_t Ks[2][KB * 64];
    __shared__ __align__(16) ushort_t Vs[2][64 * KB];
    __shared__ float    Ss[QB][68];
    __shared__ __align__(16) ushort_t Ps[QB][72];
    __shared__ float mrow[QB], lrow[QB], arow[QB];

    int tid  = threadIdx.x;
    int lane = tid & 63, wave = tid >> 6;
    int lr = lane & 15, lg = lane >> 4;
    int r = tid >> 2, p = tid & 3;

    auto stageKV = [&](int buf, int kv0) {
        const ushort_t* kbase = qkv + (size_t)(b * S_ + kv0) * 3072 + 1024 + hh * HD_;
        const ushort_t* vbase = vt + (size_t)z * HD_ * S_ + kv0;
        #pragma unroll
        for (int rnd = 0; rnd < 2; ++rnd) {
            int e8 = rnd * 256 + tid;
            int row = e8 >> 3, slot = e8 & 7;
            int ls = slot ^ (row & 7);
            const ushort_t* gk = kbase + (size_t)row * 3072 + ls * 8;
            __builtin_amdgcn_global_load_lds(
                (const __attribute__((address_space(1))) void*)gk,
                (__attribute__((address_space(3))) void*)&Ks[buf][e8 * 8], 16, 0, 0);
            const ushort_t* gv = vbase + (size_t)row * S_ + ls * 8;
            __builtin_amdgcn_global_load_lds(
                (const __attribute__((address_space(1))) void*)gv,
                (__attribute__((address_space(3))) void*)&Vs[buf][e8 * 8], 16, 0, 0);
        }
    };

    #pragma unroll
    for (int half = 0; half < 2; ++half) {
        int qt = half ? (15 - (int)blockIdx.x) : (int)blockIdx.x;
        int q0 = qt * QB;

        if (tid < QB) { mrow[tid] = -1e30f; lrow[tid] = 0.f; }
        const ushort_t* qbase = qkv + (size_t)(b * S_ + q0) * 3072 + hh * HD_;
        #pragma unroll
        for (int rnd = 0; rnd < 2; ++rnd) {
            int e8   = rnd * 256 + tid;
            int row  = e8 >> 3;
            int slot = e8 & 7;
            int ls   = slot ^ (row & 7);
            const ushort_t* g = qbase + (size_t)row * 3072 + ls * 8;
            __builtin_amdgcn_global_load_lds(
                (const __attribute__((address_space(1))) void*)g,
                (__attribute__((address_space(3))) void*)&Qs[e8 * 8], 16, 0, 0);
        }
        stageKV(0, 0);
        __syncthreads();

        s16x8 qa[4][2];
        #pragma unroll
        for (int mf = 0; mf < 4; ++mf)
            #pragma unroll
            for (int ks = 0; ks < 2; ++ks) {
                int row = mf * 16 + lr;
                int sl  = (lg + ks * 4) ^ (row & 7);
                qa[mf][ks] = *(const s16x8*)&Qs[row * 64 + sl * 8];
            }

        f32x4 acc[4] = {};
        int kv_end = q0 + QB;
        int cur = 0;
        for (int kv0 = 0; kv0 < kv_end; kv0 += KB) {
            if (kv0 + KB < kv_end) stageKV(cur ^ 1, kv0 + KB);

            s16x8 kb[2];
            #pragma unroll
            for (int ks = 0; ks < 2; ++ks) {
                int row = wave * 16 + lr;
                int sl  = (lg + ks * 4) ^ (row & 7);
                kb[ks] = *(const s16x8*)&Ks[cur][row * 64 + sl * 8];
            }
            f32x4 sa[4] = {};
            __builtin_amdgcn_s_setprio(1);
            #pragma unroll
            for (int mf = 0; mf < 4; ++mf)
                #pragma unroll
                for (int ks = 0; ks < 2; ++ks)
                    sa[mf] = __builtin_amdgcn_mfma_f32_16x16x32_bf16(
                        qa[mf][ks], kb[ks], sa[mf], 0, 0, 0);
            __builtin_amdgcn_s_setprio(0);

            int ki = kv0 + wave * 16 + lr;
            #pragma unroll
            for (int mf = 0; mf < 4; ++mf)
                #pragma unroll
                for (int j = 0; j < 4; ++j) {
                    int qi = q0 + mf * 16 + lg * 4 + j;
                    float s = (ki <= qi) ? sa[mf][j] * 0.125f : -1e30f;
                    Ss[mf * 16 + lg * 4 + j][wave * 16 + lr] = s;
                }
            __syncthreads();

            float mo = mrow[r];
            float sv[16];
            float pm = -1e30f;
            #pragma unroll
            for (int i = 0; i < 16; ++i) {
                sv[i] = Ss[r][p * 16 + i];
                pm = fmaxf(pm, sv[i]);
            }
            pm = fmaxf(pm, __shfl_xor(pm, 1, 64));
            pm = fmaxf(pm, __shfl_xor(pm, 2, 64));
            float M = fmaxf(mo, pm);
            float sum = 0.f;
            s16x8 pk0, pk1;
            #pragma unroll
            for (int i = 0; i < 8; ++i) {
                float e0 = __expf(sv[i] - M);
                float e1 = __expf(sv[i + 8] - M);
                sum += e0 + e1;
                pk0[i] = (short)f2bf(e0);
                pk1[i] = (short)f2bf(e1);
            }
            *(s16x8*)&Ps[r][p * 16]     = pk0;
            *(s16x8*)&Ps[r][p * 16 + 8] = pk1;
            sum += __shfl_xor(sum, 1, 64);
            sum += __shfl_xor(sum, 2, 64);
            if (p == 0) {
                float al = __expf(mo - M);
                arow[r] = al;
                mrow[r] = M;
                lrow[r] = lrow[r] * al + sum;
            }
            __syncthreads();

            #pragma unroll
            for (int mf = 0; mf < 4; ++mf) {
                #pragma unroll
                for (int j = 0; j < 4; ++j)
                    acc[mf][j] *= arow[mf * 16 + lg * 4 + j];
            }
            s16x8 vb[2];
            #pragma unroll
            for (int ks = 0; ks < 2; ++ks) {
                int row = wave * 16 + lr;
                int sl  = (lg + ks * 4) ^ (row & 7);
                vb[ks] = *(const s16x8*)&Vs[cur][row * 64 + sl * 8];
            }
            __builtin_amdgcn_s_setprio(1);
            #pragma unroll
            for (int mf = 0; mf < 4; ++mf)
                #pragma unroll
                for (int ks = 0; ks < 2; ++ks) {
                    s16x8 pa = *(const s16x8*)((const char*)&Ps[0][0]
                                + (mf * 16 + lr) * 144 + lg * 16 + ks * 64);
                    acc[mf] = __builtin_amdgcn_mfma_f32_16x16x32_bf16(
                        pa, vb[ks], acc[mf], 0, 0, 0);
                }
            __builtin_amdgcn_s_setprio(0);
            __syncthreads();
            cur ^= 1;
        }

        #pragma unroll
        for (int mf = 0; mf < 4; ++mf)
            #pragma unroll
            for (int j = 0; j < 4; ++j) {
                int rr = mf * 16 + lg * 4 + j;
                float o = acc[mf][j] / lrow[rr];
                ctx[(size_t)(b * S_ + q0 + rr) * D_ + hh * HD_ + wave * 16 + lr] = f2bf(o);
            }
        __syncthreads();   // protect Qs/Ks/Vs/state before next half
    }
}

// =====================================================================
// prep_layer: weight transposes+converts for one layer + qkv bias concat.
// 64x64 tiles: 256B-coalesced reads, 128B packed bf16x2 writes.
// =====================================================================
__global__ __launch_bounds__(256)
void prep_layer(const float* __restrict__ Wq, const float* __restrict__ Wk,
                const float* __restrict__ Wv, const float* __restrict__ Wo,
                const float* __restrict__ W1, const float* __restrict__ W2,
                const float* __restrict__ bq, const float* __restrict__ bk,
                const float* __restrict__ bv,
                ushort_t* __restrict__ wqkvT, ushort_t* __restrict__ woT,
                ushort_t* __restrict__ w1T, ushort_t* __restrict__ w2T,
                float* __restrict__ qkvb)
{
    int bid = blockIdx.x;
    if (bid >= 3072) {
        int j = bid - 3072;
        const float* bsrc = (j == 0) ? bq : (j == 1) ? bk : bv;
        int c = threadIdx.x * 4;
        *(f32x4*)&qkvb[j * 1024 + c] = *(const f32x4*)&bsrc[c];
        return;
    }
    __shared__ float t[64][65];
    int tid = threadIdx.x;
    int tx = tid & 63, ty = tid >> 6;
    const float* src; ushort_t* dst; int R, C, c0, r0;
    if (bid < 1024) {
        int mat = bid >> 8, tnum = bid & 255;
        src = (mat == 0) ? Wq : (mat == 1) ? Wk : (mat == 2) ? Wv : Wo;
        dst = (mat < 3) ? (wqkvT + (size_t)mat * D_ * D_) : woT;
        R = D_; C = D_;
        c0 = (tnum & 15) * 64; r0 = (tnum >> 4) * 64;
    } else if (bid < 2048) {
        int tnum = bid - 1024;
        src = W1; dst = w1T; R = D_; C = F_;
        c0 = (tnum & 63) * 64; r0 = (tnum >> 6) * 64;
    } else {
        int tnum = bid - 2048;
        src = W2; dst = w2T; R = F_; C = D_;
        c0 = (tnum & 15) * 64; r0 = (tnum >> 4) * 64;
    }
    #pragma unroll
    for (int i = 0; i < 16; ++i)
        t[ty + i * 4][tx] = src[(size_t)(r0 + ty + i * 4) * C + c0 + tx];
    __syncthreads();
    int u = tid & 31, v = tid >> 5;
    #pragma unroll
    for (int i = 0; i < 8; ++i) {
        int cc = v + i * 8;
        unsigned int val = (unsigned int)f2bf(t[u * 2][cc])
                         | ((unsigned int)f2bf(t[u * 2 + 1][cc]) << 16);
        *(unsigned int*)&dst[(size_t)(c0 + cc) * R + r0 + u * 2] = val;
    }
}

// ---- f32 [R,C] -> bf16 [C,R] transpose-convert, 64x64 tiles (Wout) ----
__global__ __launch_bounds__(256)
void tconv(const float* __restrict__ in, ushort_t* __restrict__ out, int R, int C)
{
    __shared__ float t[64][65];
    int c0 = blockIdx.x * 64, r0 = blockIdx.y * 64;
    int tid = threadIdx.x;
    int tx = tid & 63, ty = tid >> 6;
    #pragma unroll
    for (int i = 0; i < 16; ++i)
        t[ty + i * 4][tx] = in[(size_t)(r0 + ty + i * 4) * C + c0 + tx];
    __syncthreads();
    int u = tid & 31, v = tid >> 5;
    #pragma unroll
    for (int i = 0; i < 8; ++i) {
        int cc = v + i * 8;
        unsigned int val = (unsigned int)f2bf(t[u * 2][cc])
                         | ((unsigned int)f2bf(t[u * 2 + 1][cc]) << 16);
        *(unsigned int*)&out[(size_t)(c0 + cc) * R + r0 + u * 2] = val;
    }
}

// ---- embedding * sqrt(D) + sinusoidal PE -> x (f32) ----
__global__ __launch_bounds__(256)
void embed_pe(const int* __restrict__ ids, const float* __restrict__ emb,
              float* __restrict__ x)
{
    int row = blockIdx.x;
    int s   = row & (S_ - 1);
    int id  = ids[row];
    int d   = threadIdx.x * 4;
    f32x4 ev = *(const f32x4*)&emb[(size_t)id * D_ + d];
    f32x4 o;
    #pragma unroll
    for (int j = 0; j < 4; ++j) {
        int dd = d + j;
        int i  = dd >> 1;
        float div = expf(-(float)(2 * i) * (9.210340371976184f / 1024.0f));
        float arg = (float)s * div;
        float pe  = (dd & 1) ? cosf(arg) : sinf(arg);
        o[j] = ev[j] * 32.0f + pe;
    }
    *(f32x4*)&x[(size_t)row * D_ + d] = o;
}

// ---- LayerNorm row kernel: f32 in -> bf16 out ----
__global__ __launch_bounds__(256)
void ln_kernel(const float* __restrict__ x, const float* __restrict__ g,
               const float* __restrict__ b, ushort_t* __restrict__ out)
{
    __shared__ float sb[4];
    int row = blockIdx.x;
    const float* xr = x + (size_t)row * D_;
    int c = threadIdx.x * 4;
    f32x4 v = *(const f32x4*)&xr[c];
    float s = v[0] + v[1] + v[2] + v[3];
    s = blk_sum(s, sb);
    float mean = s * (1.0f / D_);
    f32x4 dv = v - mean;
    float sq = dv[0]*dv[0] + dv[1]*dv[1] + dv[2]*dv[2] + dv[3]*dv[3];
    sq = blk_sum(sq, sb);
    float rstd = rsqrtf(sq * (1.0f / D_) + EPSLN);
    u16x4 o;
    #pragma unroll
    for (int j = 0; j < 4; ++j)
        o[j] = f2bf(dv[j] * rstd * g[c + j] + b[c + j]);
    *(u16x4*)&out[(size_t)row * D_ + c] = o;
}

__global__ void ws_marker(float* o) { o[threadIdx.x] = -777777.0f; }

// =====================================================================
extern "C" void kernel_launch(void* const* d_in, const int* in_sizes, int n_in,
                              void* d_out, int out_size, void* d_ws, size_t ws_size,
                              hipStream_t stream)
{
    (void)in_sizes; (void)n_in; (void)out_size;
    const int*   ids  = (const int*)d_in[0];
    const float* emb  = (const float*)d_in[1];
    const float* Wq   = (const float*)d_in[2];
    const float* bq   = (const float*)d_in[3];
    const float* Wk   = (const float*)d_in[4];
    const float* bk   = (const float*)d_in[5];
    const float* Wv   = (const float*)d_in[6];
    const float* bv   = (const float*)d_in[7];
    const float* Wo   = (const float*)d_in[8];
    const float* bo   = (const float*)d_in[9];
    const float* ln1g = (const float*)d_in[10];
    const float* ln1b = (const float*)d_in[11];
    const float* ln2g = (const float*)d_in[12];
    const float* ln2b = (const float*)d_in[13];
    const float* W1   = (const float*)d_in[14];
    const float* b1   = (const float*)d_in[15];
    const float* W2   = (const float*)d_in[16];
    const float* b2   = (const float*)d_in[17];
    const float* fng  = (const float*)d_in[18];
    const float* fnb  = (const float*)d_in[19];
    const float* Wout = (const float*)d_in[20];
    const float* bout = (const float*)d_in[21];
    float* out = (float*)d_out;

    // ---- workspace layout ----
    char* base = (char*)d_ws;
    size_t off = 0;
    float*    x    = (float*)(base + off);    off += (size_t)MTOK * D_ * 4;
    ushort_t* h    = (ushort_t*)(base + off); off += (size_t)MTOK * D_ * 2;
    ushort_t* qkv  = (ushort_t*)(base + off); off += (size_t)MTOK * 3 * D_ * 2;
    ushort_t* vt   = (ushort_t*)(base + off); off += (size_t)B_ * H_ * HD_ * S_ * 2;
    ushort_t* ctx  = (ushort_t*)(base + off); off += (size_t)MTOK * D_ * 2;
    ushort_t* ff   = (ushort_t*)(base + off); off += (size_t)MTOK * F_ * 2;
    float*    qkvb = (float*)(base + off);    off += 3072 * 4;
    ushort_t* wqkvT= (ushort_t*)(base + off); off += (size_t)3 * D_ * D_ * 2;
    ushort_t* woT  = (ushort_t*)(base + off); off += (size_t)D_ * D_ * 2;
    ushort_t* w1T  = (ushort_t*)(base + off); off += (size_t)D_ * F_ * 2;
    ushort_t* w2T  = (ushort_t*)(base + off); off += (size_t)F_ * D_ * 2;
    ushort_t* wouT = (ushort_t*)(base + off); off += (size_t)V_ * D_ * 2;
    if (ws_size < off) { ws_marker<<<1, 64, 0, stream>>>(out); return; }

    embed_pe<<<MTOK, 256, 0, stream>>>(ids, emb, x);

    for (int i = 0; i < L_; ++i) {
        prep_layer<<<3075, 256, 0, stream>>>(
            Wq + (size_t)i * D_ * D_, Wk + (size_t)i * D_ * D_,
            Wv + (size_t)i * D_ * D_, Wo + (size_t)i * D_ * D_,
            W1 + (size_t)i * D_ * F_, W2 + (size_t)i * F_ * D_,
            bq + i * D_, bk + i * D_, bv + i * D_,
            wqkvT, woT, w1T, w2T, qkvb);

        ln_kernel<<<MTOK, 256, 0, stream>>>(x, ln1g + i * D_, ln1b + i * D_, h);

        // qkv = h @ [Wq|Wk|Wv] + bias; V cols also scattered into vt
        gemm_bt<128,false,false,true,true><<<dim3(16, 24), 256, 0, stream>>>(
            h, D_, wqkvT, D_, qkv, 3 * D_, qkvb, nullptr, MTOK, 3 * D_, D_, vt);

        flash_attn<<<dim3(8, B_ * H_), 256, 0, stream>>>(qkv, vt, ctx);

        // x = x + ctx @ Wo + bo   (BN=64 -> 256 blocks, full fill)
        gemm_bt<64,false,true,false,false><<<dim3(16, 16), 256, 0, stream>>>(
            ctx, D_, woT, D_, x, D_, bo + i * D_, x, MTOK, D_, D_, nullptr);

        ln_kernel<<<MTOK, 256, 0, stream>>>(x, ln2g + i * D_, ln2b + i * D_, h);

        // ff = gelu(h @ W1 + b1)
        gemm_bt<128,true,false,true,false><<<dim3(16, 32), 256, 0, stream>>>(
            h, D_, w1T, D_, ff, F_, b1 + i * F_, nullptr, MTOK, F_, D_, nullptr);

        // x = x + ff @ W2 + b2   (BN=64 -> 256 blocks, full fill; 64 K-iters)
        gemm_bt<64,false,true,false,false><<<dim3(16, 16), 256, 0, stream>>>(
            ff, F_, w2T, F_, x, D_, b2 + i * D_, x, MTOK, D_, F_, nullptr);
    }

    ln_kernel<<<MTOK, 256, 0, stream>>>(x, fng, fnb, h);
    tconv<<<dim3(500, 16), 256, 0, stream>>>(Wout, wouT, D_, V_);
    // logits: 256^2 tiles (measured-best for N=32000)
    gemm256<false,false><<<dim3(8, 125), 512, 0, stream>>>(
        h, D_, wouT, D_, out, V_, bout, MTOK, V_, D_);
}